// Round 6
// baseline (308.316 us; speedup 1.0000x reference)
//
#include <hip/hip_runtime.h>
#include <hip/hip_bf16.h>

// Problem constants (B=1, H=W=64, C=768, nh=12, hd=64)
#define S_TOK 4096
#define CDIM  768
#define N3C   2304
#define NH    12
#define HD    64

#define LOG2E 1.44269504f

typedef __attribute__((ext_vector_type(8))) short short8;
typedef __attribute__((ext_vector_type(4))) short short4v;
typedef __attribute__((ext_vector_type(4))) float float4v;
typedef __attribute__((ext_vector_type(4))) unsigned uint4v;

__device__ __forceinline__ float b2f(short s) {
    return __uint_as_float(((unsigned)(unsigned short)s) << 16);
}
__device__ __forceinline__ short f2b(float f) {   // round-to-nearest-even
    unsigned u = __float_as_uint(f);
    unsigned r = (u + 0x7FFFu + ((u >> 16) & 1u)) >> 16;
    return (short)r;
}

#if __has_builtin(__builtin_amdgcn_exp2f)
#define EXP2F __builtin_amdgcn_exp2f
#else
#define EXP2F exp2f
#endif

// pack trunc-bf16(a) into low short, trunc-bf16(b) into high short
__device__ __forceinline__ unsigned pack_trunc(float a, float b) {
    return __builtin_amdgcn_perm(__float_as_uint(b), __float_as_uint(a), 0x07060302u);
}

__device__ __forceinline__ short8 u4_to_s8(unsigned a, unsigned b, unsigned c, unsigned d) {
    union { uint4v u; short8 s; } t;
    t.u = (uint4v){a, b, c, d};
    return t.s;
}

// async global->LDS DMA, 16B per lane, dest = ldsbase + lane*16 (linear)
__device__ __forceinline__ void load_lds16(const void* g, void* l) {
    __builtin_amdgcn_global_load_lds(
        (const __attribute__((address_space(1))) unsigned int*)g,
        (__attribute__((address_space(3))) unsigned int*)l, 16, 0, 0);
}

// ---------------------------------------------------------------------------
// Elementwise fp32 -> bf16 cast (4 elems/thread)
// ---------------------------------------------------------------------------
__global__ __launch_bounds__(256) void cast_bf16_kernel(
    const float* __restrict__ in, short* __restrict__ out, int n4)
{
    int i = blockIdx.x * 256 + threadIdx.x;
    if (i >= n4) return;
    float4 v = ((const float4*)in)[i];
    short4v o4 = { f2b(v.x), f2b(v.y), f2b(v.z), f2b(v.w) };
    *(short4v*)&out[(size_t)i * 4] = o4;
}

// ---------------------------------------------------------------------------
// Transpose + cast: in fp32 [R][C] -> out bf16 [C][R]. 64x64 tiles, 256 thr.
// ---------------------------------------------------------------------------
__global__ __launch_bounds__(256) void transpose_cast_kernel(
    const float* __restrict__ in, short* __restrict__ out, int R, int C)
{
    __shared__ float t[64][65];
    const int tid = threadIdx.x;
    const int c0 = blockIdx.x * 64, r0 = blockIdx.y * 64;
    const int li = tid >> 6;      // 0..3
    const int lj = tid & 63;
#pragma unroll
    for (int p = 0; p < 16; ++p) {
        int i = p * 4 + li;
        t[i][lj] = in[(size_t)(r0 + i) * C + c0 + lj];
    }
    __syncthreads();
#pragma unroll
    for (int p = 0; p < 16; ++p) {
        int i = p * 4 + li;
        out[(size_t)(c0 + i) * R + r0 + lj] = f2b(t[lj][i]);
    }
}

// ---------------------------------------------------------------------------
// MFMA GEMM core v2: C[128x128] = A[128xK] @ Bt[128xK]^T
//   Staging via global_load_lds; linear LDS dest, inverse swizzle folded into
//   the per-lane GLOBAL source address; frag reads apply the same XOR.
//   smem is a single 32 KB block so epilogues can overlay it.
// ---------------------------------------------------------------------------
#define GEMM_CORE(A_, Bt_)                                                     \
    __shared__ __align__(16) short smem[2][128][64];                           \
    auto a_s = smem[0];                                                        \
    auto b_s = smem[1];                                                        \
    const int tid  = threadIdx.x;                                              \
    const int m0 = blockIdx.y * 128;                                           \
    const int n0 = blockIdx.x * 128;                                           \
    const int lane = tid & 63, w = tid >> 6;                                   \
    const int l15 = lane & 15, quad = lane >> 4;                               \
    const int wr = w >> 1, wc = w & 1;                                         \
    const int roff0 = (quad ^ (l15 & 7)) << 4;                                 \
    const int roff1 = roff0 ^ 64;                                              \
    const int srow0 = w * 8 + (lane >> 3);                                     \
    const int sslot = (lane & 7) ^ ((lane >> 3) & 7);                          \
    const short* ga = A_ + (size_t)(m0 + srow0) * 768 + sslot * 8;             \
    const short* gb = Bt_ + (size_t)(n0 + srow0) * 768 + sslot * 8;            \
    short* la = &a_s[w * 8][0];                                                \
    short* lb = &b_s[w * 8][0];                                                \
    float4v acc[4][4];                                                         \
    _Pragma("unroll")                                                          \
    for (int i = 0; i < 4; ++i)                                                \
        _Pragma("unroll")                                                      \
        for (int j = 0; j < 4; ++j) acc[i][j] = (float4v){0.f,0.f,0.f,0.f};    \
    for (int k0 = 0; k0 < 768; k0 += 64) {                                     \
        __syncthreads();                                                       \
        _Pragma("unroll")                                                      \
        for (int i = 0; i < 4; ++i) {                                          \
            load_lds16(ga + (size_t)i * (32 * 768) + k0, la + i * 32 * 64);    \
            load_lds16(gb + (size_t)i * (32 * 768) + k0, lb + i * 32 * 64);    \
        }                                                                      \
        __syncthreads();                                                       \
        _Pragma("unroll")                                                      \
        for (int kk = 0; kk < 64; kk += 32) {                                  \
            const int roff = kk ? roff1 : roff0;                               \
            short8 af[4], bfr[4];                                              \
            _Pragma("unroll")                                                  \
            for (int i = 0; i < 4; ++i)                                        \
                af[i] = *(const short8*)((const char*)&a_s[wr*64 + i*16 + l15][0] + roff); \
            _Pragma("unroll")                                                  \
            for (int j = 0; j < 4; ++j)                                        \
                bfr[j] = *(const short8*)((const char*)&b_s[wc*64 + j*16 + l15][0] + roff); \
            _Pragma("unroll")                                                  \
            for (int i = 0; i < 4; ++i)                                        \
                _Pragma("unroll")                                              \
                for (int j = 0; j < 4; ++j)                                    \
                    acc[i][j] = __builtin_amdgcn_mfma_f32_16x16x32_bf16(       \
                        af[i], bfr[j], acc[i][j], 0, 0, 0);                    \
        }                                                                      \
    }

// QKV GEMM: writes Qb[head][s][d], Kb[head][s][d], Vt[head][d][s] (bf16)
// Epilogue: stage output tile in LDS, then fully-coalesced 16B stores.
__global__ __launch_bounds__(256) void gemm_qkv_mfma(
    const short* __restrict__ A, const short* __restrict__ Bt,
    const float* __restrict__ bias,
    short* __restrict__ Qb, short* __restrict__ Kb, short* __restrict__ Vt)
{
    GEMM_CORE(A, Bt)

    const int sec = n0 / CDIM;      // tile fully inside one of q/k/v
    float bj[4];
#pragma unroll
    for (int j = 0; j < 4; ++j) bj[j] = bias[n0 + wc*64 + j*16 + l15];

    if (sec < 2) {
        short* base = (sec == 0) ? Qb : Kb;
        short (*tile)[68] = (short(*)[68])&smem[0][0][0];   // 128x68 = 17408 B
#pragma unroll
        for (int h = 0; h < 2; ++h) {
            __syncthreads();
            if (wc == h) {
#pragma unroll
                for (int i = 0; i < 4; ++i)
#pragma unroll
                    for (int j = 0; j < 4; ++j)
#pragma unroll
                        for (int r = 0; r < 4; ++r)
                            tile[wr*64 + i*16 + quad*4 + r][j*16 + l15] =
                                f2b(acc[i][j][r] + bj[j]);
            }
            __syncthreads();
            const int nn = (n0 % CDIM) + h * 64;
            const int head = nn >> 6;
            short* dst = base + ((size_t)head * S_TOK + m0) * HD;
#pragma unroll
            for (int it = 0; it < 4; ++it) {
                const int row = it * 32 + (tid >> 3), c = (tid & 7) * 8;
                *(short8*)&dst[(size_t)row * HD + c] = *(const short8*)&tile[row][c];
            }
        }
    } else {
        short (*tv)[130] = (short(*)[130])&smem[0][0][0];   // 64x130 = 16640 B
#pragma unroll
        for (int h = 0; h < 2; ++h) {
            __syncthreads();
            if (wc == h) {
#pragma unroll
                for (int i = 0; i < 4; ++i)
#pragma unroll
                    for (int j = 0; j < 4; ++j) {
                        short4v v4;
#pragma unroll
                        for (int r = 0; r < 4; ++r) v4[r] = f2b(acc[i][j][r] + bj[j]);
                        *(short4v*)&tv[j*16 + l15][wr*64 + i*16 + quad*4] = v4;
                    }
            }
            __syncthreads();
            const int nn = (n0 % CDIM) + h * 64;
            const int head = nn >> 6;
            short* dst = Vt + (size_t)head * HD * S_TOK + m0;
#pragma unroll
            for (int it = 0; it < 4; ++it) {
                const int nr = it * 16 + (tid >> 4), sc = (tid & 15) * 8;
                *(short8*)&dst[(size_t)nr * S_TOK + sc] = *(const short8*)&tv[nr][sc];
            }
        }
    }
}

// Proj GEMM: out fp32 [4096][768] = A @ Bt^T + bias
// Epilogue: LDS float tile (XOR chunk swizzle), coalesced float4 stores.
__global__ __launch_bounds__(256) void gemm_proj_mfma(
    const short* __restrict__ A, const short* __restrict__ Bt,
    const float* __restrict__ bias, float* __restrict__ out)
{
    GEMM_CORE(A, Bt)

    float bj[4];
#pragma unroll
    for (int j = 0; j < 4; ++j) bj[j] = bias[n0 + wc*64 + j*16 + l15];

    float* tf = (float*)&smem[0][0][0];   // [64][128] floats, chunk-XOR layout
#pragma unroll
    for (int h = 0; h < 2; ++h) {
        __syncthreads();
        if (wr == h) {
#pragma unroll
            for (int i = 0; i < 4; ++i)
#pragma unroll
                for (int j = 0; j < 4; ++j) {
                    const int cc = wc*16 + j*4 + (l15 >> 2);   // float4-chunk idx
                    const int ci = l15 & 3;
#pragma unroll
                    for (int r = 0; r < 4; ++r) {
                        const int row = i*16 + quad*4 + r;
                        const int pc = cc ^ ((row & 7) << 2);
                        tf[row * 128 + pc * 4 + ci] = acc[i][j][r] + bj[j];
                    }
                }
        }
        __syncthreads();
        float* dst = out + (size_t)(m0 + h * 64) * CDIM + n0;
#pragma unroll
        for (int it = 0; it < 8; ++it) {
            const int row = it * 8 + (tid >> 5);
            const int gc = tid & 31;
            const int pc = gc ^ ((row & 7) << 2);
            float4 v = *(const float4*)&tf[row * 128 + pc * 4];
            *(float4*)&dst[(size_t)row * CDIM + gc * 4] = v;
        }
    }
}

// ---------------------------------------------------------------------------
// Rel-pos tables via MFMA. One block per (y, head); 64 queries s0=y*64..+63.
// Outputs PRE-SCALED by log2e. Relh stored TRANSPOSED: RelhT[head][ky][s].
// ---------------------------------------------------------------------------
__global__ __launch_bounds__(256) void rel_mfma_kernel(
    const short* __restrict__ Qb, const float* __restrict__ rph,
    const float* __restrict__ rpw, short* __restrict__ RelhT,
    short* __restrict__ Relw)
{
    __shared__ __align__(16) short q_s [64][72];
    __shared__ __align__(16) short rh_s[64][72];
    __shared__ __align__(16) short rw_s[128][72];

    const int tid  = threadIdx.x;
    const int y    = blockIdx.x;
    const int head = blockIdx.y;
    const int s0   = y * 64;
    const int w = tid >> 6, lane = tid & 63;
    const int l15 = lane & 15, quad = lane >> 4;
    const int srow = tid >> 2;            // 0..63
    const int scol = (tid & 3) << 4;      // 0,16,32,48

    // ---- stage Q (bf16 passthrough) ----
    {
        const uint4* g = (const uint4*)(Qb + ((size_t)head * S_TOK + s0 + srow) * HD + scol);
        *(uint4*)&q_s[srow][scol]     = g[0];
        *(uint4*)&q_s[srow][scol + 8] = g[1];
    }
    // ---- stage rph rows y..y+63 (fp32 -> bf16) ----
    {
        const float* g = rph + (size_t)(y + srow) * HD + scol;
        short tmp[16];
#pragma unroll
        for (int i = 0; i < 16; i += 4) {
            float4 v = *(const float4*)(g + i);
            tmp[i] = f2b(v.x); tmp[i+1] = f2b(v.y); tmp[i+2] = f2b(v.z); tmp[i+3] = f2b(v.w);
        }
        *(short8*)&rh_s[srow][scol]     = *(short8*)&tmp[0];
        *(short8*)&rh_s[srow][scol + 8] = *(short8*)&tmp[8];
    }
    // ---- stage rpw rows 0..127 (row 127 clamped; never consumed) ----
#pragma unroll
    for (int half = 0; half < 2; ++half) {
        const int row = srow + half * 64;
        const int rr  = row > 126 ? 126 : row;
        const float* g = rpw + (size_t)rr * HD + scol;
        short tmp[16];
#pragma unroll
        for (int i = 0; i < 16; i += 4) {
            float4 v = *(const float4*)(g + i);
            tmp[i] = f2b(v.x); tmp[i+1] = f2b(v.y); tmp[i+2] = f2b(v.z); tmp[i+3] = f2b(v.w);
        }
        *(short8*)&rw_s[row][scol]     = *(short8*)&tmp[0];
        *(short8*)&rw_s[row][scol + 8] = *(short8*)&tmp[8];
    }
    __syncthreads();

    const short8 qa0 = *(const short8*)&q_s[w * 16 + l15][quad * 8];
    const short8 qa1 = *(const short8*)&q_s[w * 16 + l15][32 + quad * 8];

    // ---- relh: RH col j = y+jj, ky = 63-jj; transposed short4v stores ----
#pragma unroll
    for (int ct = 0; ct < 4; ++ct) {
        const int jj = ct * 16 + l15;
        short8 b0 = *(const short8*)&rh_s[jj][quad * 8];
        short8 b1 = *(const short8*)&rh_s[jj][32 + quad * 8];
        float4v z = (float4v){0.f, 0.f, 0.f, 0.f};
        z = __builtin_amdgcn_mfma_f32_16x16x32_bf16(qa0, b0, z, 0, 0, 0);
        z = __builtin_amdgcn_mfma_f32_16x16x32_bf16(qa1, b1, z, 0, 0, 0);
        const int ky = 63 - jj;
        short4v o4;
#pragma unroll
        for (int r = 0; r < 4; ++r) o4[r] = f2b(z[r] * LOG2E);
        *(short4v*)&RelhT[((size_t)head * HD + ky) * S_TOK + s0 + w * 16 + quad * 4] = o4;
    }

    // ---- relw: kx = q+63-j, keep 0<=kx<64 ----
#pragma unroll
    for (int ct = 0; ct < 8; ++ct) {
        const int j = ct * 16 + l15;
        short8 b0 = *(const short8*)&rw_s[j][quad * 8];
        short8 b1 = *(const short8*)&rw_s[j][32 + quad * 8];
        float4v z = (float4v){0.f, 0.f, 0.f, 0.f};
        z = __builtin_amdgcn_mfma_f32_16x16x32_bf16(qa0, b0, z, 0, 0, 0);
        z = __builtin_amdgcn_mfma_f32_16x16x32_bf16(qa1, b1, z, 0, 0, 0);
#pragma unroll
        for (int r = 0; r < 4; ++r) {
            const int q  = w * 16 + quad * 4 + r;
            const int kx = q + 63 - j;
            if (kx >= 0 && kx < 64)
                Relw[((size_t)head * S_TOK + s0 + q) * HD + kx] = f2b(z[r] * LOG2E);
        }
    }
}

// ---------------------------------------------------------------------------
// Flash attention v9: v7 occupancy regime (12 waves/CU) with V REMOVED from
// LDS entirely.
//   Fragment algebra: the PV A-frag for lane (l15,quad) is
//   Vt[head][dt*16+l15][c*64 + h*32 + quad*8 .. +7] -- 16 contiguous bytes of
//   the [head][d][s] layout in NATURAL key order (the key bit-permutation
//   only affects K->P correspondence). So V loads go global->VGPR directly,
//   hoisted before the S-phase so L2 latency hides under 16 S-MFMAs + exp2.
//   Vt[head] (512 KB) is reused by 64 blocks -> L2-resident; an XCD swizzle
//   groups blocks by head (logical=(bid%8)*96+bid/8, bijective: 768=8*96) so
//   each XCD's V working set is ~1.5 heads <= 1 MB (fits 4 MB L2).
//   LDS: K only, double-buffered per pair = 32 KB. One barrier per step
//   (K reads done + next-K DMA landed; DMA has the whole step to fly).
//   Everything else (pair-split, key permutation, rwv/rh handling, combine)
//   identical to v7.
// ---------------------------------------------------------------------------
__global__ __launch_bounds__(256, 3) void flash_kernel(
    const short* __restrict__ Qb, const short* __restrict__ Kb,
    const short* __restrict__ Vt, const short* __restrict__ RelhT,
    const short* __restrict__ Relw, short* __restrict__ attn_b)
{
    // K[pair][buf][64][64] shorts = 32 KB
    __shared__ __align__(16) short lds_s[16384];

    const int tid  = threadIdx.x;
    const int bid  = blockIdx.x;
    const int logi = (bid & 7) * 96 + (bid >> 3);   // XCD head-grouping swizzle
    const int head = logi >> 6;
    const int s0   = (logi & 63) << 6;
    const int w    = tid >> 6, lane = tid & 63;
    const int l15  = lane & 15, quad = lane >> 4;
    const int ph   = w >> 1;          // key-chunk half: chunks ph*32 + t
    const int qh   = w & 1;           // query half: queries qh*32 + ...

    const float C1 = 0.125f * LOG2E;

    // ---- K staging lane mapping (linear dest, pre-swizzled source) ----
    const int lj = lane >> 3;             // row within 8-row DMA group
    const int sl = (lane & 7) ^ lj;       // logical 16B slot this lane fetches
    const int kf0 = (lj & 3) + ((lj & 4) << 1) + qh * 32;  // permuted key, ii=0

    const short* pK0 = Kb + (size_t)head * S_TOK * HD
                     + (size_t)(ph * 32 * 64 + kf0) * HD + sl * 8;

    short* lk[2] = { &lds_s[(ph*2 + 0) << 12] + qh*32*64,
                     &lds_s[(ph*2 + 1) << 12] + qh*32*64 };
    const short* krd[2] = { &lds_s[(ph*2 + 0) << 12], &lds_s[(ph*2 + 1) << 12] };

    // swizzled read byte-offsets (row&7 == l15&7 for all frag rows)
    const int roff0 = (quad ^ (l15 & 7)) << 4;   // logical slot quad
    const int roff1 = roff0 ^ 64;                // logical slot 4+quad

    // ---- V direct-global base (natural keys) ----
    const short* vb = Vt + ((size_t)head * HD + l15) * S_TOK
                    + ph * 32 * 64 + quad * 8;

    // ---- Q B-frags: 2 q-tiles (32 queries per wave) ----
    short8 qb[2][2];
#pragma unroll
    for (int qt = 0; qt < 2; ++qt) {
        const short* qrow = Qb + ((size_t)head * S_TOK + s0 + qh * 32 + qt * 16 + l15) * HD;
        qb[qt][0] = *(const short8*)(qrow + quad * 8);
        qb[qt][1] = *(const short8*)(qrow + 32 + quad * 8);
    }

    // ---- relw invariants: rwv[qt][kt][r], key = kbase(kt) + quad*8 + r ----
    float rwv[2][4][4];
#pragma unroll
    for (int qt = 0; qt < 2; ++qt) {
        const short* rwrow = Relw + ((size_t)head * S_TOK + s0 + qh * 32 + qt * 16 + l15) * HD;
#pragma unroll
        for (int kt = 0; kt < 4; ++kt) {
            const int base = ((kt & 1) << 2) | ((kt >> 1) << 5);
            short4v v = *(const short4v*)(rwrow + base + quad * 8);
#pragma unroll
            for (int r = 0; r < 4; ++r) rwv[qt][kt][r] = b2f(v[r]);
        }
    }

    // RelhT[head][ky][s]: per-chunk coalesced loads (ky == chunk index)
    const short* rhbase = RelhT + (size_t)head * HD * S_TOK + s0 + qh * 32 + l15;
    float rhc0 = b2f(rhbase[(size_t)(ph * 32) * S_TOK]);
    float rhc1 = b2f(rhbase[(size_t)(ph * 32) * S_TOK + 16]);

    // ones A-frag for the denominator
    short8 aones;
#pragma unroll
    for (int j = 0; j < 8; ++j) aones[j] = (short)0x3F80;

    float4v od[2][4];
#pragma unroll
    for (int qt = 0; qt < 2; ++qt)
#pragma unroll
        for (int dt = 0; dt < 4; ++dt) od[qt][dt] = (float4v){0.f, 0.f, 0.f, 0.f};
    float4v dq0 = (float4v){0.f, 0.f, 0.f, 0.f};
    float4v dq1 = (float4v){0.f, 0.f, 0.f, 0.f};

    // ---- prologue: DMA K chunk (ph*32) into buf0 ----
    load_lds16(pK0,        lk[0]);
    load_lds16(pK0 + 1024, lk[0] + 8  * 64);
    load_lds16(pK0 + 256,  lk[0] + 16 * 64);
    load_lds16(pK0 + 1280, lk[0] + 24 * 64);
    __syncthreads();

    for (int t = 0; t < 32; ++t) {
        const int cur = t & 1;

        // ---- V(t) frag loads: global -> VGPR, land during S-phase ----
        short8 vfr[8];
#pragma unroll
        for (int dt = 0; dt < 4; ++dt) {
            const short* vp = vb + (size_t)(dt * 16) * S_TOK + t * 64;
            vfr[dt * 2]     = *(const short8*)(vp);
            vfr[dt * 2 + 1] = *(const short8*)(vp + 32);
        }

        // ---- K(t+1) DMA into the other buffer + rh prefetch ----
        short rhn0, rhn1;
        if (t < 31) {
            const short* gk = pK0 + (size_t)(t + 1) * 4096;
            short* k1 = lk[cur ^ 1];
            load_lds16(gk,        k1);
            load_lds16(gk + 1024, k1 + 8  * 64);
            load_lds16(gk + 256,  k1 + 16 * 64);
            load_lds16(gk + 1280, k1 + 24 * 64);
            rhn0 = rhbase[(size_t)(ph * 32 + t + 1) * S_TOK];
            rhn1 = rhbase[(size_t)(ph * 32 + t + 1) * S_TOK + 16];
        }

        // ---- S-phase: K frags read once, used by both q-tiles ----
        const short* kc = krd[cur];
        unsigned pkk[2][8];
#pragma unroll
        for (int kt = 0; kt < 4; ++kt) {
            const char* krp = (const char*)(kc + (kt * 16 + l15) * 64);
            const short8 ka0 = *(const short8*)(krp + roff0);
            const short8 ka1 = *(const short8*)(krp + roff1);
            {
                float4v z = (float4v){0.f, 0.f, 0.f, 0.f};
                z = __builtin_amdgcn_mfma_f32_16x16x32_bf16(ka0, qb[0][0], z, 0, 0, 0);
                z = __builtin_amdgcn_mfma_f32_16x16x32_bf16(ka1, qb[0][1], z, 0, 0, 0);
                float p0 = EXP2F(C1 * z[0] + (rhc0 + rwv[0][kt][0]));
                float p1 = EXP2F(C1 * z[1] + (rhc0 + rwv[0][kt][1]));
                float p2 = EXP2F(C1 * z[2] + (rhc0 + rwv[0][kt][2]));
                float p3 = EXP2F(C1 * z[3] + (rhc0 + rwv[0][kt][3]));
                pkk[0][kt * 2]     = pack_trunc(p0, p1);
                pkk[0][kt * 2 + 1] = pack_trunc(p2, p3);
            }
            {
                float4v z = (float4v){0.f, 0.f, 0.f, 0.f};
                z = __builtin_amdgcn_mfma_f32_16x16x32_bf16(ka0, qb[1][0], z, 0, 0, 0);
                z = __builtin_amdgcn_mfma_f32_16x16x32_bf16(ka1, qb[1][1], z, 0, 0, 0);
                float p0 = EXP2F(C1 * z[0] + (rhc1 + rwv[1][kt][0]));
                float p1 = EXP2F(C1 * z[1] + (rhc1 + rwv[1][kt][1]));
                float p2 = EXP2F(C1 * z[2] + (rhc1 + rwv[1][kt][2]));
                float p3 = EXP2F(C1 * z[3] + (rhc1 + rwv[1][kt][3]));
                pkk[1][kt * 2]     = pack_trunc(p0, p1);
                pkk[1][kt * 2 + 1] = pack_trunc(p2, p3);
            }
        }
        const short8 pb00 = u4_to_s8(pkk[0][0], pkk[0][1], pkk[0][2], pkk[0][3]);
        const short8 pb01 = u4_to_s8(pkk[0][4], pkk[0][5], pkk[0][6], pkk[0][7]);
        const short8 pb10 = u4_to_s8(pkk[1][0], pkk[1][1], pkk[1][2], pkk[1][3]);
        const short8 pb11 = u4_to_s8(pkk[1][4], pkk[1][5], pkk[1][6], pkk[1][7]);

        // ---- PV from V regs (T5 setprio); no mid-step barrier ----
        __builtin_amdgcn_s_setprio(1);
#pragma unroll
        for (int dt = 0; dt < 4; ++dt) {
            od[0][dt] = __builtin_amdgcn_mfma_f32_16x16x32_bf16(vfr[dt*2],   pb00, od[0][dt], 0, 0, 0);
            od[0][dt] = __builtin_amdgcn_mfma_f32_16x16x32_bf16(vfr[dt*2+1], pb01, od[0][dt], 0, 0, 0);
            od[1][dt] = __builtin_amdgcn_mfma_f32_16x16x32_bf16(vfr[dt*2],   pb10, od[1][dt], 0, 0, 0);
            od[1][dt] = __builtin_amdgcn_mfma_f32_16x16x32_bf16(vfr[dt*2+1], pb11, od[1][dt], 0, 0, 0);
        }
        dq0 = __builtin_amdgcn_mfma_f32_16x16x32_bf16(aones, pb00, dq0, 0, 0, 0);
        dq0 = __builtin_amdgcn_mfma_f32_16x16x32_bf16(aones, pb01, dq0, 0, 0, 0);
        dq1 = __builtin_amdgcn_mfma_f32_16x16x32_bf16(aones, pb10, dq1, 0, 0, 0);
        dq1 = __builtin_amdgcn_mfma_f32_16x16x32_bf16(aones, pb11, dq1, 0, 0, 0);
        __builtin_amdgcn_s_setprio(0);

        if (t < 31) {
            rhc0 = b2f(rhn0);
            rhc1 = b2f(rhn1);
        }
        __syncthreads();   // K reads of buf cur done; K-DMA of buf^1 landed
    }

    // ---- cross-pair combine (overlays the K region; all K reads done) ----
    float* cf = (float*)lds_s;   // comb: [qh][qt][dt][16][16] floats; dq at 4096
    if (ph == 1) {
#pragma unroll
        for (int qt = 0; qt < 2; ++qt)
#pragma unroll
            for (int dt = 0; dt < 4; ++dt) {
                float* dst = &cf[((((qh * 2 + qt) * 4 + dt) * 16) + quad * 4) * 16 + l15];
#pragma unroll
                for (int r = 0; r < 4; ++r) dst[r * 16] = od[qt][dt][r];
            }
        if (quad == 0) {
            cf[4096 + (qh * 2 + 0) * 16 + l15] = dq0[0];
            cf[4096 + (qh * 2 + 1) * 16 + l15] = dq1[0];
        }
    }
    __syncthreads();
    if (ph == 0) {
#pragma unroll
        for (int qt = 0; qt < 2; ++qt) {
            const float dtot = ((qt == 0) ? dq0[0] : dq1[0])
                             + cf[4096 + (qh * 2 + qt) * 16 + l15];
            const float inv = 1.f / dtot;
            short* outp = attn_b + (size_t)(s0 + qh * 32 + qt * 16 + l15) * CDIM + head * HD;
#pragma unroll
            for (int dt = 0; dt < 4; ++dt) {
                const float* src = &cf[((((qh * 2 + qt) * 4 + dt) * 16) + quad * 4) * 16 + l15];
                short4v o4;
#pragma unroll
                for (int r = 0; r < 4; ++r)
                    o4[r] = f2b((od[qt][dt][r] + src[r * 16]) * inv);
                *(short4v*)(outp + dt * 16 + quad * 4) = o4;
            }
        }
    }
}

// ---------------------------------------------------------------------------
extern "C" void kernel_launch(void* const* d_in, const int* in_sizes, int n_in,
                              void* d_out, int out_size, void* d_ws, size_t ws_size,
                              hipStream_t stream)
{
    const float* x    = (const float*)d_in[0];
    const float* qkvw = (const float*)d_in[1];
    const float* qkvb = (const float*)d_in[2];
    const float* rph  = (const float*)d_in[3];
    const float* rpw  = (const float*)d_in[4];
    const float* pw   = (const float*)d_in[5];
    const float* pb   = (const float*)d_in[6];
    float* out = (float*)d_out;

    // ws layout (shorts), total ~48.8 MB
    const size_t HSD = (size_t)NH * S_TOK * HD;   // 3,145,728
    short* xb     = (short*)d_ws;                 // 4096*768
    short* wt     = xb + (size_t)S_TOK * CDIM;    // 2304*768 (qkv_w^T)
    short* pwt    = wt + (size_t)N3C * CDIM;      // 768*768  (proj_w^T)
    short* Qb     = pwt + (size_t)CDIM * CDIM;
    short* Kb     = Qb + HSD;
    short* Vt     = Kb + HSD;
    short* RelhT  = Vt + HSD;                     // [head][ky][s]
    short* Relw   = RelhT + HSD;
    short* attn_b = Relw + HSD;                   // 4096*768

    cast_bf16_kernel<<<S_TOK * CDIM / 4 / 256, 256, 0, stream>>>(x, xb, S_TOK * CDIM / 4);
    transpose_cast_kernel<<<dim3(N3C / 64, CDIM / 64), 256, 0, stream>>>(qkvw, wt, CDIM, N3C);
    transpose_cast_kernel<<<dim3(CDIM / 64, CDIM / 64), 256, 0, stream>>>(pw, pwt, CDIM, CDIM);

    gemm_qkv_mfma<<<dim3(N3C / 128, S_TOK / 128), 256, 0, stream>>>(
        xb, wt, qkvb, Qb, Kb, Vt);
    rel_mfma_kernel<<<dim3(64, NH), 256, 0, stream>>>(Qb, rph, rpw, RelhT, Relw);
    flash_kernel<<<dim3(64 * NH), 256, 0, stream>>>(Qb, Kb, Vt, RelhT, Relw, attn_b);
    gemm_proj_mfma<<<dim3(CDIM / 128, S_TOK / 128), 256, 0, stream>>>(
        attn_b, pwt, pb, out);
}

// Round 7
// 254.016 us; speedup vs baseline: 1.2138x; 1.2138x over previous
//
#include <hip/hip_runtime.h>
#include <hip/hip_bf16.h>

// Problem constants (B=1, H=W=64, C=768, nh=12, hd=64)
#define S_TOK 4096
#define CDIM  768
#define N3C   2304
#define NH    12
#define HD    64

#define LOG2E 1.44269504f

typedef __attribute__((ext_vector_type(8))) short short8;
typedef __attribute__((ext_vector_type(4))) short short4v;
typedef __attribute__((ext_vector_type(4))) float float4v;
typedef __attribute__((ext_vector_type(4))) unsigned uint4v;

__device__ __forceinline__ float b2f(short s) {
    return __uint_as_float(((unsigned)(unsigned short)s) << 16);
}
__device__ __forceinline__ short f2b(float f) {   // round-to-nearest-even
    unsigned u = __float_as_uint(f);
    unsigned r = (u + 0x7FFFu + ((u >> 16) & 1u)) >> 16;
    return (short)r;
}

#if __has_builtin(__builtin_amdgcn_exp2f)
#define EXP2F __builtin_amdgcn_exp2f
#else
#define EXP2F exp2f
#endif

// pack trunc-bf16(a) into low short, trunc-bf16(b) into high short
__device__ __forceinline__ unsigned pack_trunc(float a, float b) {
    return __builtin_amdgcn_perm(__float_as_uint(b), __float_as_uint(a), 0x07060302u);
}

__device__ __forceinline__ short8 u4_to_s8(unsigned a, unsigned b, unsigned c, unsigned d) {
    union { uint4v u; short8 s; } t;
    t.u = (uint4v){a, b, c, d};
    return t.s;
}

// async global->LDS DMA, 16B per lane, dest = ldsbase + lane*16 (linear)
__device__ __forceinline__ void load_lds16(const void* g, void* l) {
    __builtin_amdgcn_global_load_lds(
        (const __attribute__((address_space(1))) unsigned int*)g,
        (__attribute__((address_space(3))) unsigned int*)l, 16, 0, 0);
}

// ---------------------------------------------------------------------------
// Elementwise fp32 -> bf16 cast (4 elems/thread)
// ---------------------------------------------------------------------------
__global__ __launch_bounds__(256) void cast_bf16_kernel(
    const float* __restrict__ in, short* __restrict__ out, int n4)
{
    int i = blockIdx.x * 256 + threadIdx.x;
    if (i >= n4) return;
    float4 v = ((const float4*)in)[i];
    short4v o4 = { f2b(v.x), f2b(v.y), f2b(v.z), f2b(v.w) };
    *(short4v*)&out[(size_t)i * 4] = o4;
}

// ---------------------------------------------------------------------------
// Transpose + cast: in fp32 [R][C] -> out bf16 [C][R]. 64x64 tiles, 256 thr.
// ---------------------------------------------------------------------------
__global__ __launch_bounds__(256) void transpose_cast_kernel(
    const float* __restrict__ in, short* __restrict__ out, int R, int C)
{
    __shared__ float t[64][65];
    const int tid = threadIdx.x;
    const int c0 = blockIdx.x * 64, r0 = blockIdx.y * 64;
    const int li = tid >> 6;      // 0..3
    const int lj = tid & 63;
#pragma unroll
    for (int p = 0; p < 16; ++p) {
        int i = p * 4 + li;
        t[i][lj] = in[(size_t)(r0 + i) * C + c0 + lj];
    }
    __syncthreads();
#pragma unroll
    for (int p = 0; p < 16; ++p) {
        int i = p * 4 + li;
        out[(size_t)(c0 + i) * R + r0 + lj] = f2b(t[lj][i]);
    }
}

// ---------------------------------------------------------------------------
// MFMA GEMM core v2: C[128x128] = A[128xK] @ Bt[128xK]^T
//   Staging via global_load_lds; linear LDS dest, inverse swizzle folded into
//   the per-lane GLOBAL source address; frag reads apply the same XOR.
//   smem is a single 32 KB block so epilogues can overlay it.
// ---------------------------------------------------------------------------
#define GEMM_CORE(A_, Bt_)                                                     \
    __shared__ __align__(16) short smem[2][128][64];                           \
    auto a_s = smem[0];                                                        \
    auto b_s = smem[1];                                                        \
    const int tid  = threadIdx.x;                                              \
    const int m0 = blockIdx.y * 128;                                           \
    const int n0 = blockIdx.x * 128;                                           \
    const int lane = tid & 63, w = tid >> 6;                                   \
    const int l15 = lane & 15, quad = lane >> 4;                               \
    const int wr = w >> 1, wc = w & 1;                                         \
    const int roff0 = (quad ^ (l15 & 7)) << 4;                                 \
    const int roff1 = roff0 ^ 64;                                              \
    const int srow0 = w * 8 + (lane >> 3);                                     \
    const int sslot = (lane & 7) ^ ((lane >> 3) & 7);                          \
    const short* ga = A_ + (size_t)(m0 + srow0) * 768 + sslot * 8;             \
    const short* gb = Bt_ + (size_t)(n0 + srow0) * 768 + sslot * 8;            \
    short* la = &a_s[w * 8][0];                                                \
    short* lb = &b_s[w * 8][0];                                                \
    float4v acc[4][4];                                                         \
    _Pragma("unroll")                                                          \
    for (int i = 0; i < 4; ++i)                                                \
        _Pragma("unroll")                                                      \
        for (int j = 0; j < 4; ++j) acc[i][j] = (float4v){0.f,0.f,0.f,0.f};    \
    for (int k0 = 0; k0 < 768; k0 += 64) {                                     \
        __syncthreads();                                                       \
        _Pragma("unroll")                                                      \
        for (int i = 0; i < 4; ++i) {                                          \
            load_lds16(ga + (size_t)i * (32 * 768) + k0, la + i * 32 * 64);    \
            load_lds16(gb + (size_t)i * (32 * 768) + k0, lb + i * 32 * 64);    \
        }                                                                      \
        __syncthreads();                                                       \
        _Pragma("unroll")                                                      \
        for (int kk = 0; kk < 64; kk += 32) {                                  \
            const int roff = kk ? roff1 : roff0;                               \
            short8 af[4], bfr[4];                                              \
            _Pragma("unroll")                                                  \
            for (int i = 0; i < 4; ++i)                                        \
                af[i] = *(const short8*)((const char*)&a_s[wr*64 + i*16 + l15][0] + roff); \
            _Pragma("unroll")                                                  \
            for (int j = 0; j < 4; ++j)                                        \
                bfr[j] = *(const short8*)((const char*)&b_s[wc*64 + j*16 + l15][0] + roff); \
            _Pragma("unroll")                                                  \
            for (int i = 0; i < 4; ++i)                                        \
                _Pragma("unroll")                                              \
                for (int j = 0; j < 4; ++j)                                    \
                    acc[i][j] = __builtin_amdgcn_mfma_f32_16x16x32_bf16(       \
                        af[i], bfr[j], acc[i][j], 0, 0, 0);                    \
        }                                                                      \
    }

// QKV GEMM: writes Qb[head][s][d], Kb[head][s][d], Vt[head][d][s] (bf16)
// Epilogue: stage output tile in LDS, then fully-coalesced 16B stores.
__global__ __launch_bounds__(256) void gemm_qkv_mfma(
    const short* __restrict__ A, const short* __restrict__ Bt,
    const float* __restrict__ bias,
    short* __restrict__ Qb, short* __restrict__ Kb, short* __restrict__ Vt)
{
    GEMM_CORE(A, Bt)

    const int sec = n0 / CDIM;      // tile fully inside one of q/k/v
    float bj[4];
#pragma unroll
    for (int j = 0; j < 4; ++j) bj[j] = bias[n0 + wc*64 + j*16 + l15];

    if (sec < 2) {
        short* base = (sec == 0) ? Qb : Kb;
        short (*tile)[68] = (short(*)[68])&smem[0][0][0];   // 128x68 = 17408 B
#pragma unroll
        for (int h = 0; h < 2; ++h) {
            __syncthreads();
            if (wc == h) {
#pragma unroll
                for (int i = 0; i < 4; ++i)
#pragma unroll
                    for (int j = 0; j < 4; ++j)
#pragma unroll
                        for (int r = 0; r < 4; ++r)
                            tile[wr*64 + i*16 + quad*4 + r][j*16 + l15] =
                                f2b(acc[i][j][r] + bj[j]);
            }
            __syncthreads();
            const int nn = (n0 % CDIM) + h * 64;
            const int head = nn >> 6;
            short* dst = base + ((size_t)head * S_TOK + m0) * HD;
#pragma unroll
            for (int it = 0; it < 4; ++it) {
                const int row = it * 32 + (tid >> 3), c = (tid & 7) * 8;
                *(short8*)&dst[(size_t)row * HD + c] = *(const short8*)&tile[row][c];
            }
        }
    } else {
        short (*tv)[130] = (short(*)[130])&smem[0][0][0];   // 64x130 = 16640 B
#pragma unroll
        for (int h = 0; h < 2; ++h) {
            __syncthreads();
            if (wc == h) {
#pragma unroll
                for (int i = 0; i < 4; ++i)
#pragma unroll
                    for (int j = 0; j < 4; ++j) {
                        short4v v4;
#pragma unroll
                        for (int r = 0; r < 4; ++r) v4[r] = f2b(acc[i][j][r] + bj[j]);
                        *(short4v*)&tv[j*16 + l15][wr*64 + i*16 + quad*4] = v4;
                    }
            }
            __syncthreads();
            const int nn = (n0 % CDIM) + h * 64;
            const int head = nn >> 6;
            short* dst = Vt + (size_t)head * HD * S_TOK + m0;
#pragma unroll
            for (int it = 0; it < 4; ++it) {
                const int nr = it * 16 + (tid >> 4), sc = (tid & 15) * 8;
                *(short8*)&dst[(size_t)nr * S_TOK + sc] = *(const short8*)&tv[nr][sc];
            }
        }
    }
}

// Proj GEMM: out fp32 [4096][768] = A @ Bt^T + bias
// Epilogue: LDS float tile (XOR chunk swizzle), coalesced float4 stores.
__global__ __launch_bounds__(256) void gemm_proj_mfma(
    const short* __restrict__ A, const short* __restrict__ Bt,
    const float* __restrict__ bias, float* __restrict__ out)
{
    GEMM_CORE(A, Bt)

    float bj[4];
#pragma unroll
    for (int j = 0; j < 4; ++j) bj[j] = bias[n0 + wc*64 + j*16 + l15];

    float* tf = (float*)&smem[0][0][0];   // [64][128] floats, chunk-XOR layout
#pragma unroll
    for (int h = 0; h < 2; ++h) {
        __syncthreads();
        if (wr == h) {
#pragma unroll
            for (int i = 0; i < 4; ++i)
#pragma unroll
                for (int j = 0; j < 4; ++j) {
                    const int cc = wc*16 + j*4 + (l15 >> 2);   // float4-chunk idx
                    const int ci = l15 & 3;
#pragma unroll
                    for (int r = 0; r < 4; ++r) {
                        const int row = i*16 + quad*4 + r;
                        const int pc = cc ^ ((row & 7) << 2);
                        tf[row * 128 + pc * 4 + ci] = acc[i][j][r] + bj[j];
                    }
                }
        }
        __syncthreads();
        float* dst = out + (size_t)(m0 + h * 64) * CDIM + n0;
#pragma unroll
        for (int it = 0; it < 8; ++it) {
            const int row = it * 8 + (tid >> 5);
            const int gc = tid & 31;
            const int pc = gc ^ ((row & 7) << 2);
            float4 v = *(const float4*)&tf[row * 128 + pc * 4];
            *(float4*)&dst[(size_t)row * CDIM + gc * 4] = v;
        }
    }
}

// ---------------------------------------------------------------------------
// Rel-pos tables via MFMA. One block per (y, head); 64 queries s0=y*64..+63.
// Outputs PRE-SCALED by log2e. Relh stored TRANSPOSED: RelhT[head][ky][s].
// ---------------------------------------------------------------------------
__global__ __launch_bounds__(256) void rel_mfma_kernel(
    const short* __restrict__ Qb, const float* __restrict__ rph,
    const float* __restrict__ rpw, short* __restrict__ RelhT,
    short* __restrict__ Relw)
{
    __shared__ __align__(16) short q_s [64][72];
    __shared__ __align__(16) short rh_s[64][72];
    __shared__ __align__(16) short rw_s[128][72];

    const int tid  = threadIdx.x;
    const int y    = blockIdx.x;
    const int head = blockIdx.y;
    const int s0   = y * 64;
    const int w = tid >> 6, lane = tid & 63;
    const int l15 = lane & 15, quad = lane >> 4;
    const int srow = tid >> 2;            // 0..63
    const int scol = (tid & 3) << 4;      // 0,16,32,48

    // ---- stage Q (bf16 passthrough) ----
    {
        const uint4* g = (const uint4*)(Qb + ((size_t)head * S_TOK + s0 + srow) * HD + scol);
        *(uint4*)&q_s[srow][scol]     = g[0];
        *(uint4*)&q_s[srow][scol + 8] = g[1];
    }
    // ---- stage rph rows y..y+63 (fp32 -> bf16) ----
    {
        const float* g = rph + (size_t)(y + srow) * HD + scol;
        short tmp[16];
#pragma unroll
        for (int i = 0; i < 16; i += 4) {
            float4 v = *(const float4*)(g + i);
            tmp[i] = f2b(v.x); tmp[i+1] = f2b(v.y); tmp[i+2] = f2b(v.z); tmp[i+3] = f2b(v.w);
        }
        *(short8*)&rh_s[srow][scol]     = *(short8*)&tmp[0];
        *(short8*)&rh_s[srow][scol + 8] = *(short8*)&tmp[8];
    }
    // ---- stage rpw rows 0..127 (row 127 clamped; never consumed) ----
#pragma unroll
    for (int half = 0; half < 2; ++half) {
        const int row = srow + half * 64;
        const int rr  = row > 126 ? 126 : row;
        const float* g = rpw + (size_t)rr * HD + scol;
        short tmp[16];
#pragma unroll
        for (int i = 0; i < 16; i += 4) {
            float4 v = *(const float4*)(g + i);
            tmp[i] = f2b(v.x); tmp[i+1] = f2b(v.y); tmp[i+2] = f2b(v.z); tmp[i+3] = f2b(v.w);
        }
        *(short8*)&rw_s[row][scol]     = *(short8*)&tmp[0];
        *(short8*)&rw_s[row][scol + 8] = *(short8*)&tmp[8];
    }
    __syncthreads();

    const short8 qa0 = *(const short8*)&q_s[w * 16 + l15][quad * 8];
    const short8 qa1 = *(const short8*)&q_s[w * 16 + l15][32 + quad * 8];

    // ---- relh: RH col j = y+jj, ky = 63-jj; transposed short4v stores ----
#pragma unroll
    for (int ct = 0; ct < 4; ++ct) {
        const int jj = ct * 16 + l15;
        short8 b0 = *(const short8*)&rh_s[jj][quad * 8];
        short8 b1 = *(const short8*)&rh_s[jj][32 + quad * 8];
        float4v z = (float4v){0.f, 0.f, 0.f, 0.f};
        z = __builtin_amdgcn_mfma_f32_16x16x32_bf16(qa0, b0, z, 0, 0, 0);
        z = __builtin_amdgcn_mfma_f32_16x16x32_bf16(qa1, b1, z, 0, 0, 0);
        const int ky = 63 - jj;
        short4v o4;
#pragma unroll
        for (int r = 0; r < 4; ++r) o4[r] = f2b(z[r] * LOG2E);
        *(short4v*)&RelhT[((size_t)head * HD + ky) * S_TOK + s0 + w * 16 + quad * 4] = o4;
    }

    // ---- relw: kx = q+63-j, keep 0<=kx<64 ----
#pragma unroll
    for (int ct = 0; ct < 8; ++ct) {
        const int j = ct * 16 + l15;
        short8 b0 = *(const short8*)&rw_s[j][quad * 8];
        short8 b1 = *(const short8*)&rw_s[j][32 + quad * 8];
        float4v z = (float4v){0.f, 0.f, 0.f, 0.f};
        z = __builtin_amdgcn_mfma_f32_16x16x32_bf16(qa0, b0, z, 0, 0, 0);
        z = __builtin_amdgcn_mfma_f32_16x16x32_bf16(qa1, b1, z, 0, 0, 0);
#pragma unroll
        for (int r = 0; r < 4; ++r) {
            const int q  = w * 16 + quad * 4 + r;
            const int kx = q + 63 - j;
            if (kx >= 0 && kx < 64)
                Relw[((size_t)head * S_TOK + s0 + q) * HD + kx] = f2b(z[r] * LOG2E);
        }
    }
}

// ---------------------------------------------------------------------------
// Flash attention v10 = v9 with the scratch bug fixed: the double-buffer
// pointers are selected via TERNARY (cndmask), not runtime-indexed arrays.
// (v9's lk[cur]/krd[cur] arrays went to scratch -- rule #20 -- visible as
// WRITE_SIZE 6144->34560 KB and a 2.3x slowdown.)
//   Structure: V direct global->VGPR (natural key order; L2-resident via XCD
//   head-grouping swizzle, FETCH ~= ideal 30 MB); K-only LDS double-buffer
//   (32 KB); one barrier per step; pair-split 4 waves; 12 waves/CU.
// ---------------------------------------------------------------------------
__global__ __launch_bounds__(256, 3) void flash_kernel(
    const short* __restrict__ Qb, const short* __restrict__ Kb,
    const short* __restrict__ Vt, const short* __restrict__ RelhT,
    const short* __restrict__ Relw, short* __restrict__ attn_b)
{
    // K[pair][buf][64][64] shorts = 32 KB
    __shared__ __align__(16) short lds_s[16384];

    const int tid  = threadIdx.x;
    const int bid  = blockIdx.x;
    const int logi = (bid & 7) * 96 + (bid >> 3);   // XCD head-grouping swizzle
    const int head = logi >> 6;
    const int s0   = (logi & 63) << 6;
    const int w    = tid >> 6, lane = tid & 63;
    const int l15  = lane & 15, quad = lane >> 4;
    const int ph   = w >> 1;          // key-chunk half: chunks ph*32 + t
    const int qh   = w & 1;           // query half: queries qh*32 + ...

    const float C1 = 0.125f * LOG2E;

    // ---- K staging lane mapping (linear dest, pre-swizzled source) ----
    const int lj = lane >> 3;             // row within 8-row DMA group
    const int sl = (lane & 7) ^ lj;       // logical 16B slot this lane fetches
    const int kf0 = (lj & 3) + ((lj & 4) << 1) + qh * 32;  // permuted key, ii=0

    const short* pK0 = Kb + (size_t)head * S_TOK * HD
                     + (size_t)(ph * 32 * 64 + kf0) * HD + sl * 8;

    // named double-buffer pointers (NO runtime-indexed arrays -> no scratch)
    short* lk0 = &lds_s[(ph*2 + 0) << 12] + qh*32*64;
    short* lk1 = &lds_s[(ph*2 + 1) << 12] + qh*32*64;
    const short* krd0 = &lds_s[(ph*2 + 0) << 12];
    const short* krd1 = &lds_s[(ph*2 + 1) << 12];

    // swizzled read byte-offsets (row&7 == l15&7 for all frag rows)
    const int roff0 = (quad ^ (l15 & 7)) << 4;   // logical slot quad
    const int roff1 = roff0 ^ 64;                // logical slot 4+quad

    // ---- V direct-global base (natural keys) ----
    const short* vb = Vt + ((size_t)head * HD + l15) * S_TOK
                    + ph * 32 * 64 + quad * 8;

    // ---- Q B-frags: 2 q-tiles (32 queries per wave) ----
    short8 qb[2][2];
#pragma unroll
    for (int qt = 0; qt < 2; ++qt) {
        const short* qrow = Qb + ((size_t)head * S_TOK + s0 + qh * 32 + qt * 16 + l15) * HD;
        qb[qt][0] = *(const short8*)(qrow + quad * 8);
        qb[qt][1] = *(const short8*)(qrow + 32 + quad * 8);
    }

    // ---- relw invariants: rwv[qt][kt][r], key = kbase(kt) + quad*8 + r ----
    float rwv[2][4][4];
#pragma unroll
    for (int qt = 0; qt < 2; ++qt) {
        const short* rwrow = Relw + ((size_t)head * S_TOK + s0 + qh * 32 + qt * 16 + l15) * HD;
#pragma unroll
        for (int kt = 0; kt < 4; ++kt) {
            const int base = ((kt & 1) << 2) | ((kt >> 1) << 5);
            short4v v = *(const short4v*)(rwrow + base + quad * 8);
#pragma unroll
            for (int r = 0; r < 4; ++r) rwv[qt][kt][r] = b2f(v[r]);
        }
    }

    // RelhT[head][ky][s]: per-chunk coalesced loads (ky == chunk index)
    const short* rhbase = RelhT + (size_t)head * HD * S_TOK + s0 + qh * 32 + l15;
    float rhc0 = b2f(rhbase[(size_t)(ph * 32) * S_TOK]);
    float rhc1 = b2f(rhbase[(size_t)(ph * 32) * S_TOK + 16]);

    // ones A-frag for the denominator
    short8 aones;
#pragma unroll
    for (int j = 0; j < 8; ++j) aones[j] = (short)0x3F80;

    float4v od[2][4];
#pragma unroll
    for (int qt = 0; qt < 2; ++qt)
#pragma unroll
        for (int dt = 0; dt < 4; ++dt) od[qt][dt] = (float4v){0.f, 0.f, 0.f, 0.f};
    float4v dq0 = (float4v){0.f, 0.f, 0.f, 0.f};
    float4v dq1 = (float4v){0.f, 0.f, 0.f, 0.f};

    // ---- prologue: DMA K chunk (ph*32) into buf0 ----
    load_lds16(pK0,        lk0);
    load_lds16(pK0 + 1024, lk0 + 8  * 64);
    load_lds16(pK0 + 256,  lk0 + 16 * 64);
    load_lds16(pK0 + 1280, lk0 + 24 * 64);
    __syncthreads();

    for (int t = 0; t < 32; ++t) {
        const int cur = t & 1;
        const short* kc = cur ? krd1 : krd0;
        short* lkn = cur ? lk0 : lk1;

        // ---- V(t) frag loads: global -> VGPR, land during S-phase ----
        short8 vfr[8];
#pragma unroll
        for (int dt = 0; dt < 4; ++dt) {
            const short* vp = vb + (size_t)(dt * 16) * S_TOK + t * 64;
            vfr[dt * 2]     = *(const short8*)(vp);
            vfr[dt * 2 + 1] = *(const short8*)(vp + 32);
        }

        // ---- K(t+1) DMA into the other buffer + rh prefetch ----
        short rhn0, rhn1;
        if (t < 31) {
            const short* gk = pK0 + (size_t)(t + 1) * 4096;
            load_lds16(gk,        lkn);
            load_lds16(gk + 1024, lkn + 8  * 64);
            load_lds16(gk + 256,  lkn + 16 * 64);
            load_lds16(gk + 1280, lkn + 24 * 64);
            rhn0 = rhbase[(size_t)(ph * 32 + t + 1) * S_TOK];
            rhn1 = rhbase[(size_t)(ph * 32 + t + 1) * S_TOK + 16];
        }

        // ---- S-phase: K frags read once, used by both q-tiles ----
        unsigned pkk[2][8];
#pragma unroll
        for (int kt = 0; kt < 4; ++kt) {
            const char* krp = (const char*)(kc + (kt * 16 + l15) * 64);
            const short8 ka0 = *(const short8*)(krp + roff0);
            const short8 ka1 = *(const short8*)(krp + roff1);
            {
                float4v z = (float4v){0.f, 0.f, 0.f, 0.f};
                z = __builtin_amdgcn_mfma_f32_16x16x32_bf16(ka0, qb[0][0], z, 0, 0, 0);
                z = __builtin_amdgcn_mfma_f32_16x16x32_bf16(ka1, qb[0][1], z, 0, 0, 0);
                float p0 = EXP2F(C1 * z[0] + (rhc0 + rwv[0][kt][0]));
                float p1 = EXP2F(C1 * z[1] + (rhc0 + rwv[0][kt][1]));
                float p2 = EXP2F(C1 * z[2] + (rhc0 + rwv[0][kt][2]));
                float p3 = EXP2F(C1 * z[3] + (rhc0 + rwv[0][kt][3]));
                pkk[0][kt * 2]     = pack_trunc(p0, p1);
                pkk[0][kt * 2 + 1] = pack_trunc(p2, p3);
            }
            {
                float4v z = (float4v){0.f, 0.f, 0.f, 0.f};
                z = __builtin_amdgcn_mfma_f32_16x16x32_bf16(ka0, qb[1][0], z, 0, 0, 0);
                z = __builtin_amdgcn_mfma_f32_16x16x32_bf16(ka1, qb[1][1], z, 0, 0, 0);
                float p0 = EXP2F(C1 * z[0] + (rhc1 + rwv[1][kt][0]));
                float p1 = EXP2F(C1 * z[1] + (rhc1 + rwv[1][kt][1]));
                float p2 = EXP2F(C1 * z[2] + (rhc1 + rwv[1][kt][2]));
                float p3 = EXP2F(C1 * z[3] + (rhc1 + rwv[1][kt][3]));
                pkk[1][kt * 2]     = pack_trunc(p0, p1);
                pkk[1][kt * 2 + 1] = pack_trunc(p2, p3);
            }
        }
        const short8 pb00 = u4_to_s8(pkk[0][0], pkk[0][1], pkk[0][2], pkk[0][3]);
        const short8 pb01 = u4_to_s8(pkk[0][4], pkk[0][5], pkk[0][6], pkk[0][7]);
        const short8 pb10 = u4_to_s8(pkk[1][0], pkk[1][1], pkk[1][2], pkk[1][3]);
        const short8 pb11 = u4_to_s8(pkk[1][4], pkk[1][5], pkk[1][6], pkk[1][7]);

        // ---- PV from V regs (T5 setprio); no mid-step barrier ----
        __builtin_amdgcn_s_setprio(1);
#pragma unroll
        for (int dt = 0; dt < 4; ++dt) {
            od[0][dt] = __builtin_amdgcn_mfma_f32_16x16x32_bf16(vfr[dt*2],   pb00, od[0][dt], 0, 0, 0);
            od[0][dt] = __builtin_amdgcn_mfma_f32_16x16x32_bf16(vfr[dt*2+1], pb01, od[0][dt], 0, 0, 0);
            od[1][dt] = __builtin_amdgcn_mfma_f32_16x16x32_bf16(vfr[dt*2],   pb10, od[1][dt], 0, 0, 0);
            od[1][dt] = __builtin_amdgcn_mfma_f32_16x16x32_bf16(vfr[dt*2+1], pb11, od[1][dt], 0, 0, 0);
        }
        dq0 = __builtin_amdgcn_mfma_f32_16x16x32_bf16(aones, pb00, dq0, 0, 0, 0);
        dq0 = __builtin_amdgcn_mfma_f32_16x16x32_bf16(aones, pb01, dq0, 0, 0, 0);
        dq1 = __builtin_amdgcn_mfma_f32_16x16x32_bf16(aones, pb10, dq1, 0, 0, 0);
        dq1 = __builtin_amdgcn_mfma_f32_16x16x32_bf16(aones, pb11, dq1, 0, 0, 0);
        __builtin_amdgcn_s_setprio(0);

        if (t < 31) {
            rhc0 = b2f(rhn0);
            rhc1 = b2f(rhn1);
        }
        __syncthreads();   // K reads of buf cur done; K-DMA of buf^1 landed
    }

    // ---- cross-pair combine (overlays the K region; all K reads done) ----
    float* cf = (float*)lds_s;   // comb: [qh][qt][dt][16][16] floats; dq at 4096
    if (ph == 1) {
#pragma unroll
        for (int qt = 0; qt < 2; ++qt)
#pragma unroll
            for (int dt = 0; dt < 4; ++dt) {
                float* dst = &cf[((((qh * 2 + qt) * 4 + dt) * 16) + quad * 4) * 16 + l15];
#pragma unroll
                for (int r = 0; r < 4; ++r) dst[r * 16] = od[qt][dt][r];
            }
        if (quad == 0) {
            cf[4096 + (qh * 2 + 0) * 16 + l15] = dq0[0];
            cf[4096 + (qh * 2 + 1) * 16 + l15] = dq1[0];
        }
    }
    __syncthreads();
    if (ph == 0) {
#pragma unroll
        for (int qt = 0; qt < 2; ++qt) {
            const float dtot = ((qt == 0) ? dq0[0] : dq1[0])
                             + cf[4096 + (qh * 2 + qt) * 16 + l15];
            const float inv = 1.f / dtot;
            short* outp = attn_b + (size_t)(s0 + qh * 32 + qt * 16 + l15) * CDIM + head * HD;
#pragma unroll
            for (int dt = 0; dt < 4; ++dt) {
                const float* src = &cf[((((qh * 2 + qt) * 4 + dt) * 16) + quad * 4) * 16 + l15];
                short4v o4;
#pragma unroll
                for (int r = 0; r < 4; ++r)
                    o4[r] = f2b((od[qt][dt][r] + src[r * 16]) * inv);
                *(short4v*)(outp + dt * 16 + quad * 4) = o4;
            }
        }
    }
}

// ---------------------------------------------------------------------------
extern "C" void kernel_launch(void* const* d_in, const int* in_sizes, int n_in,
                              void* d_out, int out_size, void* d_ws, size_t ws_size,
                              hipStream_t stream)
{
    const float* x    = (const float*)d_in[0];
    const float* qkvw = (const float*)d_in[1];
    const float* qkvb = (const float*)d_in[2];
    const float* rph  = (const float*)d_in[3];
    const float* rpw  = (const float*)d_in[4];
    const float* pw   = (const float*)d_in[5];
    const float* pb   = (const float*)d_in[6];
    float* out = (float*)d_out;

    // ws layout (shorts), total ~48.8 MB
    const size_t HSD = (size_t)NH * S_TOK * HD;   // 3,145,728
    short* xb     = (short*)d_ws;                 // 4096*768
    short* wt     = xb + (size_t)S_TOK * CDIM;    // 2304*768 (qkv_w^T)
    short* pwt    = wt + (size_t)N3C * CDIM;      // 768*768  (proj_w^T)
    short* Qb     = pwt + (size_t)CDIM * CDIM;
    short* Kb     = Qb + HSD;
    short* Vt     = Kb + HSD;
    short* RelhT  = Vt + HSD;                     // [head][ky][s]
    short* Relw   = RelhT + HSD;
    short* attn_b = Relw + HSD;                   // 4096*768

    cast_bf16_kernel<<<S_TOK * CDIM / 4 / 256, 256, 0, stream>>>(x, xb, S_TOK * CDIM / 4);
    transpose_cast_kernel<<<dim3(N3C / 64, CDIM / 64), 256, 0, stream>>>(qkvw, wt, CDIM, N3C);
    transpose_cast_kernel<<<dim3(CDIM / 64, CDIM / 64), 256, 0, stream>>>(pw, pwt, CDIM, CDIM);

    gemm_qkv_mfma<<<dim3(N3C / 128, S_TOK / 128), 256, 0, stream>>>(
        xb, wt, qkvb, Qb, Kb, Vt);
    rel_mfma_kernel<<<dim3(64, NH), 256, 0, stream>>>(Qb, rph, rpw, RelhT, Relw);
    flash_kernel<<<dim3(64 * NH), 256, 0, stream>>>(Qb, Kb, Vt, RelhT, Relw, attn_b);
    gemm_proj_mfma<<<dim3(CDIM / 128, S_TOK / 128), 256, 0, stream>>>(
        attn_b, pwt, pb, out);
}

// Round 8
// 250.891 us; speedup vs baseline: 1.2289x; 1.0125x over previous
//
#include <hip/hip_runtime.h>
#include <hip/hip_bf16.h>

// Problem constants (B=1, H=W=64, C=768, nh=12, hd=64)
#define S_TOK 4096
#define CDIM  768
#define N3C   2304
#define NH    12
#define HD    64

#define LOG2E 1.44269504f

typedef __attribute__((ext_vector_type(8))) short short8;
typedef __attribute__((ext_vector_type(4))) short short4v;
typedef __attribute__((ext_vector_type(4))) float float4v;
typedef __attribute__((ext_vector_type(4))) unsigned uint4v;

__device__ __forceinline__ float b2f(short s) {
    return __uint_as_float(((unsigned)(unsigned short)s) << 16);
}
__device__ __forceinline__ short f2b(float f) {   // round-to-nearest-even
    unsigned u = __float_as_uint(f);
    unsigned r = (u + 0x7FFFu + ((u >> 16) & 1u)) >> 16;
    return (short)r;
}

#if __has_builtin(__builtin_amdgcn_exp2f)
#define EXP2F __builtin_amdgcn_exp2f
#else
#define EXP2F exp2f
#endif

// pack trunc-bf16(a) into low short, trunc-bf16(b) into high short
__device__ __forceinline__ unsigned pack_trunc(float a, float b) {
    return __builtin_amdgcn_perm(__float_as_uint(b), __float_as_uint(a), 0x07060302u);
}

__device__ __forceinline__ short8 u4_to_s8(unsigned a, unsigned b, unsigned c, unsigned d) {
    union { uint4v u; short8 s; } t;
    t.u = (uint4v){a, b, c, d};
    return t.s;
}

// async global->LDS DMA, 16B per lane, dest = ldsbase + lane*16 (linear)
__device__ __forceinline__ void load_lds16(const void* g, void* l) {
    __builtin_amdgcn_global_load_lds(
        (const __attribute__((address_space(1))) unsigned int*)g,
        (__attribute__((address_space(3))) unsigned int*)l, 16, 0, 0);
}

// ---------------------------------------------------------------------------
// Elementwise fp32 -> bf16 cast (4 elems/thread)
// ---------------------------------------------------------------------------
__global__ __launch_bounds__(256) void cast_bf16_kernel(
    const float* __restrict__ in, short* __restrict__ out, int n4)
{
    int i = blockIdx.x * 256 + threadIdx.x;
    if (i >= n4) return;
    float4 v = ((const float4*)in)[i];
    short4v o4 = { f2b(v.x), f2b(v.y), f2b(v.z), f2b(v.w) };
    *(short4v*)&out[(size_t)i * 4] = o4;
}

// ---------------------------------------------------------------------------
// Transpose + cast: in fp32 [R][C] -> out bf16 [C][R]. 64x64 tiles, 256 thr.
// ---------------------------------------------------------------------------
__global__ __launch_bounds__(256) void transpose_cast_kernel(
    const float* __restrict__ in, short* __restrict__ out, int R, int C)
{
    __shared__ float t[64][65];
    const int tid = threadIdx.x;
    const int c0 = blockIdx.x * 64, r0 = blockIdx.y * 64;
    const int li = tid >> 6;      // 0..3
    const int lj = tid & 63;
#pragma unroll
    for (int p = 0; p < 16; ++p) {
        int i = p * 4 + li;
        t[i][lj] = in[(size_t)(r0 + i) * C + c0 + lj];
    }
    __syncthreads();
#pragma unroll
    for (int p = 0; p < 16; ++p) {
        int i = p * 4 + li;
        out[(size_t)(c0 + i) * R + r0 + lj] = f2b(t[lj][i]);
    }
}

// ---------------------------------------------------------------------------
// MFMA GEMM core v2: C[128x128] = A[128xK] @ Bt[128xK]^T
//   Staging via global_load_lds; linear LDS dest, inverse swizzle folded into
//   the per-lane GLOBAL source address; frag reads apply the same XOR.
//   smem is a single 32 KB block so epilogues can overlay it.
// ---------------------------------------------------------------------------
#define GEMM_CORE(A_, Bt_)                                                     \
    __shared__ __align__(16) short smem[2][128][64];                           \
    auto a_s = smem[0];                                                        \
    auto b_s = smem[1];                                                        \
    const int tid  = threadIdx.x;                                              \
    const int m0 = blockIdx.y * 128;                                           \
    const int n0 = blockIdx.x * 128;                                           \
    const int lane = tid & 63, w = tid >> 6;                                   \
    const int l15 = lane & 15, quad = lane >> 4;                               \
    const int wr = w >> 1, wc = w & 1;                                         \
    const int roff0 = (quad ^ (l15 & 7)) << 4;                                 \
    const int roff1 = roff0 ^ 64;                                              \
    const int srow0 = w * 8 + (lane >> 3);                                     \
    const int sslot = (lane & 7) ^ ((lane >> 3) & 7);                          \
    const short* ga = A_ + (size_t)(m0 + srow0) * 768 + sslot * 8;             \
    const short* gb = Bt_ + (size_t)(n0 + srow0) * 768 + sslot * 8;            \
    short* la = &a_s[w * 8][0];                                                \
    short* lb = &b_s[w * 8][0];                                                \
    float4v acc[4][4];                                                         \
    _Pragma("unroll")                                                          \
    for (int i = 0; i < 4; ++i)                                                \
        _Pragma("unroll")                                                      \
        for (int j = 0; j < 4; ++j) acc[i][j] = (float4v){0.f,0.f,0.f,0.f};    \
    for (int k0 = 0; k0 < 768; k0 += 64) {                                     \
        __syncthreads();                                                       \
        _Pragma("unroll")                                                      \
        for (int i = 0; i < 4; ++i) {                                          \
            load_lds16(ga + (size_t)i * (32 * 768) + k0, la + i * 32 * 64);    \
            load_lds16(gb + (size_t)i * (32 * 768) + k0, lb + i * 32 * 64);    \
        }                                                                      \
        __syncthreads();                                                       \
        _Pragma("unroll")                                                      \
        for (int kk = 0; kk < 64; kk += 32) {                                  \
            const int roff = kk ? roff1 : roff0;                               \
            short8 af[4], bfr[4];                                              \
            _Pragma("unroll")                                                  \
            for (int i = 0; i < 4; ++i)                                        \
                af[i] = *(const short8*)((const char*)&a_s[wr*64 + i*16 + l15][0] + roff); \
            _Pragma("unroll")                                                  \
            for (int j = 0; j < 4; ++j)                                        \
                bfr[j] = *(const short8*)((const char*)&b_s[wc*64 + j*16 + l15][0] + roff); \
            _Pragma("unroll")                                                  \
            for (int i = 0; i < 4; ++i)                                        \
                _Pragma("unroll")                                              \
                for (int j = 0; j < 4; ++j)                                    \
                    acc[i][j] = __builtin_amdgcn_mfma_f32_16x16x32_bf16(       \
                        af[i], bfr[j], acc[i][j], 0, 0, 0);                    \
        }                                                                      \
    }

// QKV GEMM: writes Qb[head][s][d], Kb[head][s][d], Vt[head][d][s] (bf16)
// Epilogue: stage output tile in LDS, then fully-coalesced 16B stores.
__global__ __launch_bounds__(256) void gemm_qkv_mfma(
    const short* __restrict__ A, const short* __restrict__ Bt,
    const float* __restrict__ bias,
    short* __restrict__ Qb, short* __restrict__ Kb, short* __restrict__ Vt)
{
    GEMM_CORE(A, Bt)

    const int sec = n0 / CDIM;      // tile fully inside one of q/k/v
    float bj[4];
#pragma unroll
    for (int j = 0; j < 4; ++j) bj[j] = bias[n0 + wc*64 + j*16 + l15];

    if (sec < 2) {
        short* base = (sec == 0) ? Qb : Kb;
        short (*tile)[68] = (short(*)[68])&smem[0][0][0];   // 128x68 = 17408 B
#pragma unroll
        for (int h = 0; h < 2; ++h) {
            __syncthreads();
            if (wc == h) {
#pragma unroll
                for (int i = 0; i < 4; ++i)
#pragma unroll
                    for (int j = 0; j < 4; ++j)
#pragma unroll
                        for (int r = 0; r < 4; ++r)
                            tile[wr*64 + i*16 + quad*4 + r][j*16 + l15] =
                                f2b(acc[i][j][r] + bj[j]);
            }
            __syncthreads();
            const int nn = (n0 % CDIM) + h * 64;
            const int head = nn >> 6;
            short* dst = base + ((size_t)head * S_TOK + m0) * HD;
#pragma unroll
            for (int it = 0; it < 4; ++it) {
                const int row = it * 32 + (tid >> 3), c = (tid & 7) * 8;
                *(short8*)&dst[(size_t)row * HD + c] = *(const short8*)&tile[row][c];
            }
        }
    } else {
        short (*tv)[130] = (short(*)[130])&smem[0][0][0];   // 64x130 = 16640 B
#pragma unroll
        for (int h = 0; h < 2; ++h) {
            __syncthreads();
            if (wc == h) {
#pragma unroll
                for (int i = 0; i < 4; ++i)
#pragma unroll
                    for (int j = 0; j < 4; ++j) {
                        short4v v4;
#pragma unroll
                        for (int r = 0; r < 4; ++r) v4[r] = f2b(acc[i][j][r] + bj[j]);
                        *(short4v*)&tv[j*16 + l15][wr*64 + i*16 + quad*4] = v4;
                    }
            }
            __syncthreads();
            const int nn = (n0 % CDIM) + h * 64;
            const int head = nn >> 6;
            short* dst = Vt + (size_t)head * HD * S_TOK + m0;
#pragma unroll
            for (int it = 0; it < 4; ++it) {
                const int nr = it * 16 + (tid >> 4), sc = (tid & 15) * 8;
                *(short8*)&dst[(size_t)nr * S_TOK + sc] = *(const short8*)&tv[nr][sc];
            }
        }
    }
}

// Proj GEMM: out fp32 [4096][768] = A @ Bt^T + bias
// Epilogue: LDS float tile (XOR chunk swizzle), coalesced float4 stores.
__global__ __launch_bounds__(256) void gemm_proj_mfma(
    const short* __restrict__ A, const short* __restrict__ Bt,
    const float* __restrict__ bias, float* __restrict__ out)
{
    GEMM_CORE(A, Bt)

    float bj[4];
#pragma unroll
    for (int j = 0; j < 4; ++j) bj[j] = bias[n0 + wc*64 + j*16 + l15];

    float* tf = (float*)&smem[0][0][0];   // [64][128] floats, chunk-XOR layout
#pragma unroll
    for (int h = 0; h < 2; ++h) {
        __syncthreads();
        if (wr == h) {
#pragma unroll
            for (int i = 0; i < 4; ++i)
#pragma unroll
                for (int j = 0; j < 4; ++j) {
                    const int cc = wc*16 + j*4 + (l15 >> 2);   // float4-chunk idx
                    const int ci = l15 & 3;
#pragma unroll
                    for (int r = 0; r < 4; ++r) {
                        const int row = i*16 + quad*4 + r;
                        const int pc = cc ^ ((row & 7) << 2);
                        tf[row * 128 + pc * 4 + ci] = acc[i][j][r] + bj[j];
                    }
                }
        }
        __syncthreads();
        float* dst = out + (size_t)(m0 + h * 64) * CDIM + n0;
#pragma unroll
        for (int it = 0; it < 8; ++it) {
            const int row = it * 8 + (tid >> 5);
            const int gc = tid & 31;
            const int pc = gc ^ ((row & 7) << 2);
            float4 v = *(const float4*)&tf[row * 128 + pc * 4];
            *(float4*)&dst[(size_t)row * CDIM + gc * 4] = v;
        }
    }
}

// ---------------------------------------------------------------------------
// Rel-pos tables via MFMA. One block per (y, head); 64 queries s0=y*64..+63.
// Outputs PRE-SCALED by log2e. Relh stored TRANSPOSED: RelhT[head][ky][s].
// ---------------------------------------------------------------------------
__global__ __launch_bounds__(256) void rel_mfma_kernel(
    const short* __restrict__ Qb, const float* __restrict__ rph,
    const float* __restrict__ rpw, short* __restrict__ RelhT,
    short* __restrict__ Relw)
{
    __shared__ __align__(16) short q_s [64][72];
    __shared__ __align__(16) short rh_s[64][72];
    __shared__ __align__(16) short rw_s[128][72];

    const int tid  = threadIdx.x;
    const int y    = blockIdx.x;
    const int head = blockIdx.y;
    const int s0   = y * 64;
    const int w = tid >> 6, lane = tid & 63;
    const int l15 = lane & 15, quad = lane >> 4;
    const int srow = tid >> 2;            // 0..63
    const int scol = (tid & 3) << 4;      // 0,16,32,48

    // ---- stage Q (bf16 passthrough) ----
    {
        const uint4* g = (const uint4*)(Qb + ((size_t)head * S_TOK + s0 + srow) * HD + scol);
        *(uint4*)&q_s[srow][scol]     = g[0];
        *(uint4*)&q_s[srow][scol + 8] = g[1];
    }
    // ---- stage rph rows y..y+63 (fp32 -> bf16) ----
    {
        const float* g = rph + (size_t)(y + srow) * HD + scol;
        short tmp[16];
#pragma unroll
        for (int i = 0; i < 16; i += 4) {
            float4 v = *(const float4*)(g + i);
            tmp[i] = f2b(v.x); tmp[i+1] = f2b(v.y); tmp[i+2] = f2b(v.z); tmp[i+3] = f2b(v.w);
        }
        *(short8*)&rh_s[srow][scol]     = *(short8*)&tmp[0];
        *(short8*)&rh_s[srow][scol + 8] = *(short8*)&tmp[8];
    }
    // ---- stage rpw rows 0..127 (row 127 clamped; never consumed) ----
#pragma unroll
    for (int half = 0; half < 2; ++half) {
        const int row = srow + half * 64;
        const int rr  = row > 126 ? 126 : row;
        const float* g = rpw + (size_t)rr * HD + scol;
        short tmp[16];
#pragma unroll
        for (int i = 0; i < 16; i += 4) {
            float4 v = *(const float4*)(g + i);
            tmp[i] = f2b(v.x); tmp[i+1] = f2b(v.y); tmp[i+2] = f2b(v.z); tmp[i+3] = f2b(v.w);
        }
        *(short8*)&rw_s[row][scol]     = *(short8*)&tmp[0];
        *(short8*)&rw_s[row][scol + 8] = *(short8*)&tmp[8];
    }
    __syncthreads();

    const short8 qa0 = *(const short8*)&q_s[w * 16 + l15][quad * 8];
    const short8 qa1 = *(const short8*)&q_s[w * 16 + l15][32 + quad * 8];

    // ---- relh: RH col j = y+jj, ky = 63-jj; transposed short4v stores ----
#pragma unroll
    for (int ct = 0; ct < 4; ++ct) {
        const int jj = ct * 16 + l15;
        short8 b0 = *(const short8*)&rh_s[jj][quad * 8];
        short8 b1 = *(const short8*)&rh_s[jj][32 + quad * 8];
        float4v z = (float4v){0.f, 0.f, 0.f, 0.f};
        z = __builtin_amdgcn_mfma_f32_16x16x32_bf16(qa0, b0, z, 0, 0, 0);
        z = __builtin_amdgcn_mfma_f32_16x16x32_bf16(qa1, b1, z, 0, 0, 0);
        const int ky = 63 - jj;
        short4v o4;
#pragma unroll
        for (int r = 0; r < 4; ++r) o4[r] = f2b(z[r] * LOG2E);
        *(short4v*)&RelhT[((size_t)head * HD + ky) * S_TOK + s0 + w * 16 + quad * 4] = o4;
    }

    // ---- relw: kx = q+63-j, keep 0<=kx<64 ----
#pragma unroll
    for (int ct = 0; ct < 8; ++ct) {
        const int j = ct * 16 + l15;
        short8 b0 = *(const short8*)&rw_s[j][quad * 8];
        short8 b1 = *(const short8*)&rw_s[j][32 + quad * 8];
        float4v z = (float4v){0.f, 0.f, 0.f, 0.f};
        z = __builtin_amdgcn_mfma_f32_16x16x32_bf16(qa0, b0, z, 0, 0, 0);
        z = __builtin_amdgcn_mfma_f32_16x16x32_bf16(qa1, b1, z, 0, 0, 0);
#pragma unroll
        for (int r = 0; r < 4; ++r) {
            const int q  = w * 16 + quad * 4 + r;
            const int kx = q + 63 - j;
            if (kx >= 0 && kx < 64)
                Relw[((size_t)head * S_TOK + s0 + q) * HD + kx] = f2b(z[r] * LOG2E);
        }
    }
}

// ---------------------------------------------------------------------------
// Flash attention v11 = v10 with register pressure halved (spill fix).
//   v10's WRITE_SIZE showed ~11.5 MB of scratch: vfr[8] (+32 live VGPRs) +
//   pkk (+16) pushed the wave state past what the allocator tolerated.
//   v11: SPLIT-PV pipeline -- load half the V frags (4 named short8, 16
//   regs), S-tiles 0,1 -> pb00/pb10, PV-A consumes them; then load half-B,
//   S-tiles 2,3 -> PV-B. rwv compressed to bf16 (16 regs, shift at use).
//   All V frags are named scalars. Everything else identical to v10:
//   V direct global->VGPR (L2-resident via XCD head-group swizzle), K-only
//   32 KB LDS double-buffer, one barrier/step, 12 waves/CU.
// ---------------------------------------------------------------------------
__global__ __launch_bounds__(256, 3) void flash_kernel(
    const short* __restrict__ Qb, const short* __restrict__ Kb,
    const short* __restrict__ Vt, const short* __restrict__ RelhT,
    const short* __restrict__ Relw, short* __restrict__ attn_b)
{
    // K[pair][buf][64][64] shorts = 32 KB
    __shared__ __align__(16) short lds_s[16384];

    const int tid  = threadIdx.x;
    const int bid  = blockIdx.x;
    const int logi = (bid & 7) * 96 + (bid >> 3);   // XCD head-grouping swizzle
    const int head = logi >> 6;
    const int s0   = (logi & 63) << 6;
    const int w    = tid >> 6, lane = tid & 63;
    const int l15  = lane & 15, quad = lane >> 4;
    const int ph   = w >> 1;          // key-chunk half: chunks ph*32 + t
    const int qh   = w & 1;           // query half: queries qh*32 + ...

    const float C1 = 0.125f * LOG2E;

    // ---- K staging lane mapping (linear dest, pre-swizzled source) ----
    const int lj = lane >> 3;             // row within 8-row DMA group
    const int sl = (lane & 7) ^ lj;       // logical 16B slot this lane fetches
    const int kf0 = (lj & 3) + ((lj & 4) << 1) + qh * 32;  // permuted key, ii=0

    const short* pK0 = Kb + (size_t)head * S_TOK * HD
                     + (size_t)(ph * 32 * 64 + kf0) * HD + sl * 8;

    // named double-buffer pointers (ternary select only; no runtime arrays)
    short* lk0 = &lds_s[(ph*2 + 0) << 12] + qh*32*64;
    short* lk1 = &lds_s[(ph*2 + 1) << 12] + qh*32*64;
    const short* krd0 = &lds_s[(ph*2 + 0) << 12];
    const short* krd1 = &lds_s[(ph*2 + 1) << 12];

    // swizzled read byte-offsets (row&7 == l15&7 for all frag rows)
    const int roff0 = (quad ^ (l15 & 7)) << 4;   // logical slot quad
    const int roff1 = roff0 ^ 64;                // logical slot 4+quad

    // ---- V direct-global base (natural keys) ----
    const short* vb = Vt + ((size_t)head * HD + l15) * S_TOK
                    + ph * 32 * 64 + quad * 8;

    // ---- Q B-frags: 2 q-tiles (32 queries per wave) ----
    short8 qb[2][2];
#pragma unroll
    for (int qt = 0; qt < 2; ++qt) {
        const short* qrow = Qb + ((size_t)head * S_TOK + s0 + qh * 32 + qt * 16 + l15) * HD;
        qb[qt][0] = *(const short8*)(qrow + quad * 8);
        qb[qt][1] = *(const short8*)(qrow + 32 + quad * 8);
    }

    // ---- relw invariants kept as bf16 (16 VGPRs): rws[qt][kt][r] ----
    short4v rws[2][4];
#pragma unroll
    for (int qt = 0; qt < 2; ++qt) {
        const short* rwrow = Relw + ((size_t)head * S_TOK + s0 + qh * 32 + qt * 16 + l15) * HD;
#pragma unroll
        for (int kt = 0; kt < 4; ++kt) {
            const int base = ((kt & 1) << 2) | ((kt >> 1) << 5);
            rws[qt][kt] = *(const short4v*)(rwrow + base + quad * 8);
        }
    }

    // RelhT[head][ky][s]: per-chunk coalesced loads (ky == chunk index)
    const short* rhbase = RelhT + (size_t)head * HD * S_TOK + s0 + qh * 32 + l15;
    float rhc0 = b2f(rhbase[(size_t)(ph * 32) * S_TOK]);
    float rhc1 = b2f(rhbase[(size_t)(ph * 32) * S_TOK + 16]);

    // ones A-frag for the denominator
    short8 aones;
#pragma unroll
    for (int j = 0; j < 8; ++j) aones[j] = (short)0x3F80;

    float4v od[2][4];
#pragma unroll
    for (int qt = 0; qt < 2; ++qt)
#pragma unroll
        for (int dt = 0; dt < 4; ++dt) od[qt][dt] = (float4v){0.f, 0.f, 0.f, 0.f};
    float4v dq0 = (float4v){0.f, 0.f, 0.f, 0.f};
    float4v dq1 = (float4v){0.f, 0.f, 0.f, 0.f};

    // ---- prologue: DMA K chunk (ph*32) into buf0 ----
    load_lds16(pK0,        lk0);
    load_lds16(pK0 + 1024, lk0 + 8  * 64);
    load_lds16(pK0 + 256,  lk0 + 16 * 64);
    load_lds16(pK0 + 1280, lk0 + 24 * 64);
    __syncthreads();

    for (int t = 0; t < 32; ++t) {
        const int cur = t & 1;
        const short* kc = cur ? krd1 : krd0;
        short* lkn = cur ? lk0 : lk1;
        const short* vt0 = vb + t * 64;

        // ---- V half-A loads (keys quad*8+0..7): 4 named short8 ----
        short8 vfA0 = *(const short8*)(vt0);
        short8 vfA1 = *(const short8*)(vt0 + 16 * S_TOK);
        short8 vfA2 = *(const short8*)(vt0 + 32 * S_TOK);
        short8 vfA3 = *(const short8*)(vt0 + 48 * S_TOK);

        // ---- K(t+1) DMA into the other buffer + rh prefetch ----
        short rhn0, rhn1;
        if (t < 31) {
            const short* gk = pK0 + (size_t)(t + 1) * 4096;
            load_lds16(gk,        lkn);
            load_lds16(gk + 1024, lkn + 8  * 64);
            load_lds16(gk + 256,  lkn + 16 * 64);
            load_lds16(gk + 1280, lkn + 24 * 64);
            rhn0 = rhbase[(size_t)(ph * 32 + t + 1) * S_TOK];
            rhn1 = rhbase[(size_t)(ph * 32 + t + 1) * S_TOK + 16];
        }

        // ---- S tiles 0,1 -> pb00 (qt0), pb10 (qt1) ----
        unsigned pa0[4], pa1[4];
#pragma unroll
        for (int kt = 0; kt < 2; ++kt) {
            const char* krp = (const char*)(kc + (kt * 16 + l15) * 64);
            const short8 ka0 = *(const short8*)(krp + roff0);
            const short8 ka1 = *(const short8*)(krp + roff1);
            {
                float4v z = (float4v){0.f, 0.f, 0.f, 0.f};
                z = __builtin_amdgcn_mfma_f32_16x16x32_bf16(ka0, qb[0][0], z, 0, 0, 0);
                z = __builtin_amdgcn_mfma_f32_16x16x32_bf16(ka1, qb[0][1], z, 0, 0, 0);
                float p0 = EXP2F(C1 * z[0] + (rhc0 + b2f(rws[0][kt][0])));
                float p1 = EXP2F(C1 * z[1] + (rhc0 + b2f(rws[0][kt][1])));
                float p2 = EXP2F(C1 * z[2] + (rhc0 + b2f(rws[0][kt][2])));
                float p3 = EXP2F(C1 * z[3] + (rhc0 + b2f(rws[0][kt][3])));
                pa0[kt * 2]     = pack_trunc(p0, p1);
                pa0[kt * 2 + 1] = pack_trunc(p2, p3);
            }
            {
                float4v z = (float4v){0.f, 0.f, 0.f, 0.f};
                z = __builtin_amdgcn_mfma_f32_16x16x32_bf16(ka0, qb[1][0], z, 0, 0, 0);
                z = __builtin_amdgcn_mfma_f32_16x16x32_bf16(ka1, qb[1][1], z, 0, 0, 0);
                float p0 = EXP2F(C1 * z[0] + (rhc1 + b2f(rws[1][kt][0])));
                float p1 = EXP2F(C1 * z[1] + (rhc1 + b2f(rws[1][kt][1])));
                float p2 = EXP2F(C1 * z[2] + (rhc1 + b2f(rws[1][kt][2])));
                float p3 = EXP2F(C1 * z[3] + (rhc1 + b2f(rws[1][kt][3])));
                pa1[kt * 2]     = pack_trunc(p0, p1);
                pa1[kt * 2 + 1] = pack_trunc(p2, p3);
            }
        }
        const short8 pb00 = u4_to_s8(pa0[0], pa0[1], pa0[2], pa0[3]);
        const short8 pb10 = u4_to_s8(pa1[0], pa1[1], pa1[2], pa1[3]);

        // ---- PV-A (consumes vfA*, pb00/pb10) ----
        __builtin_amdgcn_s_setprio(1);
        od[0][0] = __builtin_amdgcn_mfma_f32_16x16x32_bf16(vfA0, pb00, od[0][0], 0, 0, 0);
        od[0][1] = __builtin_amdgcn_mfma_f32_16x16x32_bf16(vfA1, pb00, od[0][1], 0, 0, 0);
        od[0][2] = __builtin_amdgcn_mfma_f32_16x16x32_bf16(vfA2, pb00, od[0][2], 0, 0, 0);
        od[0][3] = __builtin_amdgcn_mfma_f32_16x16x32_bf16(vfA3, pb00, od[0][3], 0, 0, 0);
        od[1][0] = __builtin_amdgcn_mfma_f32_16x16x32_bf16(vfA0, pb10, od[1][0], 0, 0, 0);
        od[1][1] = __builtin_amdgcn_mfma_f32_16x16x32_bf16(vfA1, pb10, od[1][1], 0, 0, 0);
        od[1][2] = __builtin_amdgcn_mfma_f32_16x16x32_bf16(vfA2, pb10, od[1][2], 0, 0, 0);
        od[1][3] = __builtin_amdgcn_mfma_f32_16x16x32_bf16(vfA3, pb10, od[1][3], 0, 0, 0);
        dq0 = __builtin_amdgcn_mfma_f32_16x16x32_bf16(aones, pb00, dq0, 0, 0, 0);
        dq1 = __builtin_amdgcn_mfma_f32_16x16x32_bf16(aones, pb10, dq1, 0, 0, 0);
        __builtin_amdgcn_s_setprio(0);

        // ---- V half-B loads (keys 32+quad*8+0..7) ----
        short8 vfB0 = *(const short8*)(vt0 + 32);
        short8 vfB1 = *(const short8*)(vt0 + 16 * S_TOK + 32);
        short8 vfB2 = *(const short8*)(vt0 + 32 * S_TOK + 32);
        short8 vfB3 = *(const short8*)(vt0 + 48 * S_TOK + 32);

        // ---- S tiles 2,3 -> pb01, pb11 ----
#pragma unroll
        for (int kt = 2; kt < 4; ++kt) {
            const char* krp = (const char*)(kc + (kt * 16 + l15) * 64);
            const short8 ka0 = *(const short8*)(krp + roff0);
            const short8 ka1 = *(const short8*)(krp + roff1);
            {
                float4v z = (float4v){0.f, 0.f, 0.f, 0.f};
                z = __builtin_amdgcn_mfma_f32_16x16x32_bf16(ka0, qb[0][0], z, 0, 0, 0);
                z = __builtin_amdgcn_mfma_f32_16x16x32_bf16(ka1, qb[0][1], z, 0, 0, 0);
                float p0 = EXP2F(C1 * z[0] + (rhc0 + b2f(rws[0][kt][0])));
                float p1 = EXP2F(C1 * z[1] + (rhc0 + b2f(rws[0][kt][1])));
                float p2 = EXP2F(C1 * z[2] + (rhc0 + b2f(rws[0][kt][2])));
                float p3 = EXP2F(C1 * z[3] + (rhc0 + b2f(rws[0][kt][3])));
                pa0[(kt - 2) * 2]     = pack_trunc(p0, p1);
                pa0[(kt - 2) * 2 + 1] = pack_trunc(p2, p3);
            }
            {
                float4v z = (float4v){0.f, 0.f, 0.f, 0.f};
                z = __builtin_amdgcn_mfma_f32_16x16x32_bf16(ka0, qb[1][0], z, 0, 0, 0);
                z = __builtin_amdgcn_mfma_f32_16x16x32_bf16(ka1, qb[1][1], z, 0, 0, 0);
                float p0 = EXP2F(C1 * z[0] + (rhc1 + b2f(rws[1][kt][0])));
                float p1 = EXP2F(C1 * z[1] + (rhc1 + b2f(rws[1][kt][1])));
                float p2 = EXP2F(C1 * z[2] + (rhc1 + b2f(rws[1][kt][2])));
                float p3 = EXP2F(C1 * z[3] + (rhc1 + b2f(rws[1][kt][3])));
                pa1[(kt - 2) * 2]     = pack_trunc(p0, p1);
                pa1[(kt - 2) * 2 + 1] = pack_trunc(p2, p3);
            }
        }
        const short8 pb01 = u4_to_s8(pa0[0], pa0[1], pa0[2], pa0[3]);
        const short8 pb11 = u4_to_s8(pa1[0], pa1[1], pa1[2], pa1[3]);

        // ---- PV-B ----
        __builtin_amdgcn_s_setprio(1);
        od[0][0] = __builtin_amdgcn_mfma_f32_16x16x32_bf16(vfB0, pb01, od[0][0], 0, 0, 0);
        od[0][1] = __builtin_amdgcn_mfma_f32_16x16x32_bf16(vfB1, pb01, od[0][1], 0, 0, 0);
        od[0][2] = __builtin_amdgcn_mfma_f32_16x16x32_bf16(vfB2, pb01, od[0][2], 0, 0, 0);
        od[0][3] = __builtin_amdgcn_mfma_f32_16x16x32_bf16(vfB3, pb01, od[0][3], 0, 0, 0);
        od[1][0] = __builtin_amdgcn_mfma_f32_16x16x32_bf16(vfB0, pb11, od[1][0], 0, 0, 0);
        od[1][1] = __builtin_amdgcn_mfma_f32_16x16x32_bf16(vfB1, pb11, od[1][1], 0, 0, 0);
        od[1][2] = __builtin_amdgcn_mfma_f32_16x16x32_bf16(vfB2, pb11, od[1][2], 0, 0, 0);
        od[1][3] = __builtin_amdgcn_mfma_f32_16x16x32_bf16(vfB3, pb11, od[1][3], 0, 0, 0);
        dq0 = __builtin_amdgcn_mfma_f32_16x16x32_bf16(aones, pb01, dq0, 0, 0, 0);
        dq1 = __builtin_amdgcn_mfma_f32_16x16x32_bf16(aones, pb11, dq1, 0, 0, 0);
        __builtin_amdgcn_s_setprio(0);

        if (t < 31) {
            rhc0 = b2f(rhn0);
            rhc1 = b2f(rhn1);
        }
        __syncthreads();   // K reads of buf cur done; K-DMA of buf^1 landed
    }

    // ---- cross-pair combine (overlays the K region; all K reads done) ----
    float* cf = (float*)lds_s;   // comb: [qh][qt][dt][16][16] floats; dq at 4096
    if (ph == 1) {
#pragma unroll
        for (int qt = 0; qt < 2; ++qt)
#pragma unroll
            for (int dt = 0; dt < 4; ++dt) {
                float* dst = &cf[((((qh * 2 + qt) * 4 + dt) * 16) + quad * 4) * 16 + l15];
#pragma unroll
                for (int r = 0; r < 4; ++r) dst[r * 16] = od[qt][dt][r];
            }
        if (quad == 0) {
            cf[4096 + (qh * 2 + 0) * 16 + l15] = dq0[0];
            cf[4096 + (qh * 2 + 1) * 16 + l15] = dq1[0];
        }
    }
    __syncthreads();
    if (ph == 0) {
#pragma unroll
        for (int qt = 0; qt < 2; ++qt) {
            const float dtot = ((qt == 0) ? dq0[0] : dq1[0])
                             + cf[4096 + (qh * 2 + qt) * 16 + l15];
            const float inv = 1.f / dtot;
            short* outp = attn_b + (size_t)(s0 + qh * 32 + qt * 16 + l15) * CDIM + head * HD;
#pragma unroll
            for (int dt = 0; dt < 4; ++dt) {
                const float* src = &cf[((((qh * 2 + qt) * 4 + dt) * 16) + quad * 4) * 16 + l15];
                short4v o4;
#pragma unroll
                for (int r = 0; r < 4; ++r)
                    o4[r] = f2b((od[qt][dt][r] + src[r * 16]) * inv);
                *(short4v*)(outp + dt * 16 + quad * 4) = o4;
            }
        }
    }
}

// ---------------------------------------------------------------------------
extern "C" void kernel_launch(void* const* d_in, const int* in_sizes, int n_in,
                              void* d_out, int out_size, void* d_ws, size_t ws_size,
                              hipStream_t stream)
{
    const float* x    = (const float*)d_in[0];
    const float* qkvw = (const float*)d_in[1];
    const float* qkvb = (const float*)d_in[2];
    const float* rph  = (const float*)d_in[3];
    const float* rpw  = (const float*)d_in[4];
    const float* pw   = (const float*)d_in[5];
    const float* pb   = (const float*)d_in[6];
    float* out = (float*)d_out;

    // ws layout (shorts), total ~48.8 MB
    const size_t HSD = (size_t)NH * S_TOK * HD;   // 3,145,728
    short* xb     = (short*)d_ws;                 // 4096*768
    short* wt     = xb + (size_t)S_TOK * CDIM;    // 2304*768 (qkv_w^T)
    short* pwt    = wt + (size_t)N3C * CDIM;      // 768*768  (proj_w^T)
    short* Qb     = pwt + (size_t)CDIM * CDIM;
    short* Kb     = Qb + HSD;
    short* Vt     = Kb + HSD;
    short* RelhT  = Vt + HSD;                     // [head][ky][s]
    short* Relw   = RelhT + HSD;
    short* attn_b = Relw + HSD;                   // 4096*768

    cast_bf16_kernel<<<S_TOK * CDIM / 4 / 256, 256, 0, stream>>>(x, xb, S_TOK * CDIM / 4);
    transpose_cast_kernel<<<dim3(N3C / 64, CDIM / 64), 256, 0, stream>>>(qkvw, wt, CDIM, N3C);
    transpose_cast_kernel<<<dim3(CDIM / 64, CDIM / 64), 256, 0, stream>>>(pw, pwt, CDIM, CDIM);

    gemm_qkv_mfma<<<dim3(N3C / 128, S_TOK / 128), 256, 0, stream>>>(
        xb, wt, qkvb, Qb, Kb, Vt);
    rel_mfma_kernel<<<dim3(64, NH), 256, 0, stream>>>(Qb, rph, rpw, RelhT, Relw);
    flash_kernel<<<dim3(64 * NH), 256, 0, stream>>>(Qb, Kb, Vt, RelhT, Relw, attn_b);
    gemm_proj_mfma<<<dim3(CDIM / 128, S_TOK / 128), 256, 0, stream>>>(
        attn_b, pwt, pb, out);
}

// Round 9
// 210.588 us; speedup vs baseline: 1.4641x; 1.1914x over previous
//
#include <hip/hip_runtime.h>
#include <hip/hip_bf16.h>

// Problem constants (B=1, H=W=64, C=768, nh=12, hd=64)
#define S_TOK 4096
#define CDIM  768
#define N3C   2304
#define NH    12
#define HD    64

#define LOG2E 1.44269504f

typedef __attribute__((ext_vector_type(8))) short short8;
typedef __attribute__((ext_vector_type(4))) short short4v;
typedef __attribute__((ext_vector_type(4))) float float4v;
typedef __attribute__((ext_vector_type(4))) unsigned uint4v;

__device__ __forceinline__ float b2f(short s) {
    return __uint_as_float(((unsigned)(unsigned short)s) << 16);
}
__device__ __forceinline__ short f2b(float f) {   // round-to-nearest-even
    unsigned u = __float_as_uint(f);
    unsigned r = (u + 0x7FFFu + ((u >> 16) & 1u)) >> 16;
    return (short)r;
}

#if __has_builtin(__builtin_amdgcn_exp2f)
#define EXP2F __builtin_amdgcn_exp2f
#else
#define EXP2F exp2f
#endif

// pack trunc-bf16(a) into low short, trunc-bf16(b) into high short
__device__ __forceinline__ unsigned pack_trunc(float a, float b) {
    return __builtin_amdgcn_perm(__float_as_uint(b), __float_as_uint(a), 0x07060302u);
}

__device__ __forceinline__ short8 u4_to_s8(unsigned a, unsigned b, unsigned c, unsigned d) {
    union { uint4v u; short8 s; } t;
    t.u = (uint4v){a, b, c, d};
    return t.s;
}

// async global->LDS DMA, 16B per lane, dest = ldsbase + lane*16 (linear)
__device__ __forceinline__ void load_lds16(const void* g, void* l) {
    __builtin_amdgcn_global_load_lds(
        (const __attribute__((address_space(1))) unsigned int*)g,
        (__attribute__((address_space(3))) unsigned int*)l, 16, 0, 0);
}

// ---------------------------------------------------------------------------
// Elementwise fp32 -> bf16 cast (4 elems/thread)
// ---------------------------------------------------------------------------
__global__ __launch_bounds__(256) void cast_bf16_kernel(
    const float* __restrict__ in, short* __restrict__ out, int n4)
{
    int i = blockIdx.x * 256 + threadIdx.x;
    if (i >= n4) return;
    float4 v = ((const float4*)in)[i];
    short4v o4 = { f2b(v.x), f2b(v.y), f2b(v.z), f2b(v.w) };
    *(short4v*)&out[(size_t)i * 4] = o4;
}

// ---------------------------------------------------------------------------
// Transpose + cast: in fp32 [R][C] -> out bf16 [C][R]. 64x64 tiles, 256 thr.
// ---------------------------------------------------------------------------
__global__ __launch_bounds__(256) void transpose_cast_kernel(
    const float* __restrict__ in, short* __restrict__ out, int R, int C)
{
    __shared__ float t[64][65];
    const int tid = threadIdx.x;
    const int c0 = blockIdx.x * 64, r0 = blockIdx.y * 64;
    const int li = tid >> 6;      // 0..3
    const int lj = tid & 63;
#pragma unroll
    for (int p = 0; p < 16; ++p) {
        int i = p * 4 + li;
        t[i][lj] = in[(size_t)(r0 + i) * C + c0 + lj];
    }
    __syncthreads();
#pragma unroll
    for (int p = 0; p < 16; ++p) {
        int i = p * 4 + li;
        out[(size_t)(c0 + i) * R + r0 + lj] = f2b(t[lj][i]);
    }
}

// ---------------------------------------------------------------------------
// MFMA GEMM core v2: C[128x128] = A[128xK] @ Bt[128xK]^T
//   Staging via global_load_lds; linear LDS dest, inverse swizzle folded into
//   the per-lane GLOBAL source address; frag reads apply the same XOR.
//   smem is a single 32 KB block so epilogues can overlay it.
// ---------------------------------------------------------------------------
#define GEMM_CORE(A_, Bt_)                                                     \
    __shared__ __align__(16) short smem[2][128][64];                           \
    auto a_s = smem[0];                                                        \
    auto b_s = smem[1];                                                        \
    const int tid  = threadIdx.x;                                              \
    const int m0 = blockIdx.y * 128;                                           \
    const int n0 = blockIdx.x * 128;                                           \
    const int lane = tid & 63, w = tid >> 6;                                   \
    const int l15 = lane & 15, quad = lane >> 4;                               \
    const int wr = w >> 1, wc = w & 1;                                         \
    const int roff0 = (quad ^ (l15 & 7)) << 4;                                 \
    const int roff1 = roff0 ^ 64;                                              \
    const int srow0 = w * 8 + (lane >> 3);                                     \
    const int sslot = (lane & 7) ^ ((lane >> 3) & 7);                          \
    const short* ga = A_ + (size_t)(m0 + srow0) * 768 + sslot * 8;             \
    const short* gb = Bt_ + (size_t)(n0 + srow0) * 768 + sslot * 8;            \
    short* la = &a_s[w * 8][0];                                                \
    short* lb = &b_s[w * 8][0];                                                \
    float4v acc[4][4];                                                         \
    _Pragma("unroll")                                                          \
    for (int i = 0; i < 4; ++i)                                                \
        _Pragma("unroll")                                                      \
        for (int j = 0; j < 4; ++j) acc[i][j] = (float4v){0.f,0.f,0.f,0.f};    \
    for (int k0 = 0; k0 < 768; k0 += 64) {                                     \
        __syncthreads();                                                       \
        _Pragma("unroll")                                                      \
        for (int i = 0; i < 4; ++i) {                                          \
            load_lds16(ga + (size_t)i * (32 * 768) + k0, la + i * 32 * 64);    \
            load_lds16(gb + (size_t)i * (32 * 768) + k0, lb + i * 32 * 64);    \
        }                                                                      \
        __syncthreads();                                                       \
        _Pragma("unroll")                                                      \
        for (int kk = 0; kk < 64; kk += 32) {                                  \
            const int roff = kk ? roff1 : roff0;                               \
            short8 af[4], bfr[4];                                              \
            _Pragma("unroll")                                                  \
            for (int i = 0; i < 4; ++i)                                        \
                af[i] = *(const short8*)((const char*)&a_s[wr*64 + i*16 + l15][0] + roff); \
            _Pragma("unroll")                                                  \
            for (int j = 0; j < 4; ++j)                                        \
                bfr[j] = *(const short8*)((const char*)&b_s[wc*64 + j*16 + l15][0] + roff); \
            _Pragma("unroll")                                                  \
            for (int i = 0; i < 4; ++i)                                        \
                _Pragma("unroll")                                              \
                for (int j = 0; j < 4; ++j)                                    \
                    acc[i][j] = __builtin_amdgcn_mfma_f32_16x16x32_bf16(       \
                        af[i], bfr[j], acc[i][j], 0, 0, 0);                    \
        }                                                                      \
    }

// QKV GEMM: writes Qb[head][s][d], Kb[head][s][d], Vt[head][d][s] (bf16)
// Epilogue: stage output tile in LDS, then fully-coalesced 16B stores.
__global__ __launch_bounds__(256) void gemm_qkv_mfma(
    const short* __restrict__ A, const short* __restrict__ Bt,
    const float* __restrict__ bias,
    short* __restrict__ Qb, short* __restrict__ Kb, short* __restrict__ Vt)
{
    GEMM_CORE(A, Bt)

    const int sec = n0 / CDIM;      // tile fully inside one of q/k/v
    float bj[4];
#pragma unroll
    for (int j = 0; j < 4; ++j) bj[j] = bias[n0 + wc*64 + j*16 + l15];

    if (sec < 2) {
        short* base = (sec == 0) ? Qb : Kb;
        short (*tile)[68] = (short(*)[68])&smem[0][0][0];   // 128x68 = 17408 B
#pragma unroll
        for (int h = 0; h < 2; ++h) {
            __syncthreads();
            if (wc == h) {
#pragma unroll
                for (int i = 0; i < 4; ++i)
#pragma unroll
                    for (int j = 0; j < 4; ++j)
#pragma unroll
                        for (int r = 0; r < 4; ++r)
                            tile[wr*64 + i*16 + quad*4 + r][j*16 + l15] =
                                f2b(acc[i][j][r] + bj[j]);
            }
            __syncthreads();
            const int nn = (n0 % CDIM) + h * 64;
            const int head = nn >> 6;
            short* dst = base + ((size_t)head * S_TOK + m0) * HD;
#pragma unroll
            for (int it = 0; it < 4; ++it) {
                const int row = it * 32 + (tid >> 3), c = (tid & 7) * 8;
                *(short8*)&dst[(size_t)row * HD + c] = *(const short8*)&tile[row][c];
            }
        }
    } else {
        short (*tv)[130] = (short(*)[130])&smem[0][0][0];   // 64x130 = 16640 B
#pragma unroll
        for (int h = 0; h < 2; ++h) {
            __syncthreads();
            if (wc == h) {
#pragma unroll
                for (int i = 0; i < 4; ++i)
#pragma unroll
                    for (int j = 0; j < 4; ++j) {
                        short4v v4;
#pragma unroll
                        for (int r = 0; r < 4; ++r) v4[r] = f2b(acc[i][j][r] + bj[j]);
                        *(short4v*)&tv[j*16 + l15][wr*64 + i*16 + quad*4] = v4;
                    }
            }
            __syncthreads();
            const int nn = (n0 % CDIM) + h * 64;
            const int head = nn >> 6;
            short* dst = Vt + (size_t)head * HD * S_TOK + m0;
#pragma unroll
            for (int it = 0; it < 4; ++it) {
                const int nr = it * 16 + (tid >> 4), sc = (tid & 15) * 8;
                *(short8*)&dst[(size_t)nr * S_TOK + sc] = *(const short8*)&tv[nr][sc];
            }
        }
    }
}

// Proj GEMM: out fp32 [4096][768] = A @ Bt^T + bias
// Epilogue: LDS float tile (XOR chunk swizzle), coalesced float4 stores.
__global__ __launch_bounds__(256) void gemm_proj_mfma(
    const short* __restrict__ A, const short* __restrict__ Bt,
    const float* __restrict__ bias, float* __restrict__ out)
{
    GEMM_CORE(A, Bt)

    float bj[4];
#pragma unroll
    for (int j = 0; j < 4; ++j) bj[j] = bias[n0 + wc*64 + j*16 + l15];

    float* tf = (float*)&smem[0][0][0];   // [64][128] floats, chunk-XOR layout
#pragma unroll
    for (int h = 0; h < 2; ++h) {
        __syncthreads();
        if (wr == h) {
#pragma unroll
            for (int i = 0; i < 4; ++i)
#pragma unroll
                for (int j = 0; j < 4; ++j) {
                    const int cc = wc*16 + j*4 + (l15 >> 2);   // float4-chunk idx
                    const int ci = l15 & 3;
#pragma unroll
                    for (int r = 0; r < 4; ++r) {
                        const int row = i*16 + quad*4 + r;
                        const int pc = cc ^ ((row & 7) << 2);
                        tf[row * 128 + pc * 4 + ci] = acc[i][j][r] + bj[j];
                    }
                }
        }
        __syncthreads();
        float* dst = out + (size_t)(m0 + h * 64) * CDIM + n0;
#pragma unroll
        for (int it = 0; it < 8; ++it) {
            const int row = it * 8 + (tid >> 5);
            const int gc = tid & 31;
            const int pc = gc ^ ((row & 7) << 2);
            float4 v = *(const float4*)&tf[row * 128 + pc * 4];
            *(float4*)&dst[(size_t)row * CDIM + gc * 4] = v;
        }
    }
}

// ---------------------------------------------------------------------------
// Rel-pos tables via MFMA. One block per (y, head); 64 queries s0=y*64..+63.
// Outputs PRE-SCALED by log2e. Relh stored TRANSPOSED: RelhT[head][ky][s].
// ---------------------------------------------------------------------------
__global__ __launch_bounds__(256) void rel_mfma_kernel(
    const short* __restrict__ Qb, const float* __restrict__ rph,
    const float* __restrict__ rpw, short* __restrict__ RelhT,
    short* __restrict__ Relw)
{
    __shared__ __align__(16) short q_s [64][72];
    __shared__ __align__(16) short rh_s[64][72];
    __shared__ __align__(16) short rw_s[128][72];

    const int tid  = threadIdx.x;
    const int y    = blockIdx.x;
    const int head = blockIdx.y;
    const int s0   = y * 64;
    const int w = tid >> 6, lane = tid & 63;
    const int l15 = lane & 15, quad = lane >> 4;
    const int srow = tid >> 2;            // 0..63
    const int scol = (tid & 3) << 4;      // 0,16,32,48

    // ---- stage Q (bf16 passthrough) ----
    {
        const uint4* g = (const uint4*)(Qb + ((size_t)head * S_TOK + s0 + srow) * HD + scol);
        *(uint4*)&q_s[srow][scol]     = g[0];
        *(uint4*)&q_s[srow][scol + 8] = g[1];
    }
    // ---- stage rph rows y..y+63 (fp32 -> bf16) ----
    {
        const float* g = rph + (size_t)(y + srow) * HD + scol;
        short tmp[16];
#pragma unroll
        for (int i = 0; i < 16; i += 4) {
            float4 v = *(const float4*)(g + i);
            tmp[i] = f2b(v.x); tmp[i+1] = f2b(v.y); tmp[i+2] = f2b(v.z); tmp[i+3] = f2b(v.w);
        }
        *(short8*)&rh_s[srow][scol]     = *(short8*)&tmp[0];
        *(short8*)&rh_s[srow][scol + 8] = *(short8*)&tmp[8];
    }
    // ---- stage rpw rows 0..127 (row 127 clamped; never consumed) ----
#pragma unroll
    for (int half = 0; half < 2; ++half) {
        const int row = srow + half * 64;
        const int rr  = row > 126 ? 126 : row;
        const float* g = rpw + (size_t)rr * HD + scol;
        short tmp[16];
#pragma unroll
        for (int i = 0; i < 16; i += 4) {
            float4 v = *(const float4*)(g + i);
            tmp[i] = f2b(v.x); tmp[i+1] = f2b(v.y); tmp[i+2] = f2b(v.z); tmp[i+3] = f2b(v.w);
        }
        *(short8*)&rw_s[row][scol]     = *(short8*)&tmp[0];
        *(short8*)&rw_s[row][scol + 8] = *(short8*)&tmp[8];
    }
    __syncthreads();

    const short8 qa0 = *(const short8*)&q_s[w * 16 + l15][quad * 8];
    const short8 qa1 = *(const short8*)&q_s[w * 16 + l15][32 + quad * 8];

    // ---- relh: RH col j = y+jj, ky = 63-jj; transposed short4v stores ----
#pragma unroll
    for (int ct = 0; ct < 4; ++ct) {
        const int jj = ct * 16 + l15;
        short8 b0 = *(const short8*)&rh_s[jj][quad * 8];
        short8 b1 = *(const short8*)&rh_s[jj][32 + quad * 8];
        float4v z = (float4v){0.f, 0.f, 0.f, 0.f};
        z = __builtin_amdgcn_mfma_f32_16x16x32_bf16(qa0, b0, z, 0, 0, 0);
        z = __builtin_amdgcn_mfma_f32_16x16x32_bf16(qa1, b1, z, 0, 0, 0);
        const int ky = 63 - jj;
        short4v o4;
#pragma unroll
        for (int r = 0; r < 4; ++r) o4[r] = f2b(z[r] * LOG2E);
        *(short4v*)&RelhT[((size_t)head * HD + ky) * S_TOK + s0 + w * 16 + quad * 4] = o4;
    }

    // ---- relw: kx = q+63-j, keep 0<=kx<64 ----
#pragma unroll
    for (int ct = 0; ct < 8; ++ct) {
        const int j = ct * 16 + l15;
        short8 b0 = *(const short8*)&rw_s[j][quad * 8];
        short8 b1 = *(const short8*)&rw_s[j][32 + quad * 8];
        float4v z = (float4v){0.f, 0.f, 0.f, 0.f};
        z = __builtin_amdgcn_mfma_f32_16x16x32_bf16(qa0, b0, z, 0, 0, 0);
        z = __builtin_amdgcn_mfma_f32_16x16x32_bf16(qa1, b1, z, 0, 0, 0);
#pragma unroll
        for (int r = 0; r < 4; ++r) {
            const int q  = w * 16 + quad * 4 + r;
            const int kx = q + 63 - j;
            if (kx >= 0 && kx < 64)
                Relw[((size_t)head * S_TOK + s0 + q) * HD + kx] = f2b(z[r] * LOG2E);
        }
    }
}

// ---------------------------------------------------------------------------
// Flash attention v12 = v7 (the 76 us best: pair-split, K-dbuf + V-single LDS
// staging via global_load_lds, 2 barriers/step, 48 KB, 12 waves/CU) + the
// XCD head-grouping swizzle validated in v9-v11 (FETCH 58->~22 MB): with 96
// consecutive logical blocks per XCD, each XCD's K/V working set is ~1.5
// heads (<=1.5 MB << 4 MB L2), so the K/V DMAs drained at each barrier
// complete from L2 (~200 cy) instead of HBM (~900 cy).
//   The V-from-global line (v9-v11) is abandoned: PV's wait on mid-step V
//   vector-loads force-drains the in-order vmcnt queue, killing the K
//   prefetch (119 us spill-free floor vs v7's 76).
// ---------------------------------------------------------------------------
__global__ __launch_bounds__(256, 3) void flash_kernel(
    const short* __restrict__ Qb, const short* __restrict__ Kb,
    const short* __restrict__ Vt, const short* __restrict__ RelhT,
    const short* __restrict__ Relw, short* __restrict__ attn_b)
{
    // shorts 0..16383: K[pair][buf][64][64]; 16384..24575: V[pair][64][64]
    __shared__ __align__(16) short lds_s[24576];

    const int tid  = threadIdx.x;
    const int bid  = blockIdx.x;
    const int logi = (bid & 7) * 96 + (bid >> 3);   // XCD head-grouping swizzle
    const int head = logi >> 6;
    const int s0   = (logi & 63) << 6;
    const int w    = tid >> 6, lane = tid & 63;
    const int l15  = lane & 15, quad = lane >> 4;
    const int ph   = w >> 1;          // key-chunk half: chunks ph*32 + t
    const int qh   = w & 1;           // query half: queries qh*32 + ...

    const float C1 = 0.125f * LOG2E;

    // ---- staging lane mapping (linear dest, pre-swizzled source) ----
    const int lj = lane >> 3;             // row within 8-row DMA group
    const int sl = (lane & 7) ^ lj;       // logical 16B slot this lane fetches
    const int kf0 = (lj & 3) + ((lj & 4) << 1) + qh * 32;  // permuted key, ii=0

    const short* pKs = Kb + (size_t)head * S_TOK * HD
                     + (size_t)(ph * 32 * 64 + kf0) * HD + sl * 8;
    const short* pVs = Vt + ((size_t)head * HD + qh * 32 + lj) * S_TOK
                     + ph * 32 * 64 + sl * 8;

    // wave-uniform LDS dest bases (named; ternary select only)
    short* lk0 = &lds_s[(ph * 2 + 0) << 12] + qh * 32 * 64;
    short* lk1 = &lds_s[(ph * 2 + 1) << 12] + qh * 32 * 64;
    short* lv  = &lds_s[16384 + (ph << 12)] + qh * 32 * 64;
    const short* krd0 = &lds_s[(ph * 2 + 0) << 12];
    const short* krd1 = &lds_s[(ph * 2 + 1) << 12];
    const short* vrd  = &lds_s[16384 + (ph << 12)];

    // swizzled read byte-offsets (row&7 == l15&7 for all frag rows)
    const int roff0 = (quad ^ (l15 & 7)) << 4;   // logical slot quad
    const int roff1 = roff0 ^ 64;                // logical slot 4+quad

    // ---- Q B-frags: 2 q-tiles (32 queries per wave) ----
    short8 qb[2][2];
#pragma unroll
    for (int qt = 0; qt < 2; ++qt) {
        const short* qrow = Qb + ((size_t)head * S_TOK + s0 + qh * 32 + qt * 16 + l15) * HD;
        qb[qt][0] = *(const short8*)(qrow + quad * 8);
        qb[qt][1] = *(const short8*)(qrow + 32 + quad * 8);
    }

    // ---- relw invariants: rwv[qt][kt][r], key = kbase(kt) + quad*8 + r ----
    float rwv[2][4][4];
#pragma unroll
    for (int qt = 0; qt < 2; ++qt) {
        const short* rwrow = Relw + ((size_t)head * S_TOK + s0 + qh * 32 + qt * 16 + l15) * HD;
#pragma unroll
        for (int kt = 0; kt < 4; ++kt) {
            const int base = ((kt & 1) << 2) | ((kt >> 1) << 5);
            short4v v = *(const short4v*)(rwrow + base + quad * 8);
#pragma unroll
            for (int r = 0; r < 4; ++r) rwv[qt][kt][r] = b2f(v[r]);
        }
    }

    // RelhT[head][ky][s]: per-chunk coalesced loads (ky == chunk index)
    const short* rhbase = RelhT + (size_t)head * HD * S_TOK + s0 + qh * 32 + l15;
    float rhc0 = b2f(rhbase[(size_t)(ph * 32) * S_TOK]);
    float rhc1 = b2f(rhbase[(size_t)(ph * 32) * S_TOK + 16]);

    // ones A-frag for the denominator
    short8 aones;
#pragma unroll
    for (int j = 0; j < 8; ++j) aones[j] = (short)0x3F80;

    float4v od[2][4];
#pragma unroll
    for (int qt = 0; qt < 2; ++qt)
#pragma unroll
        for (int dt = 0; dt < 4; ++dt) od[qt][dt] = (float4v){0.f, 0.f, 0.f, 0.f};
    float4v dq0 = (float4v){0.f, 0.f, 0.f, 0.f};
    float4v dq1 = (float4v){0.f, 0.f, 0.f, 0.f};

    // ---- prologue: DMA K chunk (ph*32) into buf0 ----
    load_lds16(pKs,        lk0);
    load_lds16(pKs + 1024, lk0 + 8  * 64);
    load_lds16(pKs + 256,  lk0 + 16 * 64);
    load_lds16(pKs + 1280, lk0 + 24 * 64);
    __syncthreads();

    for (int t = 0; t < 32; ++t) {
        const int cur = t & 1;
        const short* krd = cur ? krd1 : krd0;
        short* lkn = cur ? lk0 : lk1;

        // ---- V-DMA current chunk (prev PV separated by loop-end barrier) ----
        load_lds16(pVs,               lv);
        load_lds16(pVs + 8  * S_TOK,  lv + 8  * 64);
        load_lds16(pVs + 16 * S_TOK,  lv + 16 * 64);
        load_lds16(pVs + 24 * S_TOK,  lv + 24 * 64);
        // ---- K-DMA next chunk into the other buffer ----
        if (t < 31) {
            const short* pk = pKs + 4096;
            load_lds16(pk,        lkn);
            load_lds16(pk + 1024, lkn + 8  * 64);
            load_lds16(pk + 256,  lkn + 16 * 64);
            load_lds16(pk + 1280, lkn + 24 * 64);
        }
        pKs += 4096;
        pVs += 64;

        // ---- prefetch next chunk's rh (coalesced 2B loads) ----
        short rhn0, rhn1;
        if (t < 31) {
            rhn0 = rhbase[(size_t)(ph * 32 + t + 1) * S_TOK];
            rhn1 = rhbase[(size_t)(ph * 32 + t + 1) * S_TOK + 16];
        }

        // ---- S-phase: K frags read once, used by both q-tiles ----
        unsigned pkk[2][8];
#pragma unroll
        for (int kt = 0; kt < 4; ++kt) {
            const char* krp = (const char*)(krd + (kt * 16 + l15) * 64);
            const short8 ka0 = *(const short8*)(krp + roff0);
            const short8 ka1 = *(const short8*)(krp + roff1);
            {
                float4v z = (float4v){0.f, 0.f, 0.f, 0.f};
                z = __builtin_amdgcn_mfma_f32_16x16x32_bf16(ka0, qb[0][0], z, 0, 0, 0);
                z = __builtin_amdgcn_mfma_f32_16x16x32_bf16(ka1, qb[0][1], z, 0, 0, 0);
                float p0 = EXP2F(C1 * z[0] + (rhc0 + rwv[0][kt][0]));
                float p1 = EXP2F(C1 * z[1] + (rhc0 + rwv[0][kt][1]));
                float p2 = EXP2F(C1 * z[2] + (rhc0 + rwv[0][kt][2]));
                float p3 = EXP2F(C1 * z[3] + (rhc0 + rwv[0][kt][3]));
                pkk[0][kt * 2]     = pack_trunc(p0, p1);
                pkk[0][kt * 2 + 1] = pack_trunc(p2, p3);
            }
            {
                float4v z = (float4v){0.f, 0.f, 0.f, 0.f};
                z = __builtin_amdgcn_mfma_f32_16x16x32_bf16(ka0, qb[1][0], z, 0, 0, 0);
                z = __builtin_amdgcn_mfma_f32_16x16x32_bf16(ka1, qb[1][1], z, 0, 0, 0);
                float p0 = EXP2F(C1 * z[0] + (rhc1 + rwv[1][kt][0]));
                float p1 = EXP2F(C1 * z[1] + (rhc1 + rwv[1][kt][1]));
                float p2 = EXP2F(C1 * z[2] + (rhc1 + rwv[1][kt][2]));
                float p3 = EXP2F(C1 * z[3] + (rhc1 + rwv[1][kt][3]));
                pkk[1][kt * 2]     = pack_trunc(p0, p1);
                pkk[1][kt * 2 + 1] = pack_trunc(p2, p3);
            }
        }
        const short8 pb00 = u4_to_s8(pkk[0][0], pkk[0][1], pkk[0][2], pkk[0][3]);
        const short8 pb01 = u4_to_s8(pkk[0][4], pkk[0][5], pkk[0][6], pkk[0][7]);
        const short8 pb10 = u4_to_s8(pkk[1][0], pkk[1][1], pkk[1][2], pkk[1][3]);
        const short8 pb11 = u4_to_s8(pkk[1][4], pkk[1][5], pkk[1][6], pkk[1][7]);

        __syncthreads();   // drains vmcnt: V (and next K) landed; K reads done

        // ---- PV: V frags read once, used by both q-tiles (T5 setprio) ----
        __builtin_amdgcn_s_setprio(1);
#pragma unroll
        for (int dt = 0; dt < 4; ++dt) {
            const char* vrp = (const char*)(vrd + (dt * 16 + l15) * 64);
            const short8 va0 = *(const short8*)(vrp + roff0);
            const short8 va1 = *(const short8*)(vrp + roff1);
            od[0][dt] = __builtin_amdgcn_mfma_f32_16x16x32_bf16(va0, pb00, od[0][dt], 0, 0, 0);
            od[0][dt] = __builtin_amdgcn_mfma_f32_16x16x32_bf16(va1, pb01, od[0][dt], 0, 0, 0);
            od[1][dt] = __builtin_amdgcn_mfma_f32_16x16x32_bf16(va0, pb10, od[1][dt], 0, 0, 0);
            od[1][dt] = __builtin_amdgcn_mfma_f32_16x16x32_bf16(va1, pb11, od[1][dt], 0, 0, 0);
        }
        dq0 = __builtin_amdgcn_mfma_f32_16x16x32_bf16(aones, pb00, dq0, 0, 0, 0);
        dq0 = __builtin_amdgcn_mfma_f32_16x16x32_bf16(aones, pb01, dq0, 0, 0, 0);
        dq1 = __builtin_amdgcn_mfma_f32_16x16x32_bf16(aones, pb10, dq1, 0, 0, 0);
        dq1 = __builtin_amdgcn_mfma_f32_16x16x32_bf16(aones, pb11, dq1, 0, 0, 0);
        __builtin_amdgcn_s_setprio(0);

        if (t < 31) {
            rhc0 = b2f(rhn0);
            rhc1 = b2f(rhn1);
        }
        __syncthreads();   // PV done pair-wide; next iter may overwrite V
    }

    // ---- cross-pair combine (overlays the K region; all K reads done) ----
    float* cf = (float*)lds_s;   // comb: [qh][qt][dt][16][16] floats; dq at 4096
    if (ph == 1) {
#pragma unroll
        for (int qt = 0; qt < 2; ++qt)
#pragma unroll
            for (int dt = 0; dt < 4; ++dt) {
                float* dst = &cf[((((qh * 2 + qt) * 4 + dt) * 16) + quad * 4) * 16 + l15];
#pragma unroll
                for (int r = 0; r < 4; ++r) dst[r * 16] = od[qt][dt][r];
            }
        if (quad == 0) {
            cf[4096 + (qh * 2 + 0) * 16 + l15] = dq0[0];
            cf[4096 + (qh * 2 + 1) * 16 + l15] = dq1[0];
        }
    }
    __syncthreads();
    if (ph == 0) {
#pragma unroll
        for (int qt = 0; qt < 2; ++qt) {
            const float dtot = ((qt == 0) ? dq0[0] : dq1[0])
                             + cf[4096 + (qh * 2 + qt) * 16 + l15];
            const float inv = 1.f / dtot;
            short* outp = attn_b + (size_t)(s0 + qh * 32 + qt * 16 + l15) * CDIM + head * HD;
#pragma unroll
            for (int dt = 0; dt < 4; ++dt) {
                const float* src = &cf[((((qh * 2 + qt) * 4 + dt) * 16) + quad * 4) * 16 + l15];
                short4v o4;
#pragma unroll
                for (int r = 0; r < 4; ++r)
                    o4[r] = f2b((od[qt][dt][r] + src[r * 16]) * inv);
                *(short4v*)(outp + dt * 16 + quad * 4) = o4;
            }
        }
    }
}

// ---------------------------------------------------------------------------
extern "C" void kernel_launch(void* const* d_in, const int* in_sizes, int n_in,
                              void* d_out, int out_size, void* d_ws, size_t ws_size,
                              hipStream_t stream)
{
    const float* x    = (const float*)d_in[0];
    const float* qkvw = (const float*)d_in[1];
    const float* qkvb = (const float*)d_in[2];
    const float* rph  = (const float*)d_in[3];
    const float* rpw  = (const float*)d_in[4];
    const float* pw   = (const float*)d_in[5];
    const float* pb   = (const float*)d_in[6];
    float* out = (float*)d_out;

    // ws layout (shorts), total ~48.8 MB
    const size_t HSD = (size_t)NH * S_TOK * HD;   // 3,145,728
    short* xb     = (short*)d_ws;                 // 4096*768
    short* wt     = xb + (size_t)S_TOK * CDIM;    // 2304*768 (qkv_w^T)
    short* pwt    = wt + (size_t)N3C * CDIM;      // 768*768  (proj_w^T)
    short* Qb     = pwt + (size_t)CDIM * CDIM;
    short* Kb     = Qb + HSD;
    short* Vt     = Kb + HSD;
    short* RelhT  = Vt + HSD;                     // [head][ky][s]
    short* Relw   = RelhT + HSD;
    short* attn_b = Relw + HSD;                   // 4096*768

    cast_bf16_kernel<<<S_TOK * CDIM / 4 / 256, 256, 0, stream>>>(x, xb, S_TOK * CDIM / 4);
    transpose_cast_kernel<<<dim3(N3C / 64, CDIM / 64), 256, 0, stream>>>(qkvw, wt, CDIM, N3C);
    transpose_cast_kernel<<<dim3(CDIM / 64, CDIM / 64), 256, 0, stream>>>(pw, pwt, CDIM, CDIM);

    gemm_qkv_mfma<<<dim3(N3C / 128, S_TOK / 128), 256, 0, stream>>>(
        xb, wt, qkvb, Qb, Kb, Vt);
    rel_mfma_kernel<<<dim3(64, NH), 256, 0, stream>>>(Qb, rph, rpw, RelhT, Relw);
    flash_kernel<<<dim3(64 * NH), 256, 0, stream>>>(Qb, Kb, Vt, RelhT, Relw, attn_b);
    gemm_proj_mfma<<<dim3(CDIM / 128, S_TOK / 128), 256, 0, stream>>>(
        attn_b, pwt, pb, out);
}

// Round 11
// 210.263 us; speedup vs baseline: 1.4663x; 1.0015x over previous
//
#include <hip/hip_runtime.h>
#include <hip/hip_bf16.h>

// Problem constants (B=1, H=W=64, C=768, nh=12, hd=64)
#define S_TOK 4096
#define CDIM  768
#define N3C   2304
#define NH    12
#define HD    64

#define LOG2E 1.44269504f

typedef __attribute__((ext_vector_type(8))) short short8;
typedef __attribute__((ext_vector_type(4))) short short4v;
typedef __attribute__((ext_vector_type(4))) float float4v;
typedef __attribute__((ext_vector_type(4))) unsigned uint4v;

__device__ __forceinline__ float b2f(short s) {
    return __uint_as_float(((unsigned)(unsigned short)s) << 16);
}
__device__ __forceinline__ short f2b(float f) {   // round-to-nearest-even
    unsigned u = __float_as_uint(f);
    unsigned r = (u + 0x7FFFu + ((u >> 16) & 1u)) >> 16;
    return (short)r;
}

#if __has_builtin(__builtin_amdgcn_exp2f)
#define EXP2F __builtin_amdgcn_exp2f
#else
#define EXP2F exp2f
#endif

// pack trunc-bf16(a) into low short, trunc-bf16(b) into high short
__device__ __forceinline__ unsigned pack_trunc(float a, float b) {
    return __builtin_amdgcn_perm(__float_as_uint(b), __float_as_uint(a), 0x07060302u);
}

__device__ __forceinline__ short8 u4_to_s8(unsigned a, unsigned b, unsigned c, unsigned d) {
    union { uint4v u; short8 s; } t;
    t.u = (uint4v){a, b, c, d};
    return t.s;
}

// async global->LDS DMA, 16B per lane, dest = ldsbase + lane*16 (linear)
__device__ __forceinline__ void load_lds16(const void* g, void* l) {
    __builtin_amdgcn_global_load_lds(
        (const __attribute__((address_space(1))) unsigned int*)g,
        (__attribute__((address_space(3))) unsigned int*)l, 16, 0, 0);
}

// ---------------------------------------------------------------------------
// Elementwise fp32 -> bf16 cast (4 elems/thread)
// ---------------------------------------------------------------------------
__global__ __launch_bounds__(256) void cast_bf16_kernel(
    const float* __restrict__ in, short* __restrict__ out, int n4)
{
    int i = blockIdx.x * 256 + threadIdx.x;
    if (i >= n4) return;
    float4 v = ((const float4*)in)[i];
    short4v o4 = { f2b(v.x), f2b(v.y), f2b(v.z), f2b(v.w) };
    *(short4v*)&out[(size_t)i * 4] = o4;
}

// ---------------------------------------------------------------------------
// Transpose + cast: in fp32 [R][C] -> out bf16 [C][R]. 64x64 tiles, 256 thr.
// ---------------------------------------------------------------------------
__global__ __launch_bounds__(256) void transpose_cast_kernel(
    const float* __restrict__ in, short* __restrict__ out, int R, int C)
{
    __shared__ float t[64][65];
    const int tid = threadIdx.x;
    const int c0 = blockIdx.x * 64, r0 = blockIdx.y * 64;
    const int li = tid >> 6;      // 0..3
    const int lj = tid & 63;
#pragma unroll
    for (int p = 0; p < 16; ++p) {
        int i = p * 4 + li;
        t[i][lj] = in[(size_t)(r0 + i) * C + c0 + lj];
    }
    __syncthreads();
#pragma unroll
    for (int p = 0; p < 16; ++p) {
        int i = p * 4 + li;
        out[(size_t)(c0 + i) * R + r0 + lj] = f2b(t[lj][i]);
    }
}

// ---------------------------------------------------------------------------
// MFMA GEMM core v2: C[128x128] = A[128xK] @ Bt[128xK]^T
//   Staging via global_load_lds; linear LDS dest, inverse swizzle folded into
//   the per-lane GLOBAL source address; frag reads apply the same XOR.
//   smem is a single 32 KB block so epilogues can overlay it.
// ---------------------------------------------------------------------------
#define GEMM_CORE(A_, Bt_)                                                     \
    __shared__ __align__(16) short smem[2][128][64];                           \
    auto a_s = smem[0];                                                        \
    auto b_s = smem[1];                                                        \
    const int tid  = threadIdx.x;                                              \
    const int m0 = blockIdx.y * 128;                                           \
    const int n0 = blockIdx.x * 128;                                           \
    const int lane = tid & 63, w = tid >> 6;                                   \
    const int l15 = lane & 15, quad = lane >> 4;                               \
    const int wr = w >> 1, wc = w & 1;                                         \
    const int roff0 = (quad ^ (l15 & 7)) << 4;                                 \
    const int roff1 = roff0 ^ 64;                                              \
    const int srow0 = w * 8 + (lane >> 3);                                     \
    const int sslot = (lane & 7) ^ ((lane >> 3) & 7);                          \
    const short* ga = A_ + (size_t)(m0 + srow0) * 768 + sslot * 8;             \
    const short* gb = Bt_ + (size_t)(n0 + srow0) * 768 + sslot * 8;            \
    short* la = &a_s[w * 8][0];                                                \
    short* lb = &b_s[w * 8][0];                                                \
    float4v acc[4][4];                                                         \
    _Pragma("unroll")                                                          \
    for (int i = 0; i < 4; ++i)                                                \
        _Pragma("unroll")                                                      \
        for (int j = 0; j < 4; ++j) acc[i][j] = (float4v){0.f,0.f,0.f,0.f};    \
    for (int k0 = 0; k0 < 768; k0 += 64) {                                     \
        __syncthreads();                                                       \
        _Pragma("unroll")                                                      \
        for (int i = 0; i < 4; ++i) {                                          \
            load_lds16(ga + (size_t)i * (32 * 768) + k0, la + i * 32 * 64);    \
            load_lds16(gb + (size_t)i * (32 * 768) + k0, lb + i * 32 * 64);    \
        }                                                                      \
        __syncthreads();                                                       \
        _Pragma("unroll")                                                      \
        for (int kk = 0; kk < 64; kk += 32) {                                  \
            const int roff = kk ? roff1 : roff0;                               \
            short8 af[4], bfr[4];                                              \
            _Pragma("unroll")                                                  \
            for (int i = 0; i < 4; ++i)                                        \
                af[i] = *(const short8*)((const char*)&a_s[wr*64 + i*16 + l15][0] + roff); \
            _Pragma("unroll")                                                  \
            for (int j = 0; j < 4; ++j)                                        \
                bfr[j] = *(const short8*)((const char*)&b_s[wc*64 + j*16 + l15][0] + roff); \
            _Pragma("unroll")                                                  \
            for (int i = 0; i < 4; ++i)                                        \
                _Pragma("unroll")                                              \
                for (int j = 0; j < 4; ++j)                                    \
                    acc[i][j] = __builtin_amdgcn_mfma_f32_16x16x32_bf16(       \
                        af[i], bfr[j], acc[i][j], 0, 0, 0);                    \
        }                                                                      \
    }

// QKV GEMM: writes Qb[head][s][d], Kb[head][s][d], Vt[head][d][s] (bf16)
// Epilogue: stage output tile in LDS, then fully-coalesced 16B stores.
__global__ __launch_bounds__(256) void gemm_qkv_mfma(
    const short* __restrict__ A, const short* __restrict__ Bt,
    const float* __restrict__ bias,
    short* __restrict__ Qb, short* __restrict__ Kb, short* __restrict__ Vt)
{
    GEMM_CORE(A, Bt)

    const int sec = n0 / CDIM;      // tile fully inside one of q/k/v
    float bj[4];
#pragma unroll
    for (int j = 0; j < 4; ++j) bj[j] = bias[n0 + wc*64 + j*16 + l15];

    if (sec < 2) {
        short* base = (sec == 0) ? Qb : Kb;
        short (*tile)[68] = (short(*)[68])&smem[0][0][0];   // 128x68 = 17408 B
#pragma unroll
        for (int h = 0; h < 2; ++h) {
            __syncthreads();
            if (wc == h) {
#pragma unroll
                for (int i = 0; i < 4; ++i)
#pragma unroll
                    for (int j = 0; j < 4; ++j)
#pragma unroll
                        for (int r = 0; r < 4; ++r)
                            tile[wr*64 + i*16 + quad*4 + r][j*16 + l15] =
                                f2b(acc[i][j][r] + bj[j]);
            }
            __syncthreads();
            const int nn = (n0 % CDIM) + h * 64;
            const int head = nn >> 6;
            short* dst = base + ((size_t)head * S_TOK + m0) * HD;
#pragma unroll
            for (int it = 0; it < 4; ++it) {
                const int row = it * 32 + (tid >> 3), c = (tid & 7) * 8;
                *(short8*)&dst[(size_t)row * HD + c] = *(const short8*)&tile[row][c];
            }
        }
    } else {
        short (*tv)[130] = (short(*)[130])&smem[0][0][0];   // 64x130 = 16640 B
#pragma unroll
        for (int h = 0; h < 2; ++h) {
            __syncthreads();
            if (wc == h) {
#pragma unroll
                for (int i = 0; i < 4; ++i)
#pragma unroll
                    for (int j = 0; j < 4; ++j) {
                        short4v v4;
#pragma unroll
                        for (int r = 0; r < 4; ++r) v4[r] = f2b(acc[i][j][r] + bj[j]);
                        *(short4v*)&tv[j*16 + l15][wr*64 + i*16 + quad*4] = v4;
                    }
            }
            __syncthreads();
            const int nn = (n0 % CDIM) + h * 64;
            const int head = nn >> 6;
            short* dst = Vt + (size_t)head * HD * S_TOK + m0;
#pragma unroll
            for (int it = 0; it < 4; ++it) {
                const int nr = it * 16 + (tid >> 4), sc = (tid & 15) * 8;
                *(short8*)&dst[(size_t)nr * S_TOK + sc] = *(const short8*)&tv[nr][sc];
            }
        }
    }
}

// Proj GEMM: out fp32 [4096][768] = A @ Bt^T + bias
// Epilogue: LDS float tile (XOR chunk swizzle), coalesced float4 stores.
__global__ __launch_bounds__(256) void gemm_proj_mfma(
    const short* __restrict__ A, const short* __restrict__ Bt,
    const float* __restrict__ bias, float* __restrict__ out)
{
    GEMM_CORE(A, Bt)

    float bj[4];
#pragma unroll
    for (int j = 0; j < 4; ++j) bj[j] = bias[n0 + wc*64 + j*16 + l15];

    float* tf = (float*)&smem[0][0][0];   // [64][128] floats, chunk-XOR layout
#pragma unroll
    for (int h = 0; h < 2; ++h) {
        __syncthreads();
        if (wr == h) {
#pragma unroll
            for (int i = 0; i < 4; ++i)
#pragma unroll
                for (int j = 0; j < 4; ++j) {
                    const int cc = wc*16 + j*4 + (l15 >> 2);   // float4-chunk idx
                    const int ci = l15 & 3;
#pragma unroll
                    for (int r = 0; r < 4; ++r) {
                        const int row = i*16 + quad*4 + r;
                        const int pc = cc ^ ((row & 7) << 2);
                        tf[row * 128 + pc * 4 + ci] = acc[i][j][r] + bj[j];
                    }
                }
        }
        __syncthreads();
        float* dst = out + (size_t)(m0 + h * 64) * CDIM + n0;
#pragma unroll
        for (int it = 0; it < 8; ++it) {
            const int row = it * 8 + (tid >> 5);
            const int gc = tid & 31;
            const int pc = gc ^ ((row & 7) << 2);
            float4 v = *(const float4*)&tf[row * 128 + pc * 4];
            *(float4*)&dst[(size_t)row * CDIM + gc * 4] = v;
        }
    }
}

// ---------------------------------------------------------------------------
// Rel-pos tables via MFMA. One block per (y, head); 64 queries s0=y*64..+63.
// Outputs PRE-SCALED by log2e. Relh stored TRANSPOSED: RelhT[head][ky][s].
// ---------------------------------------------------------------------------
__global__ __launch_bounds__(256) void rel_mfma_kernel(
    const short* __restrict__ Qb, const float* __restrict__ rph,
    const float* __restrict__ rpw, short* __restrict__ RelhT,
    short* __restrict__ Relw)
{
    __shared__ __align__(16) short q_s [64][72];
    __shared__ __align__(16) short rh_s[64][72];
    __shared__ __align__(16) short rw_s[128][72];

    const int tid  = threadIdx.x;
    const int y    = blockIdx.x;
    const int head = blockIdx.y;
    const int s0   = y * 64;
    const int w = tid >> 6, lane = tid & 63;
    const int l15 = lane & 15, quad = lane >> 4;
    const int srow = tid >> 2;            // 0..63
    const int scol = (tid & 3) << 4;      // 0,16,32,48

    // ---- stage Q (bf16 passthrough) ----
    {
        const uint4* g = (const uint4*)(Qb + ((size_t)head * S_TOK + s0 + srow) * HD + scol);
        *(uint4*)&q_s[srow][scol]     = g[0];
        *(uint4*)&q_s[srow][scol + 8] = g[1];
    }
    // ---- stage rph rows y..y+63 (fp32 -> bf16) ----
    {
        const float* g = rph + (size_t)(y + srow) * HD + scol;
        short tmp[16];
#pragma unroll
        for (int i = 0; i < 16; i += 4) {
            float4 v = *(const float4*)(g + i);
            tmp[i] = f2b(v.x); tmp[i+1] = f2b(v.y); tmp[i+2] = f2b(v.z); tmp[i+3] = f2b(v.w);
        }
        *(short8*)&rh_s[srow][scol]     = *(short8*)&tmp[0];
        *(short8*)&rh_s[srow][scol + 8] = *(short8*)&tmp[8];
    }
    // ---- stage rpw rows 0..127 (row 127 clamped; never consumed) ----
#pragma unroll
    for (int half = 0; half < 2; ++half) {
        const int row = srow + half * 64;
        const int rr  = row > 126 ? 126 : row;
        const float* g = rpw + (size_t)rr * HD + scol;
        short tmp[16];
#pragma unroll
        for (int i = 0; i < 16; i += 4) {
            float4 v = *(const float4*)(g + i);
            tmp[i] = f2b(v.x); tmp[i+1] = f2b(v.y); tmp[i+2] = f2b(v.z); tmp[i+3] = f2b(v.w);
        }
        *(short8*)&rw_s[row][scol]     = *(short8*)&tmp[0];
        *(short8*)&rw_s[row][scol + 8] = *(short8*)&tmp[8];
    }
    __syncthreads();

    const short8 qa0 = *(const short8*)&q_s[w * 16 + l15][quad * 8];
    const short8 qa1 = *(const short8*)&q_s[w * 16 + l15][32 + quad * 8];

    // ---- relh: RH col j = y+jj, ky = 63-jj; transposed short4v stores ----
#pragma unroll
    for (int ct = 0; ct < 4; ++ct) {
        const int jj = ct * 16 + l15;
        short8 b0 = *(const short8*)&rh_s[jj][quad * 8];
        short8 b1 = *(const short8*)&rh_s[jj][32 + quad * 8];
        float4v z = (float4v){0.f, 0.f, 0.f, 0.f};
        z = __builtin_amdgcn_mfma_f32_16x16x32_bf16(qa0, b0, z, 0, 0, 0);
        z = __builtin_amdgcn_mfma_f32_16x16x32_bf16(qa1, b1, z, 0, 0, 0);
        const int ky = 63 - jj;
        short4v o4;
#pragma unroll
        for (int r = 0; r < 4; ++r) o4[r] = f2b(z[r] * LOG2E);
        *(short4v*)&RelhT[((size_t)head * HD + ky) * S_TOK + s0 + w * 16 + quad * 4] = o4;
    }

    // ---- relw: kx = q+63-j, keep 0<=kx<64 ----
#pragma unroll
    for (int ct = 0; ct < 8; ++ct) {
        const int j = ct * 16 + l15;
        short8 b0 = *(const short8*)&rw_s[j][quad * 8];
        short8 b1 = *(const short8*)&rw_s[j][32 + quad * 8];
        float4v z = (float4v){0.f, 0.f, 0.f, 0.f};
        z = __builtin_amdgcn_mfma_f32_16x16x32_bf16(qa0, b0, z, 0, 0, 0);
        z = __builtin_amdgcn_mfma_f32_16x16x32_bf16(qa1, b1, z, 0, 0, 0);
#pragma unroll
        for (int r = 0; r < 4; ++r) {
            const int q  = w * 16 + quad * 4 + r;
            const int kx = q + 63 - j;
            if (kx >= 0 && kx < 64)
                Relw[((size_t)head * S_TOK + s0 + q) * HD + kx] = f2b(z[r] * LOG2E);
        }
    }
}

// ---------------------------------------------------------------------------
// Flash attention v14: counted-vmcnt protocol, RACE-CORRECTED.
//   v13 bug: vmcnt is PER-WAVE, but K/V tiles are written by one wave and
//   read by its pair partner -- v13's vmcnt(10) at step top had no barrier
//   before the S-phase reads, so a wave could read the partner's K rows
//   before the partner's DMA landed. v14 protocol (3 light barriers, ZERO
//   forced drains; wait-THEN-barrier so every cross-wave read follows a
//   barrier at which ALL waves drained the relevant loads):
//     top: issue V(t), rh(t+1), K(t+1)      [order pinned by fences]
//     vmcnt(10) [own K(t) done]  -> bar1 -> S-phase reads K(t)
//     vmcnt(6)  [own V(t) done]  -> bar2 -> PV reads V(t)
//     bar3 [PV reads done before next step's V(t+1) overwrite]
//   K(t+1) crosses all three barriers IN FLIGHT (waited a full step later).
//   Overwrite hazards: K(t+1)->buf^1 issued after bar3(t-1) > bar2(t-1)
//   where buf^1 reads ended; V(t) issued after bar3(t-1) = end of V(t-1)
//   reads. Barrier counts wave-uniform. Everything else identical to v12
//   (pair-split, K-dbuf + V-single LDS, XCD head-group swizzle, 48 KB,
//   12 waves/CU, setprio on PV).
// ---------------------------------------------------------------------------
__global__ __launch_bounds__(256, 3) void flash_kernel(
    const short* __restrict__ Qb, const short* __restrict__ Kb,
    const short* __restrict__ Vt, const short* __restrict__ RelhT,
    const short* __restrict__ Relw, short* __restrict__ attn_b)
{
    // shorts 0..16383: K[pair][buf][64][64]; 16384..24575: V[pair][64][64]
    __shared__ __align__(16) short lds_s[24576];

    const int tid  = threadIdx.x;
    const int bid  = blockIdx.x;
    const int logi = (bid & 7) * 96 + (bid >> 3);   // XCD head-grouping swizzle
    const int head = logi >> 6;
    const int s0   = (logi & 63) << 6;
    const int w    = tid >> 6, lane = tid & 63;
    const int l15  = lane & 15, quad = lane >> 4;
    const int ph   = w >> 1;          // key-chunk half: chunks ph*32 + t
    const int qh   = w & 1;           // query half: queries qh*32 + ...

    const float C1 = 0.125f * LOG2E;

    // ---- staging lane mapping (linear dest, pre-swizzled source) ----
    const int lj = lane >> 3;             // row within 8-row DMA group
    const int sl = (lane & 7) ^ lj;       // logical 16B slot this lane fetches
    const int kf0 = (lj & 3) + ((lj & 4) << 1) + qh * 32;  // permuted key, ii=0

    const short* pKs = Kb + (size_t)head * S_TOK * HD
                     + (size_t)(ph * 32 * 64 + kf0) * HD + sl * 8;
    const short* pVs = Vt + ((size_t)head * HD + qh * 32 + lj) * S_TOK
                     + ph * 32 * 64 + sl * 8;

    // wave-uniform LDS dest bases (named; ternary select only)
    short* lk0 = &lds_s[(ph * 2 + 0) << 12] + qh * 32 * 64;
    short* lk1 = &lds_s[(ph * 2 + 1) << 12] + qh * 32 * 64;
    short* lv  = &lds_s[16384 + (ph << 12)] + qh * 32 * 64;
    const short* krd0 = &lds_s[(ph * 2 + 0) << 12];
    const short* krd1 = &lds_s[(ph * 2 + 1) << 12];
    const short* vrd  = &lds_s[16384 + (ph << 12)];

    // swizzled read byte-offsets (row&7 == l15&7 for all frag rows)
    const int roff0 = (quad ^ (l15 & 7)) << 4;   // logical slot quad
    const int roff1 = roff0 ^ 64;                // logical slot 4+quad

    // ---- Q B-frags: 2 q-tiles (32 queries per wave) ----
    short8 qb[2][2];
#pragma unroll
    for (int qt = 0; qt < 2; ++qt) {
        const short* qrow = Qb + ((size_t)head * S_TOK + s0 + qh * 32 + qt * 16 + l15) * HD;
        qb[qt][0] = *(const short8*)(qrow + quad * 8);
        qb[qt][1] = *(const short8*)(qrow + 32 + quad * 8);
    }

    // ---- relw invariants: rwv[qt][kt][r], key = kbase(kt) + quad*8 + r ----
    float rwv[2][4][4];
#pragma unroll
    for (int qt = 0; qt < 2; ++qt) {
        const short* rwrow = Relw + ((size_t)head * S_TOK + s0 + qh * 32 + qt * 16 + l15) * HD;
#pragma unroll
        for (int kt = 0; kt < 4; ++kt) {
            const int base = ((kt & 1) << 2) | ((kt >> 1) << 5);
            short4v v = *(const short4v*)(rwrow + base + quad * 8);
#pragma unroll
            for (int r = 0; r < 4; ++r) rwv[qt][kt][r] = b2f(v[r]);
        }
    }

    // RelhT[head][ky][s]: per-chunk coalesced loads (ky == chunk index)
    const short* rhbase = RelhT + (size_t)head * HD * S_TOK + s0 + qh * 32 + l15;
    float rhc0 = b2f(rhbase[(size_t)(ph * 32) * S_TOK]);
    float rhc1 = b2f(rhbase[(size_t)(ph * 32) * S_TOK + 16]);

    // ones A-frag for the denominator
    short8 aones;
#pragma unroll
    for (int j = 0; j < 8; ++j) aones[j] = (short)0x3F80;

    float4v od[2][4];
#pragma unroll
    for (int qt = 0; qt < 2; ++qt)
#pragma unroll
        for (int dt = 0; dt < 4; ++dt) od[qt][dt] = (float4v){0.f, 0.f, 0.f, 0.f};
    float4v dq0 = (float4v){0.f, 0.f, 0.f, 0.f};
    float4v dq1 = (float4v){0.f, 0.f, 0.f, 0.f};

    // ---- prologue: DMA K chunk (ph*32) into buf0; full drain once ----
    load_lds16(pKs,        lk0);
    load_lds16(pKs + 1024, lk0 + 8  * 64);
    load_lds16(pKs + 256,  lk0 + 16 * 64);
    load_lds16(pKs + 1280, lk0 + 24 * 64);
    __syncthreads();

#define S_PHASE(krd_)                                                          \
        unsigned pkk[2][8];                                                    \
        _Pragma("unroll")                                                      \
        for (int kt = 0; kt < 4; ++kt) {                                       \
            const char* krp = (const char*)((krd_) + (kt * 16 + l15) * 64);    \
            const short8 ka0 = *(const short8*)(krp + roff0);                  \
            const short8 ka1 = *(const short8*)(krp + roff1);                  \
            {                                                                  \
                float4v z = (float4v){0.f, 0.f, 0.f, 0.f};                     \
                z = __builtin_amdgcn_mfma_f32_16x16x32_bf16(ka0, qb[0][0], z, 0, 0, 0); \
                z = __builtin_amdgcn_mfma_f32_16x16x32_bf16(ka1, qb[0][1], z, 0, 0, 0); \
                float p0 = EXP2F(C1 * z[0] + (rhc0 + rwv[0][kt][0]));          \
                float p1 = EXP2F(C1 * z[1] + (rhc0 + rwv[0][kt][1]));          \
                float p2 = EXP2F(C1 * z[2] + (rhc0 + rwv[0][kt][2]));          \
                float p3 = EXP2F(C1 * z[3] + (rhc0 + rwv[0][kt][3]));          \
                pkk[0][kt * 2]     = pack_trunc(p0, p1);                       \
                pkk[0][kt * 2 + 1] = pack_trunc(p2, p3);                       \
            }                                                                  \
            {                                                                  \
                float4v z = (float4v){0.f, 0.f, 0.f, 0.f};                     \
                z = __builtin_amdgcn_mfma_f32_16x16x32_bf16(ka0, qb[1][0], z, 0, 0, 0); \
                z = __builtin_amdgcn_mfma_f32_16x16x32_bf16(ka1, qb[1][1], z, 0, 0, 0); \
                float p0 = EXP2F(C1 * z[0] + (rhc1 + rwv[1][kt][0]));          \
                float p1 = EXP2F(C1 * z[1] + (rhc1 + rwv[1][kt][1]));          \
                float p2 = EXP2F(C1 * z[2] + (rhc1 + rwv[1][kt][2]));          \
                float p3 = EXP2F(C1 * z[3] + (rhc1 + rwv[1][kt][3]));          \
                pkk[1][kt * 2]     = pack_trunc(p0, p1);                       \
                pkk[1][kt * 2 + 1] = pack_trunc(p2, p3);                       \
            }                                                                  \
        }                                                                      \
        const short8 pb00 = u4_to_s8(pkk[0][0], pkk[0][1], pkk[0][2], pkk[0][3]); \
        const short8 pb01 = u4_to_s8(pkk[0][4], pkk[0][5], pkk[0][6], pkk[0][7]); \
        const short8 pb10 = u4_to_s8(pkk[1][0], pkk[1][1], pkk[1][2], pkk[1][3]); \
        const short8 pb11 = u4_to_s8(pkk[1][4], pkk[1][5], pkk[1][6], pkk[1][7]);

#define PV_PHASE                                                               \
        __builtin_amdgcn_s_setprio(1);                                         \
        _Pragma("unroll")                                                      \
        for (int dt = 0; dt < 4; ++dt) {                                       \
            const char* vrp = (const char*)(vrd + (dt * 16 + l15) * 64);       \
            const short8 va0 = *(const short8*)(vrp + roff0);                  \
            const short8 va1 = *(const short8*)(vrp + roff1);                  \
            od[0][dt] = __builtin_amdgcn_mfma_f32_16x16x32_bf16(va0, pb00, od[0][dt], 0, 0, 0); \
            od[0][dt] = __builtin_amdgcn_mfma_f32_16x16x32_bf16(va1, pb01, od[0][dt], 0, 0, 0); \
            od[1][dt] = __builtin_amdgcn_mfma_f32_16x16x32_bf16(va0, pb10, od[1][dt], 0, 0, 0); \
            od[1][dt] = __builtin_amdgcn_mfma_f32_16x16x32_bf16(va1, pb11, od[1][dt], 0, 0, 0); \
        }                                                                      \
        dq0 = __builtin_amdgcn_mfma_f32_16x16x32_bf16(aones, pb00, dq0, 0, 0, 0); \
        dq0 = __builtin_amdgcn_mfma_f32_16x16x32_bf16(aones, pb01, dq0, 0, 0, 0); \
        dq1 = __builtin_amdgcn_mfma_f32_16x16x32_bf16(aones, pb10, dq1, 0, 0, 0); \
        dq1 = __builtin_amdgcn_mfma_f32_16x16x32_bf16(aones, pb11, dq1, 0, 0, 0); \
        __builtin_amdgcn_s_setprio(0);

    for (int t = 0; t < 31; ++t) {
        const int cur = t & 1;
        const short* krd = cur ? krd1 : krd0;
        short* lkn = cur ? lk0 : lk1;

        // ---- issue order pinned: V(t), rh(t+1), K(t+1) ----
        load_lds16(pVs,               lv);
        load_lds16(pVs + 8  * S_TOK,  lv + 8  * 64);
        load_lds16(pVs + 16 * S_TOK,  lv + 16 * 64);
        load_lds16(pVs + 24 * S_TOK,  lv + 24 * 64);
        asm volatile("" ::: "memory");
        short rhn0 = rhbase[(size_t)(ph * 32 + t + 1) * S_TOK];
        short rhn1 = rhbase[(size_t)(ph * 32 + t + 1) * S_TOK + 16];
        asm volatile("" ::: "memory");
        {
            const short* pk = pKs + 4096;
            load_lds16(pk,        lkn);
            load_lds16(pk + 1024, lkn + 8  * 64);
            load_lds16(pk + 256,  lkn + 16 * 64);
            load_lds16(pk + 1280, lkn + 24 * 64);
        }
        pKs += 4096;
        pVs += 64;

        // own K(t) drained (oldest 4); V/rh/K(t+1) stay in flight (10)
        asm volatile("s_waitcnt vmcnt(10)" ::: "memory");
        __builtin_amdgcn_sched_barrier(0);
        __builtin_amdgcn_s_barrier();         // bar1: ALL waves' K(t) visible

        S_PHASE(krd)

        // own V(t) drained; rh(2)+K(t+1)(4) stay in flight
        asm volatile("s_waitcnt vmcnt(6)" ::: "memory");
        __builtin_amdgcn_sched_barrier(0);
        __builtin_amdgcn_s_barrier();         // bar2: ALL waves' V(t) visible

        PV_PHASE

        rhc0 = b2f(rhn0);   // compiler emits vmcnt(4): K(t+1) keeps flying
        rhc1 = b2f(rhn1);

        __builtin_amdgcn_s_barrier();         // bar3: PV reads done before
                                              //        next step's V writes
    }

    // ---- peeled t = 31 (no prefetches; safe drains) ----
    {
        const short* krd = krd1;   // 31 & 1
        load_lds16(pVs,               lv);
        load_lds16(pVs + 8  * S_TOK,  lv + 8  * 64);
        load_lds16(pVs + 16 * S_TOK,  lv + 16 * 64);
        load_lds16(pVs + 24 * S_TOK,  lv + 24 * 64);

        asm volatile("s_waitcnt vmcnt(4)" ::: "memory");   // own K(31) done
        __builtin_amdgcn_sched_barrier(0);
        __builtin_amdgcn_s_barrier();

        S_PHASE(krd)

        asm volatile("s_waitcnt vmcnt(0)" ::: "memory");   // own V(31) done
        __builtin_amdgcn_sched_barrier(0);
        __builtin_amdgcn_s_barrier();

        PV_PHASE
    }
#undef S_PHASE
#undef PV_PHASE

    // ---- cross-pair combine (cf overlays K bufs: all K reads ended before
    //      the peeled bar2; cf does not overlap vrd, so no barrier needed
    //      between PV and the ph==1 cf writes) ----
    float* cf = (float*)lds_s;   // comb: [qh][qt][dt][16][16] floats; dq at 4096
    if (ph == 1) {
#pragma unroll
        for (int qt = 0; qt < 2; ++qt)
#pragma unroll
            for (int dt = 0; dt < 4; ++dt) {
                float* dst = &cf[((((qh * 2 + qt) * 4 + dt) * 16) + quad * 4) * 16 + l15];
#pragma unroll
                for (int r = 0; r < 4; ++r) dst[r * 16] = od[qt][dt][r];
            }
        if (quad == 0) {
            cf[4096 + (qh * 2 + 0) * 16 + l15] = dq0[0];
            cf[4096 + (qh * 2 + 1) * 16 + l15] = dq1[0];
        }
    }
    __syncthreads();
    if (ph == 0) {
#pragma unroll
        for (int qt = 0; qt < 2; ++qt) {
            const float dtot = ((qt == 0) ? dq0[0] : dq1[0])
                             + cf[4096 + (qh * 2 + qt) * 16 + l15];
            const float inv = 1.f / dtot;
            short* outp = attn_b + (size_t)(s0 + qh * 32 + qt * 16 + l15) * CDIM + head * HD;
#pragma unroll
            for (int dt = 0; dt < 4; ++dt) {
                const float* src = &cf[((((qh * 2 + qt) * 4 + dt) * 16) + quad * 4) * 16 + l15];
                short4v o4;
#pragma unroll
                for (int r = 0; r < 4; ++r)
                    o4[r] = f2b((od[qt][dt][r] + src[r * 16]) * inv);
                *(short4v*)(outp + dt * 16 + quad * 4) = o4;
            }
        }
    }
}

// ---------------------------------------------------------------------------
extern "C" void kernel_launch(void* const* d_in, const int* in_sizes, int n_in,
                              void* d_out, int out_size, void* d_ws, size_t ws_size,
                              hipStream_t stream)
{
    const float* x    = (const float*)d_in[0];
    const float* qkvw = (const float*)d_in[1];
    const float* qkvb = (const float*)d_in[2];
    const float* rph  = (const float*)d_in[3];
    const float* rpw  = (const float*)d_in[4];
    const float* pw   = (const float*)d_in[5];
    const float* pb   = (const float*)d_in[6];
    float* out = (float*)d_out;

    // ws layout (shorts), total ~48.8 MB
    const size_t HSD = (size_t)NH * S_TOK * HD;   // 3,145,728
    short* xb     = (short*)d_ws;                 // 4096*768
    short* wt     = xb + (size_t)S_TOK * CDIM;    // 2304*768 (qkv_w^T)
    short* pwt    = wt + (size_t)N3C * CDIM;      // 768*768  (proj_w^T)
    short* Qb     = pwt + (size_t)CDIM * CDIM;
    short* Kb     = Qb + HSD;
    short* Vt     = Kb + HSD;
    short* RelhT  = Vt + HSD;                     // [head][ky][s]
    short* Relw   = RelhT + HSD;
    short* attn_b = Relw + HSD;                   // 4096*768

    cast_bf16_kernel<<<S_TOK * CDIM / 4 / 256, 256, 0, stream>>>(x, xb, S_TOK * CDIM / 4);
    transpose_cast_kernel<<<dim3(N3C / 64, CDIM / 64), 256, 0, stream>>>(qkvw, wt, CDIM, N3C);
    transpose_cast_kernel<<<dim3(CDIM / 64, CDIM / 64), 256, 0, stream>>>(pw, pwt, CDIM, CDIM);

    gemm_qkv_mfma<<<dim3(N3C / 128, S_TOK / 128), 256, 0, stream>>>(
        xb, wt, qkvb, Qb, Kb, Vt);
    rel_mfma_kernel<<<dim3(64, NH), 256, 0, stream>>>(Qb, rph, rpw, RelhT, Relw);
    flash_kernel<<<dim3(64 * NH), 256, 0, stream>>>(Qb, Kb, Vt, RelhT, Relw, attn_b);
    gemm_proj_mfma<<<dim3(CDIM / 128, S_TOK / 128), 256, 0, stream>>>(
        attn_b, pwt, pb, out);
}

// Round 12
// 207.445 us; speedup vs baseline: 1.4862x; 1.0136x over previous
//
#include <hip/hip_runtime.h>
#include <hip/hip_bf16.h>

// Problem constants (B=1, H=W=64, C=768, nh=12, hd=64)
#define S_TOK 4096
#define CDIM  768
#define N3C   2304
#define NH    12
#define HD    64

#define LOG2E 1.44269504f

typedef __attribute__((ext_vector_type(8))) short short8;
typedef __attribute__((ext_vector_type(4))) short short4v;
typedef __attribute__((ext_vector_type(4))) float float4v;
typedef __attribute__((ext_vector_type(4))) unsigned uint4v;

__device__ __forceinline__ float b2f(short s) {
    return __uint_as_float(((unsigned)(unsigned short)s) << 16);
}
__device__ __forceinline__ short f2b(float f) {   // round-to-nearest-even
    unsigned u = __float_as_uint(f);
    unsigned r = (u + 0x7FFFu + ((u >> 16) & 1u)) >> 16;
    return (short)r;
}

#if __has_builtin(__builtin_amdgcn_exp2f)
#define EXP2F __builtin_amdgcn_exp2f
#else
#define EXP2F exp2f
#endif

// pack trunc-bf16(a) into low short, trunc-bf16(b) into high short
__device__ __forceinline__ unsigned pack_trunc(float a, float b) {
    return __builtin_amdgcn_perm(__float_as_uint(b), __float_as_uint(a), 0x07060302u);
}

__device__ __forceinline__ short8 u4_to_s8(unsigned a, unsigned b, unsigned c, unsigned d) {
    union { uint4v u; short8 s; } t;
    t.u = (uint4v){a, b, c, d};
    return t.s;
}

// async global->LDS DMA, 16B per lane, dest = ldsbase + lane*16 (linear)
__device__ __forceinline__ void load_lds16(const void* g, void* l) {
    __builtin_amdgcn_global_load_lds(
        (const __attribute__((address_space(1))) unsigned int*)g,
        (__attribute__((address_space(3))) unsigned int*)l, 16, 0, 0);
}

// ---------------------------------------------------------------------------
// Elementwise fp32 -> bf16 cast (4 elems/thread)
// ---------------------------------------------------------------------------
__global__ __launch_bounds__(256) void cast_bf16_kernel(
    const float* __restrict__ in, short* __restrict__ out, int n4)
{
    int i = blockIdx.x * 256 + threadIdx.x;
    if (i >= n4) return;
    float4 v = ((const float4*)in)[i];
    short4v o4 = { f2b(v.x), f2b(v.y), f2b(v.z), f2b(v.w) };
    *(short4v*)&out[(size_t)i * 4] = o4;
}

// ---------------------------------------------------------------------------
// Transpose + cast: in fp32 [R][C] -> out bf16 [C][R]. 64x64 tiles, 256 thr.
// ---------------------------------------------------------------------------
__global__ __launch_bounds__(256) void transpose_cast_kernel(
    const float* __restrict__ in, short* __restrict__ out, int R, int C)
{
    __shared__ float t[64][65];
    const int tid = threadIdx.x;
    const int c0 = blockIdx.x * 64, r0 = blockIdx.y * 64;
    const int li = tid >> 6;      // 0..3
    const int lj = tid & 63;
#pragma unroll
    for (int p = 0; p < 16; ++p) {
        int i = p * 4 + li;
        t[i][lj] = in[(size_t)(r0 + i) * C + c0 + lj];
    }
    __syncthreads();
#pragma unroll
    for (int p = 0; p < 16; ++p) {
        int i = p * 4 + li;
        out[(size_t)(c0 + i) * R + r0 + lj] = f2b(t[lj][i]);
    }
}

// ---------------------------------------------------------------------------
// MFMA GEMM core v3: C[128x128] = A[128xK] @ Bt[128xK]^T, caller provides
//   m0/n0 (enables XCD-chunked block swizzle). Staging via global_load_lds;
//   linear LDS dest, inverse swizzle folded into the per-lane GLOBAL source
//   address; frag reads apply the same XOR. smem is one 32 KB block so
//   epilogues can overlay it.
// ---------------------------------------------------------------------------
#define GEMM_CORE(A_, Bt_, m0_, n0_)                                           \
    __shared__ __align__(16) short smem[2][128][64];                           \
    auto a_s = smem[0];                                                        \
    auto b_s = smem[1];                                                        \
    const int tid  = threadIdx.x;                                              \
    const int m0 = (m0_);                                                      \
    const int n0 = (n0_);                                                      \
    const int lane = tid & 63, w = tid >> 6;                                   \
    const int l15 = lane & 15, quad = lane >> 4;                               \
    const int wr = w >> 1, wc = w & 1;                                         \
    const int roff0 = (quad ^ (l15 & 7)) << 4;                                 \
    const int roff1 = roff0 ^ 64;                                              \
    const int srow0 = w * 8 + (lane >> 3);                                     \
    const int sslot = (lane & 7) ^ ((lane >> 3) & 7);                          \
    const short* ga = A_ + (size_t)(m0 + srow0) * 768 + sslot * 8;             \
    const short* gb = Bt_ + (size_t)(n0 + srow0) * 768 + sslot * 8;            \
    short* la = &a_s[w * 8][0];                                                \
    short* lb = &b_s[w * 8][0];                                                \
    float4v acc[4][4];                                                         \
    _Pragma("unroll")                                                          \
    for (int i = 0; i < 4; ++i)                                                \
        _Pragma("unroll")                                                      \
        for (int j = 0; j < 4; ++j) acc[i][j] = (float4v){0.f,0.f,0.f,0.f};    \
    for (int k0 = 0; k0 < 768; k0 += 64) {                                     \
        __syncthreads();                                                       \
        _Pragma("unroll")                                                      \
        for (int i = 0; i < 4; ++i) {                                          \
            load_lds16(ga + (size_t)i * (32 * 768) + k0, la + i * 32 * 64);    \
            load_lds16(gb + (size_t)i * (32 * 768) + k0, lb + i * 32 * 64);    \
        }                                                                      \
        __syncthreads();                                                       \
        _Pragma("unroll")                                                      \
        for (int kk = 0; kk < 64; kk += 32) {                                  \
            const int roff = kk ? roff1 : roff0;                               \
            short8 af[4], bfr[4];                                              \
            _Pragma("unroll")                                                  \
            for (int i = 0; i < 4; ++i)                                        \
                af[i] = *(const short8*)((const char*)&a_s[wr*64 + i*16 + l15][0] + roff); \
            _Pragma("unroll")                                                  \
            for (int j = 0; j < 4; ++j)                                        \
                bfr[j] = *(const short8*)((const char*)&b_s[wc*64 + j*16 + l15][0] + roff); \
            _Pragma("unroll")                                                  \
            for (int i = 0; i < 4; ++i)                                        \
                _Pragma("unroll")                                              \
                for (int j = 0; j < 4; ++j)                                    \
                    acc[i][j] = __builtin_amdgcn_mfma_f32_16x16x32_bf16(       \
                        af[i], bfr[j], acc[i][j], 0, 0, 0);                    \
        }                                                                      \
    }

// QKV GEMM: writes Qb[head][s][d], Kb[head][s][d], Vt[head][d][s] (bf16)
// Grid: 576 1-D blocks, XCD-chunked swizzle (576 = 8 XCD x 72; 72 = 4m x 18n)
// -> per-XCD working set = 4 A-panels (784 KB) + B (3.5 MB) ~= L2-fit;
// A read once chip-wide. Epilogue: LDS-staged coalesced 16B stores.
__global__ __launch_bounds__(256) void gemm_qkv_mfma(
    const short* __restrict__ A, const short* __restrict__ Bt,
    const float* __restrict__ bias,
    short* __restrict__ Qb, short* __restrict__ Kb, short* __restrict__ Vt)
{
    const int flat = blockIdx.x;                    // 0..575
    const int logi = (flat & 7) * 72 + (flat >> 3); // bijective XCD chunking
    GEMM_CORE(A, Bt, (logi / 18) * 128, (logi % 18) * 128)

    const int sec = n0 / CDIM;      // tile fully inside one of q/k/v
    float bj[4];
#pragma unroll
    for (int j = 0; j < 4; ++j) bj[j] = bias[n0 + wc*64 + j*16 + l15];

    if (sec < 2) {
        short* base = (sec == 0) ? Qb : Kb;
        short (*tile)[68] = (short(*)[68])&smem[0][0][0];   // 128x68 = 17408 B
#pragma unroll
        for (int h = 0; h < 2; ++h) {
            __syncthreads();
            if (wc == h) {
#pragma unroll
                for (int i = 0; i < 4; ++i)
#pragma unroll
                    for (int j = 0; j < 4; ++j)
#pragma unroll
                        for (int r = 0; r < 4; ++r)
                            tile[wr*64 + i*16 + quad*4 + r][j*16 + l15] =
                                f2b(acc[i][j][r] + bj[j]);
            }
            __syncthreads();
            const int nn = (n0 % CDIM) + h * 64;
            const int head = nn >> 6;
            short* dst = base + ((size_t)head * S_TOK + m0) * HD;
#pragma unroll
            for (int it = 0; it < 4; ++it) {
                const int row = it * 32 + (tid >> 3), c = (tid & 7) * 8;
                *(short8*)&dst[(size_t)row * HD + c] = *(const short8*)&tile[row][c];
            }
        }
    } else {
        short (*tv)[130] = (short(*)[130])&smem[0][0][0];   // 64x130 = 16640 B
#pragma unroll
        for (int h = 0; h < 2; ++h) {
            __syncthreads();
            if (wc == h) {
#pragma unroll
                for (int i = 0; i < 4; ++i)
#pragma unroll
                    for (int j = 0; j < 4; ++j) {
                        short4v v4;
#pragma unroll
                        for (int r = 0; r < 4; ++r) v4[r] = f2b(acc[i][j][r] + bj[j]);
                        *(short4v*)&tv[j*16 + l15][wr*64 + i*16 + quad*4] = v4;
                    }
            }
            __syncthreads();
            const int nn = (n0 % CDIM) + h * 64;
            const int head = nn >> 6;
            short* dst = Vt + (size_t)head * HD * S_TOK + m0;
#pragma unroll
            for (int it = 0; it < 4; ++it) {
                const int nr = it * 16 + (tid >> 4), sc = (tid & 15) * 8;
                *(short8*)&dst[(size_t)nr * S_TOK + sc] = *(const short8*)&tv[nr][sc];
            }
        }
    }
}

// Proj GEMM: out fp32 [4096][768] = A @ Bt^T + bias
// Grid: 192 1-D blocks, XCD-chunked (192 = 8 x 24; 24 = 4m x 6n).
// Epilogue: LDS float tile (XOR chunk swizzle), coalesced float4 stores.
__global__ __launch_bounds__(256) void gemm_proj_mfma(
    const short* __restrict__ A, const short* __restrict__ Bt,
    const float* __restrict__ bias, float* __restrict__ out)
{
    const int flat = blockIdx.x;                    // 0..191
    const int logi = (flat & 7) * 24 + (flat >> 3); // bijective XCD chunking
    GEMM_CORE(A, Bt, (logi / 6) * 128, (logi % 6) * 128)

    float bj[4];
#pragma unroll
    for (int j = 0; j < 4; ++j) bj[j] = bias[n0 + wc*64 + j*16 + l15];

    float* tf = (float*)&smem[0][0][0];   // [64][128] floats, chunk-XOR layout
#pragma unroll
    for (int h = 0; h < 2; ++h) {
        __syncthreads();
        if (wr == h) {
#pragma unroll
            for (int i = 0; i < 4; ++i)
#pragma unroll
                for (int j = 0; j < 4; ++j) {
                    const int cc = wc*16 + j*4 + (l15 >> 2);   // float4-chunk idx
                    const int ci = l15 & 3;
#pragma unroll
                    for (int r = 0; r < 4; ++r) {
                        const int row = i*16 + quad*4 + r;
                        const int pc = cc ^ ((row & 7) << 2);
                        tf[row * 128 + pc * 4 + ci] = acc[i][j][r] + bj[j];
                    }
                }
        }
        __syncthreads();
        float* dst = out + (size_t)(m0 + h * 64) * CDIM + n0;
#pragma unroll
        for (int it = 0; it < 8; ++it) {
            const int row = it * 8 + (tid >> 5);
            const int gc = tid & 31;
            const int pc = gc ^ ((row & 7) << 2);
            float4 v = *(const float4*)&tf[row * 128 + pc * 4];
            *(float4*)&dst[(size_t)row * CDIM + gc * 4] = v;
        }
    }
}

// ---------------------------------------------------------------------------
// Rel-pos tables via MFMA. One block per (y, head); 64 queries s0=y*64..+63.
// Outputs PRE-SCALED by log2e. Relh stored TRANSPOSED: RelhT[head][ky][s].
// ---------------------------------------------------------------------------
__global__ __launch_bounds__(256) void rel_mfma_kernel(
    const short* __restrict__ Qb, const float* __restrict__ rph,
    const float* __restrict__ rpw, short* __restrict__ RelhT,
    short* __restrict__ Relw)
{
    __shared__ __align__(16) short q_s [64][72];
    __shared__ __align__(16) short rh_s[64][72];
    __shared__ __align__(16) short rw_s[128][72];

    const int tid  = threadIdx.x;
    const int y    = blockIdx.x;
    const int head = blockIdx.y;
    const int s0   = y * 64;
    const int w = tid >> 6, lane = tid & 63;
    const int l15 = lane & 15, quad = lane >> 4;
    const int srow = tid >> 2;            // 0..63
    const int scol = (tid & 3) << 4;      // 0,16,32,48

    // ---- stage Q (bf16 passthrough) ----
    {
        const uint4* g = (const uint4*)(Qb + ((size_t)head * S_TOK + s0 + srow) * HD + scol);
        *(uint4*)&q_s[srow][scol]     = g[0];
        *(uint4*)&q_s[srow][scol + 8] = g[1];
    }
    // ---- stage rph rows y..y+63 (fp32 -> bf16) ----
    {
        const float* g = rph + (size_t)(y + srow) * HD + scol;
        short tmp[16];
#pragma unroll
        for (int i = 0; i < 16; i += 4) {
            float4 v = *(const float4*)(g + i);
            tmp[i] = f2b(v.x); tmp[i+1] = f2b(v.y); tmp[i+2] = f2b(v.z); tmp[i+3] = f2b(v.w);
        }
        *(short8*)&rh_s[srow][scol]     = *(short8*)&tmp[0];
        *(short8*)&rh_s[srow][scol + 8] = *(short8*)&tmp[8];
    }
    // ---- stage rpw rows 0..127 (row 127 clamped; never consumed) ----
#pragma unroll
    for (int half = 0; half < 2; ++half) {
        const int row = srow + half * 64;
        const int rr  = row > 126 ? 126 : row;
        const float* g = rpw + (size_t)rr * HD + scol;
        short tmp[16];
#pragma unroll
        for (int i = 0; i < 16; i += 4) {
            float4 v = *(const float4*)(g + i);
            tmp[i] = f2b(v.x); tmp[i+1] = f2b(v.y); tmp[i+2] = f2b(v.z); tmp[i+3] = f2b(v.w);
        }
        *(short8*)&rw_s[row][scol]     = *(short8*)&tmp[0];
        *(short8*)&rw_s[row][scol + 8] = *(short8*)&tmp[8];
    }
    __syncthreads();

    const short8 qa0 = *(const short8*)&q_s[w * 16 + l15][quad * 8];
    const short8 qa1 = *(const short8*)&q_s[w * 16 + l15][32 + quad * 8];

    // ---- relh: RH col j = y+jj, ky = 63-jj; transposed short4v stores ----
#pragma unroll
    for (int ct = 0; ct < 4; ++ct) {
        const int jj = ct * 16 + l15;
        short8 b0 = *(const short8*)&rh_s[jj][quad * 8];
        short8 b1 = *(const short8*)&rh_s[jj][32 + quad * 8];
        float4v z = (float4v){0.f, 0.f, 0.f, 0.f};
        z = __builtin_amdgcn_mfma_f32_16x16x32_bf16(qa0, b0, z, 0, 0, 0);
        z = __builtin_amdgcn_mfma_f32_16x16x32_bf16(qa1, b1, z, 0, 0, 0);
        const int ky = 63 - jj;
        short4v o4;
#pragma unroll
        for (int r = 0; r < 4; ++r) o4[r] = f2b(z[r] * LOG2E);
        *(short4v*)&RelhT[((size_t)head * HD + ky) * S_TOK + s0 + w * 16 + quad * 4] = o4;
    }

    // ---- relw: kx = q+63-j, keep 0<=kx<64 ----
#pragma unroll
    for (int ct = 0; ct < 8; ++ct) {
        const int j = ct * 16 + l15;
        short8 b0 = *(const short8*)&rw_s[j][quad * 8];
        short8 b1 = *(const short8*)&rw_s[j][32 + quad * 8];
        float4v z = (float4v){0.f, 0.f, 0.f, 0.f};
        z = __builtin_amdgcn_mfma_f32_16x16x32_bf16(qa0, b0, z, 0, 0, 0);
        z = __builtin_amdgcn_mfma_f32_16x16x32_bf16(qa1, b1, z, 0, 0, 0);
#pragma unroll
        for (int r = 0; r < 4; ++r) {
            const int q  = w * 16 + quad * 4 + r;
            const int kx = q + 63 - j;
            if (kx >= 0 && kx < 64)
                Relw[((size_t)head * S_TOK + s0 + q) * HD + kx] = f2b(z[r] * LOG2E);
        }
    }
}

// ---------------------------------------------------------------------------
// Flash attention v14 (UNCHANGED from R11, 75.0 us measured): counted-vmcnt
// protocol, race-corrected. 3 light barriers/step, zero forced drains;
// wait-THEN-barrier so every cross-wave read follows a barrier at which all
// waves drained the relevant loads. K(t+1) crosses all barriers in flight.
// Pair-split, K-dbuf + V-single LDS, XCD head-group swizzle, 48 KB,
// 12 waves/CU, setprio on PV.
// ---------------------------------------------------------------------------
__global__ __launch_bounds__(256, 3) void flash_kernel(
    const short* __restrict__ Qb, const short* __restrict__ Kb,
    const short* __restrict__ Vt, const short* __restrict__ RelhT,
    const short* __restrict__ Relw, short* __restrict__ attn_b)
{
    // shorts 0..16383: K[pair][buf][64][64]; 16384..24575: V[pair][64][64]
    __shared__ __align__(16) short lds_s[24576];

    const int tid  = threadIdx.x;
    const int bid  = blockIdx.x;
    const int logi = (bid & 7) * 96 + (bid >> 3);   // XCD head-grouping swizzle
    const int head = logi >> 6;
    const int s0   = (logi & 63) << 6;
    const int w    = tid >> 6, lane = tid & 63;
    const int l15  = lane & 15, quad = lane >> 4;
    const int ph   = w >> 1;          // key-chunk half: chunks ph*32 + t
    const int qh   = w & 1;           // query half: queries qh*32 + ...

    const float C1 = 0.125f * LOG2E;

    // ---- staging lane mapping (linear dest, pre-swizzled source) ----
    const int lj = lane >> 3;             // row within 8-row DMA group
    const int sl = (lane & 7) ^ lj;       // logical 16B slot this lane fetches
    const int kf0 = (lj & 3) + ((lj & 4) << 1) + qh * 32;  // permuted key, ii=0

    const short* pKs = Kb + (size_t)head * S_TOK * HD
                     + (size_t)(ph * 32 * 64 + kf0) * HD + sl * 8;
    const short* pVs = Vt + ((size_t)head * HD + qh * 32 + lj) * S_TOK
                     + ph * 32 * 64 + sl * 8;

    // wave-uniform LDS dest bases (named; ternary select only)
    short* lk0 = &lds_s[(ph * 2 + 0) << 12] + qh * 32 * 64;
    short* lk1 = &lds_s[(ph * 2 + 1) << 12] + qh * 32 * 64;
    short* lv  = &lds_s[16384 + (ph << 12)] + qh * 32 * 64;
    const short* krd0 = &lds_s[(ph * 2 + 0) << 12];
    const short* krd1 = &lds_s[(ph * 2 + 1) << 12];
    const short* vrd  = &lds_s[16384 + (ph << 12)];

    // swizzled read byte-offsets (row&7 == l15&7 for all frag rows)
    const int roff0 = (quad ^ (l15 & 7)) << 4;   // logical slot quad
    const int roff1 = roff0 ^ 64;                // logical slot 4+quad

    // ---- Q B-frags: 2 q-tiles (32 queries per wave) ----
    short8 qb[2][2];
#pragma unroll
    for (int qt = 0; qt < 2; ++qt) {
        const short* qrow = Qb + ((size_t)head * S_TOK + s0 + qh * 32 + qt * 16 + l15) * HD;
        qb[qt][0] = *(const short8*)(qrow + quad * 8);
        qb[qt][1] = *(const short8*)(qrow + 32 + quad * 8);
    }

    // ---- relw invariants: rwv[qt][kt][r], key = kbase(kt) + quad*8 + r ----
    float rwv[2][4][4];
#pragma unroll
    for (int qt = 0; qt < 2; ++qt) {
        const short* rwrow = Relw + ((size_t)head * S_TOK + s0 + qh * 32 + qt * 16 + l15) * HD;
#pragma unroll
        for (int kt = 0; kt < 4; ++kt) {
            const int base = ((kt & 1) << 2) | ((kt >> 1) << 5);
            short4v v = *(const short4v*)(rwrow + base + quad * 8);
#pragma unroll
            for (int r = 0; r < 4; ++r) rwv[qt][kt][r] = b2f(v[r]);
        }
    }

    // RelhT[head][ky][s]: per-chunk coalesced loads (ky == chunk index)
    const short* rhbase = RelhT + (size_t)head * HD * S_TOK + s0 + qh * 32 + l15;
    float rhc0 = b2f(rhbase[(size_t)(ph * 32) * S_TOK]);
    float rhc1 = b2f(rhbase[(size_t)(ph * 32) * S_TOK + 16]);

    // ones A-frag for the denominator
    short8 aones;
#pragma unroll
    for (int j = 0; j < 8; ++j) aones[j] = (short)0x3F80;

    float4v od[2][4];
#pragma unroll
    for (int qt = 0; qt < 2; ++qt)
#pragma unroll
        for (int dt = 0; dt < 4; ++dt) od[qt][dt] = (float4v){0.f, 0.f, 0.f, 0.f};
    float4v dq0 = (float4v){0.f, 0.f, 0.f, 0.f};
    float4v dq1 = (float4v){0.f, 0.f, 0.f, 0.f};

    // ---- prologue: DMA K chunk (ph*32) into buf0; full drain once ----
    load_lds16(pKs,        lk0);
    load_lds16(pKs + 1024, lk0 + 8  * 64);
    load_lds16(pKs + 256,  lk0 + 16 * 64);
    load_lds16(pKs + 1280, lk0 + 24 * 64);
    __syncthreads();

#define S_PHASE(krd_)                                                          \
        unsigned pkk[2][8];                                                    \
        _Pragma("unroll")                                                      \
        for (int kt = 0; kt < 4; ++kt) {                                       \
            const char* krp = (const char*)((krd_) + (kt * 16 + l15) * 64);    \
            const short8 ka0 = *(const short8*)(krp + roff0);                  \
            const short8 ka1 = *(const short8*)(krp + roff1);                  \
            {                                                                  \
                float4v z = (float4v){0.f, 0.f, 0.f, 0.f};                     \
                z = __builtin_amdgcn_mfma_f32_16x16x32_bf16(ka0, qb[0][0], z, 0, 0, 0); \
                z = __builtin_amdgcn_mfma_f32_16x16x32_bf16(ka1, qb[0][1], z, 0, 0, 0); \
                float p0 = EXP2F(C1 * z[0] + (rhc0 + rwv[0][kt][0]));          \
                float p1 = EXP2F(C1 * z[1] + (rhc0 + rwv[0][kt][1]));          \
                float p2 = EXP2F(C1 * z[2] + (rhc0 + rwv[0][kt][2]));          \
                float p3 = EXP2F(C1 * z[3] + (rhc0 + rwv[0][kt][3]));          \
                pkk[0][kt * 2]     = pack_trunc(p0, p1);                       \
                pkk[0][kt * 2 + 1] = pack_trunc(p2, p3);                       \
            }                                                                  \
            {                                                                  \
                float4v z = (float4v){0.f, 0.f, 0.f, 0.f};                     \
                z = __builtin_amdgcn_mfma_f32_16x16x32_bf16(ka0, qb[1][0], z, 0, 0, 0); \
                z = __builtin_amdgcn_mfma_f32_16x16x32_bf16(ka1, qb[1][1], z, 0, 0, 0); \
                float p0 = EXP2F(C1 * z[0] + (rhc1 + rwv[1][kt][0]));          \
                float p1 = EXP2F(C1 * z[1] + (rhc1 + rwv[1][kt][1]));          \
                float p2 = EXP2F(C1 * z[2] + (rhc1 + rwv[1][kt][2]));          \
                float p3 = EXP2F(C1 * z[3] + (rhc1 + rwv[1][kt][3]));          \
                pkk[1][kt * 2]     = pack_trunc(p0, p1);                       \
                pkk[1][kt * 2 + 1] = pack_trunc(p2, p3);                       \
            }                                                                  \
        }                                                                      \
        const short8 pb00 = u4_to_s8(pkk[0][0], pkk[0][1], pkk[0][2], pkk[0][3]); \
        const short8 pb01 = u4_to_s8(pkk[0][4], pkk[0][5], pkk[0][6], pkk[0][7]); \
        const short8 pb10 = u4_to_s8(pkk[1][0], pkk[1][1], pkk[1][2], pkk[1][3]); \
        const short8 pb11 = u4_to_s8(pkk[1][4], pkk[1][5], pkk[1][6], pkk[1][7]);

#define PV_PHASE                                                               \
        __builtin_amdgcn_s_setprio(1);                                         \
        _Pragma("unroll")                                                      \
        for (int dt = 0; dt < 4; ++dt) {                                       \
            const char* vrp = (const char*)(vrd + (dt * 16 + l15) * 64);       \
            const short8 va0 = *(const short8*)(vrp + roff0);                  \
            const short8 va1 = *(const short8*)(vrp + roff1);                  \
            od[0][dt] = __builtin_amdgcn_mfma_f32_16x16x32_bf16(va0, pb00, od[0][dt], 0, 0, 0); \
            od[0][dt] = __builtin_amdgcn_mfma_f32_16x16x32_bf16(va1, pb01, od[0][dt], 0, 0, 0); \
            od[1][dt] = __builtin_amdgcn_mfma_f32_16x16x32_bf16(va0, pb10, od[1][dt], 0, 0, 0); \
            od[1][dt] = __builtin_amdgcn_mfma_f32_16x16x32_bf16(va1, pb11, od[1][dt], 0, 0, 0); \
        }                                                                      \
        dq0 = __builtin_amdgcn_mfma_f32_16x16x32_bf16(aones, pb00, dq0, 0, 0, 0); \
        dq0 = __builtin_amdgcn_mfma_f32_16x16x32_bf16(aones, pb01, dq0, 0, 0, 0); \
        dq1 = __builtin_amdgcn_mfma_f32_16x16x32_bf16(aones, pb10, dq1, 0, 0, 0); \
        dq1 = __builtin_amdgcn_mfma_f32_16x16x32_bf16(aones, pb11, dq1, 0, 0, 0); \
        __builtin_amdgcn_s_setprio(0);

    for (int t = 0; t < 31; ++t) {
        const int cur = t & 1;
        const short* krd = cur ? krd1 : krd0;
        short* lkn = cur ? lk0 : lk1;

        // ---- issue order pinned: V(t), rh(t+1), K(t+1) ----
        load_lds16(pVs,               lv);
        load_lds16(pVs + 8  * S_TOK,  lv + 8  * 64);
        load_lds16(pVs + 16 * S_TOK,  lv + 16 * 64);
        load_lds16(pVs + 24 * S_TOK,  lv + 24 * 64);
        asm volatile("" ::: "memory");
        short rhn0 = rhbase[(size_t)(ph * 32 + t + 1) * S_TOK];
        short rhn1 = rhbase[(size_t)(ph * 32 + t + 1) * S_TOK + 16];
        asm volatile("" ::: "memory");
        {
            const short* pk = pKs + 4096;
            load_lds16(pk,        lkn);
            load_lds16(pk + 1024, lkn + 8  * 64);
            load_lds16(pk + 256,  lkn + 16 * 64);
            load_lds16(pk + 1280, lkn + 24 * 64);
        }
        pKs += 4096;
        pVs += 64;

        // own K(t) drained (oldest 4); V/rh/K(t+1) stay in flight (10)
        asm volatile("s_waitcnt vmcnt(10)" ::: "memory");
        __builtin_amdgcn_sched_barrier(0);
        __builtin_amdgcn_s_barrier();         // bar1: ALL waves' K(t) visible

        S_PHASE(krd)

        // own V(t) drained; rh(2)+K(t+1)(4) stay in flight
        asm volatile("s_waitcnt vmcnt(6)" ::: "memory");
        __builtin_amdgcn_sched_barrier(0);
        __builtin_amdgcn_s_barrier();         // bar2: ALL waves' V(t) visible

        PV_PHASE

        rhc0 = b2f(rhn0);   // compiler emits vmcnt(4): K(t+1) keeps flying
        rhc1 = b2f(rhn1);

        __builtin_amdgcn_s_barrier();         // bar3: PV reads done before
                                              //        next step's V writes
    }

    // ---- peeled t = 31 (no prefetches; safe drains) ----
    {
        const short* krd = krd1;   // 31 & 1
        load_lds16(pVs,               lv);
        load_lds16(pVs + 8  * S_TOK,  lv + 8  * 64);
        load_lds16(pVs + 16 * S_TOK,  lv + 16 * 64);
        load_lds16(pVs + 24 * S_TOK,  lv + 24 * 64);

        asm volatile("s_waitcnt vmcnt(4)" ::: "memory");   // own K(31) done
        __builtin_amdgcn_sched_barrier(0);
        __builtin_amdgcn_s_barrier();

        S_PHASE(krd)

        asm volatile("s_waitcnt vmcnt(0)" ::: "memory");   // own V(31) done
        __builtin_amdgcn_sched_barrier(0);
        __builtin_amdgcn_s_barrier();

        PV_PHASE
    }
#undef S_PHASE
#undef PV_PHASE

    // ---- cross-pair combine (cf overlays K bufs: all K reads ended before
    //      the peeled bar2; cf does not overlap vrd, so no barrier needed
    //      between PV and the ph==1 cf writes) ----
    float* cf = (float*)lds_s;   // comb: [qh][qt][dt][16][16] floats; dq at 4096
    if (ph == 1) {
#pragma unroll
        for (int qt = 0; qt < 2; ++qt)
#pragma unroll
            for (int dt = 0; dt < 4; ++dt) {
                float* dst = &cf[((((qh * 2 + qt) * 4 + dt) * 16) + quad * 4) * 16 + l15];
#pragma unroll
                for (int r = 0; r < 4; ++r) dst[r * 16] = od[qt][dt][r];
            }
        if (quad == 0) {
            cf[4096 + (qh * 2 + 0) * 16 + l15] = dq0[0];
            cf[4096 + (qh * 2 + 1) * 16 + l15] = dq1[0];
        }
    }
    __syncthreads();
    if (ph == 0) {
#pragma unroll
        for (int qt = 0; qt < 2; ++qt) {
            const float dtot = ((qt == 0) ? dq0[0] : dq1[0])
                             + cf[4096 + (qh * 2 + qt) * 16 + l15];
            const float inv = 1.f / dtot;
            short* outp = attn_b + (size_t)(s0 + qh * 32 + qt * 16 + l15) * CDIM + head * HD;
#pragma unroll
            for (int dt = 0; dt < 4; ++dt) {
                const float* src = &cf[((((qh * 2 + qt) * 4 + dt) * 16) + quad * 4) * 16 + l15];
                short4v o4;
#pragma unroll
                for (int r = 0; r < 4; ++r)
                    o4[r] = f2b((od[qt][dt][r] + src[r * 16]) * inv);
                *(short4v*)(outp + dt * 16 + quad * 4) = o4;
            }
        }
    }
}

// ---------------------------------------------------------------------------
extern "C" void kernel_launch(void* const* d_in, const int* in_sizes, int n_in,
                              void* d_out, int out_size, void* d_ws, size_t ws_size,
                              hipStream_t stream)
{
    const float* x    = (const float*)d_in[0];
    const float* qkvw = (const float*)d_in[1];
    const float* qkvb = (const float*)d_in[2];
    const float* rph  = (const float*)d_in[3];
    const float* rpw  = (const float*)d_in[4];
    const float* pw   = (const float*)d_in[5];
    const float* pb   = (const float*)d_in[6];
    float* out = (float*)d_out;

    // ws layout (shorts), total ~48.8 MB
    const size_t HSD = (size_t)NH * S_TOK * HD;   // 3,145,728
    short* xb     = (short*)d_ws;                 // 4096*768
    short* wt     = xb + (size_t)S_TOK * CDIM;    // 2304*768 (qkv_w^T)
    short* pwt    = wt + (size_t)N3C * CDIM;      // 768*768  (proj_w^T)
    short* Qb     = pwt + (size_t)CDIM * CDIM;
    short* Kb     = Qb + HSD;
    short* Vt     = Kb + HSD;
    short* RelhT  = Vt + HSD;                     // [head][ky][s]
    short* Relw   = RelhT + HSD;
    short* attn_b = Relw + HSD;                   // 4096*768

    cast_bf16_kernel<<<S_TOK * CDIM / 4 / 256, 256, 0, stream>>>(x, xb, S_TOK * CDIM / 4);
    transpose_cast_kernel<<<dim3(N3C / 64, CDIM / 64), 256, 0, stream>>>(qkvw, wt, CDIM, N3C);
    transpose_cast_kernel<<<dim3(CDIM / 64, CDIM / 64), 256, 0, stream>>>(pw, pwt, CDIM, CDIM);

    gemm_qkv_mfma<<<dim3((N3C / 128) * (S_TOK / 128)), 256, 0, stream>>>(
        xb, wt, qkvb, Qb, Kb, Vt);
    rel_mfma_kernel<<<dim3(64, NH), 256, 0, stream>>>(Qb, rph, rpw, RelhT, Relw);
    flash_kernel<<<dim3(64 * NH), 256, 0, stream>>>(Qb, Kb, Vt, RelhT, Relw, attn_b);
    gemm_proj_mfma<<<dim3((CDIM / 128) * (S_TOK / 128)), 256, 0, stream>>>(
        attn_b, pwt, pb, out);
}

// Round 13
// 204.489 us; speedup vs baseline: 1.5077x; 1.0145x over previous
//
#include <hip/hip_runtime.h>
#include <hip/hip_bf16.h>

// Problem constants (B=1, H=W=64, C=768, nh=12, hd=64)
#define S_TOK 4096
#define CDIM  768
#define N3C   2304
#define NH    12
#define HD    64

#define LOG2E 1.44269504f

typedef __attribute__((ext_vector_type(8))) short short8;
typedef __attribute__((ext_vector_type(4))) short short4v;
typedef __attribute__((ext_vector_type(4))) float float4v;
typedef __attribute__((ext_vector_type(4))) unsigned uint4v;

__device__ __forceinline__ float b2f(short s) {
    return __uint_as_float(((unsigned)(unsigned short)s) << 16);
}
__device__ __forceinline__ short f2b(float f) {   // round-to-nearest-even
    unsigned u = __float_as_uint(f);
    unsigned r = (u + 0x7FFFu + ((u >> 16) & 1u)) >> 16;
    return (short)r;
}

#if __has_builtin(__builtin_amdgcn_exp2f)
#define EXP2F __builtin_amdgcn_exp2f
#else
#define EXP2F exp2f
#endif

// pack trunc-bf16(a) into low short, trunc-bf16(b) into high short
__device__ __forceinline__ unsigned pack_trunc(float a, float b) {
    return __builtin_amdgcn_perm(__float_as_uint(b), __float_as_uint(a), 0x07060302u);
}

__device__ __forceinline__ short8 u4_to_s8(unsigned a, unsigned b, unsigned c, unsigned d) {
    union { uint4v u; short8 s; } t;
    t.u = (uint4v){a, b, c, d};
    return t.s;
}

// async global->LDS DMA, 16B per lane, dest = ldsbase + lane*16 (linear)
__device__ __forceinline__ void load_lds16(const void* g, void* l) {
    __builtin_amdgcn_global_load_lds(
        (const __attribute__((address_space(1))) unsigned int*)g,
        (__attribute__((address_space(3))) unsigned int*)l, 16, 0, 0);
}

// ---------------------------------------------------------------------------
// Fused preprocessing: ONE kernel (saves 2 launch/tail boundaries).
//   blocks [0,432):   transpose+cast qkv_w fp32[768][2304] -> wt bf16[2304][768]
//   blocks [432,576): transpose+cast proj_w fp32[768][768] -> pwt bf16[768][768]
//   blocks [576,3648): elementwise cast x fp32 -> xb bf16 (4 elems/thread)
// ---------------------------------------------------------------------------
__global__ __launch_bounds__(256) void prep_kernel(
    const float* __restrict__ x, const float* __restrict__ qkvw,
    const float* __restrict__ pw,
    short* __restrict__ xb, short* __restrict__ wt, short* __restrict__ pwt)
{
    __shared__ float t[64][65];
    const int bid = blockIdx.x;
    const int tid = threadIdx.x;

    if (bid < 576) {
        const float* in;
        short* out;
        int C, bx, by;
        if (bid < 432) { in = qkvw; out = wt;  C = N3C;  bx = bid % 36;  by = bid / 36; }
        else           { in = pw;   out = pwt; C = CDIM; bx = (bid - 432) % 12; by = (bid - 432) / 12; }
        const int c0 = bx * 64, r0 = by * 64;
        const int li = tid >> 6;      // 0..3
        const int lj = tid & 63;
#pragma unroll
        for (int p = 0; p < 16; ++p) {
            int i = p * 4 + li;
            t[i][lj] = in[(size_t)(r0 + i) * C + c0 + lj];
        }
        __syncthreads();
#pragma unroll
        for (int p = 0; p < 16; ++p) {
            int i = p * 4 + li;
            out[(size_t)(c0 + i) * CDIM + r0 + lj] = f2b(t[lj][i]);
        }
    } else {
        const int i = (bid - 576) * 256 + tid;   // < 786432 by grid construction
        float4 v = ((const float4*)x)[i];
        short4v o4 = { f2b(v.x), f2b(v.y), f2b(v.z), f2b(v.w) };
        *(short4v*)&xb[(size_t)i * 4] = o4;
    }
}

// ---------------------------------------------------------------------------
// MFMA GEMM core v3: C[128x128] = A[128xK] @ Bt[128xK]^T, caller provides
//   m0/n0 (enables XCD-chunked block swizzle). Staging via global_load_lds;
//   linear LDS dest, inverse swizzle folded into the per-lane GLOBAL source
//   address; frag reads apply the same XOR. smem is one 32 KB block so
//   epilogues can overlay it.
// ---------------------------------------------------------------------------
#define GEMM_CORE(A_, Bt_, m0_, n0_)                                           \
    __shared__ __align__(16) short smem[2][128][64];                           \
    auto a_s = smem[0];                                                        \
    auto b_s = smem[1];                                                        \
    const int tid  = threadIdx.x;                                              \
    const int m0 = (m0_);                                                      \
    const int n0 = (n0_);                                                      \
    const int lane = tid & 63, w = tid >> 6;                                   \
    const int l15 = lane & 15, quad = lane >> 4;                               \
    const int wr = w >> 1, wc = w & 1;                                         \
    const int roff0 = (quad ^ (l15 & 7)) << 4;                                 \
    const int roff1 = roff0 ^ 64;                                              \
    const int srow0 = w * 8 + (lane >> 3);                                     \
    const int sslot = (lane & 7) ^ ((lane >> 3) & 7);                          \
    const short* ga = A_ + (size_t)(m0 + srow0) * 768 + sslot * 8;             \
    const short* gb = Bt_ + (size_t)(n0 + srow0) * 768 + sslot * 8;            \
    short* la = &a_s[w * 8][0];                                                \
    short* lb = &b_s[w * 8][0];                                                \
    float4v acc[4][4];                                                         \
    _Pragma("unroll")                                                          \
    for (int i = 0; i < 4; ++i)                                                \
        _Pragma("unroll")                                                      \
        for (int j = 0; j < 4; ++j) acc[i][j] = (float4v){0.f,0.f,0.f,0.f};    \
    for (int k0 = 0; k0 < 768; k0 += 64) {                                     \
        __syncthreads();                                                       \
        _Pragma("unroll")                                                      \
        for (int i = 0; i < 4; ++i) {                                          \
            load_lds16(ga + (size_t)i * (32 * 768) + k0, la + i * 32 * 64);    \
            load_lds16(gb + (size_t)i * (32 * 768) + k0, lb + i * 32 * 64);    \
        }                                                                      \
        __syncthreads();                                                       \
        _Pragma("unroll")                                                      \
        for (int kk = 0; kk < 64; kk += 32) {                                  \
            const int roff = kk ? roff1 : roff0;                               \
            short8 af[4], bfr[4];                                              \
            _Pragma("unroll")                                                  \
            for (int i = 0; i < 4; ++i)                                        \
                af[i] = *(const short8*)((const char*)&a_s[wr*64 + i*16 + l15][0] + roff); \
            _Pragma("unroll")                                                  \
            for (int j = 0; j < 4; ++j)                                        \
                bfr[j] = *(const short8*)((const char*)&b_s[wc*64 + j*16 + l15][0] + roff); \
            _Pragma("unroll")                                                  \
            for (int i = 0; i < 4; ++i)                                        \
                _Pragma("unroll")                                              \
                for (int j = 0; j < 4; ++j)                                    \
                    acc[i][j] = __builtin_amdgcn_mfma_f32_16x16x32_bf16(       \
                        af[i], bfr[j], acc[i][j], 0, 0, 0);                    \
        }                                                                      \
    }

// QKV GEMM: writes Qb[head][s][d], Kb[head][s][d], Vt[head][d][s] (bf16)
// Grid: 576 1-D blocks, XCD-chunked swizzle (576 = 8 XCD x 72; 72 = 4m x 18n).
// Epilogue: LDS-staged coalesced 16B stores.
__global__ __launch_bounds__(256) void gemm_qkv_mfma(
    const short* __restrict__ A, const short* __restrict__ Bt,
    const float* __restrict__ bias,
    short* __restrict__ Qb, short* __restrict__ Kb, short* __restrict__ Vt)
{
    const int flat = blockIdx.x;                    // 0..575
    const int logi = (flat & 7) * 72 + (flat >> 3); // bijective XCD chunking
    GEMM_CORE(A, Bt, (logi / 18) * 128, (logi % 18) * 128)

    const int sec = n0 / CDIM;      // tile fully inside one of q/k/v
    float bj[4];
#pragma unroll
    for (int j = 0; j < 4; ++j) bj[j] = bias[n0 + wc*64 + j*16 + l15];

    if (sec < 2) {
        short* base = (sec == 0) ? Qb : Kb;
        short (*tile)[68] = (short(*)[68])&smem[0][0][0];   // 128x68 = 17408 B
#pragma unroll
        for (int h = 0; h < 2; ++h) {
            __syncthreads();
            if (wc == h) {
#pragma unroll
                for (int i = 0; i < 4; ++i)
#pragma unroll
                    for (int j = 0; j < 4; ++j)
#pragma unroll
                        for (int r = 0; r < 4; ++r)
                            tile[wr*64 + i*16 + quad*4 + r][j*16 + l15] =
                                f2b(acc[i][j][r] + bj[j]);
            }
            __syncthreads();
            const int nn = (n0 % CDIM) + h * 64;
            const int head = nn >> 6;
            short* dst = base + ((size_t)head * S_TOK + m0) * HD;
#pragma unroll
            for (int it = 0; it < 4; ++it) {
                const int row = it * 32 + (tid >> 3), c = (tid & 7) * 8;
                *(short8*)&dst[(size_t)row * HD + c] = *(const short8*)&tile[row][c];
            }
        }
    } else {
        short (*tv)[130] = (short(*)[130])&smem[0][0][0];   // 64x130 = 16640 B
#pragma unroll
        for (int h = 0; h < 2; ++h) {
            __syncthreads();
            if (wc == h) {
#pragma unroll
                for (int i = 0; i < 4; ++i)
#pragma unroll
                    for (int j = 0; j < 4; ++j) {
                        short4v v4;
#pragma unroll
                        for (int r = 0; r < 4; ++r) v4[r] = f2b(acc[i][j][r] + bj[j]);
                        *(short4v*)&tv[j*16 + l15][wr*64 + i*16 + quad*4] = v4;
                    }
            }
            __syncthreads();
            const int nn = (n0 % CDIM) + h * 64;
            const int head = nn >> 6;
            short* dst = Vt + (size_t)head * HD * S_TOK + m0;
#pragma unroll
            for (int it = 0; it < 4; ++it) {
                const int nr = it * 16 + (tid >> 4), sc = (tid & 15) * 8;
                *(short8*)&dst[(size_t)nr * S_TOK + sc] = *(const short8*)&tv[nr][sc];
            }
        }
    }
}

// Proj GEMM: out fp32 [4096][768] = A @ Bt^T + bias
// Grid: 192 1-D blocks, XCD-chunked (192 = 8 x 24; 24 = 4m x 6n).
// Epilogue: LDS float tile (XOR chunk swizzle), coalesced float4 stores.
__global__ __launch_bounds__(256) void gemm_proj_mfma(
    const short* __restrict__ A, const short* __restrict__ Bt,
    const float* __restrict__ bias, float* __restrict__ out)
{
    const int flat = blockIdx.x;                    // 0..191
    const int logi = (flat & 7) * 24 + (flat >> 3); // bijective XCD chunking
    GEMM_CORE(A, Bt, (logi / 6) * 128, (logi % 6) * 128)

    float bj[4];
#pragma unroll
    for (int j = 0; j < 4; ++j) bj[j] = bias[n0 + wc*64 + j*16 + l15];

    float* tf = (float*)&smem[0][0][0];   // [64][128] floats, chunk-XOR layout
#pragma unroll
    for (int h = 0; h < 2; ++h) {
        __syncthreads();
        if (wr == h) {
#pragma unroll
            for (int i = 0; i < 4; ++i)
#pragma unroll
                for (int j = 0; j < 4; ++j) {
                    const int cc = wc*16 + j*4 + (l15 >> 2);   // float4-chunk idx
                    const int ci = l15 & 3;
#pragma unroll
                    for (int r = 0; r < 4; ++r) {
                        const int row = i*16 + quad*4 + r;
                        const int pc = cc ^ ((row & 7) << 2);
                        tf[row * 128 + pc * 4 + ci] = acc[i][j][r] + bj[j];
                    }
                }
        }
        __syncthreads();
        float* dst = out + (size_t)(m0 + h * 64) * CDIM + n0;
#pragma unroll
        for (int it = 0; it < 8; ++it) {
            const int row = it * 8 + (tid >> 5);
            const int gc = tid & 31;
            const int pc = gc ^ ((row & 7) << 2);
            float4 v = *(const float4*)&tf[row * 128 + pc * 4];
            *(float4*)&dst[(size_t)row * CDIM + gc * 4] = v;
        }
    }
}

// ---------------------------------------------------------------------------
// Rel-pos tables via MFMA. One block per (y, head); 64 queries s0=y*64..+63.
// Outputs PRE-SCALED by log2e. Relh stored TRANSPOSED: RelhT[head][ky][s].
// Relw epilogue: LDS-staged (relw_t) -> fully-coalesced 16B row stores
// (replaces 32 predicated scalar 2B global stores per thread).
// ---------------------------------------------------------------------------
__global__ __launch_bounds__(256) void rel_mfma_kernel(
    const short* __restrict__ Qb, const float* __restrict__ rph,
    const float* __restrict__ rpw, short* __restrict__ RelhT,
    short* __restrict__ Relw)
{
    __shared__ __align__(16) short q_s [64][72];
    __shared__ __align__(16) short rh_s[64][72];
    __shared__ __align__(16) short rw_s[128][72];
    __shared__ __align__(16) short relw_t[64][64];

    const int tid  = threadIdx.x;
    const int y    = blockIdx.x;
    const int head = blockIdx.y;
    const int s0   = y * 64;
    const int w = tid >> 6, lane = tid & 63;
    const int l15 = lane & 15, quad = lane >> 4;
    const int srow = tid >> 2;            // 0..63
    const int scol = (tid & 3) << 4;      // 0,16,32,48

    // ---- stage Q (bf16 passthrough) ----
    {
        const uint4* g = (const uint4*)(Qb + ((size_t)head * S_TOK + s0 + srow) * HD + scol);
        *(uint4*)&q_s[srow][scol]     = g[0];
        *(uint4*)&q_s[srow][scol + 8] = g[1];
    }
    // ---- stage rph rows y..y+63 (fp32 -> bf16) ----
    {
        const float* g = rph + (size_t)(y + srow) * HD + scol;
        short tmp[16];
#pragma unroll
        for (int i = 0; i < 16; i += 4) {
            float4 v = *(const float4*)(g + i);
            tmp[i] = f2b(v.x); tmp[i+1] = f2b(v.y); tmp[i+2] = f2b(v.z); tmp[i+3] = f2b(v.w);
        }
        *(short8*)&rh_s[srow][scol]     = *(short8*)&tmp[0];
        *(short8*)&rh_s[srow][scol + 8] = *(short8*)&tmp[8];
    }
    // ---- stage rpw rows 0..127 (row 127 clamped; never consumed) ----
#pragma unroll
    for (int half = 0; half < 2; ++half) {
        const int row = srow + half * 64;
        const int rr  = row > 126 ? 126 : row;
        const float* g = rpw + (size_t)rr * HD + scol;
        short tmp[16];
#pragma unroll
        for (int i = 0; i < 16; i += 4) {
            float4 v = *(const float4*)(g + i);
            tmp[i] = f2b(v.x); tmp[i+1] = f2b(v.y); tmp[i+2] = f2b(v.z); tmp[i+3] = f2b(v.w);
        }
        *(short8*)&rw_s[row][scol]     = *(short8*)&tmp[0];
        *(short8*)&rw_s[row][scol + 8] = *(short8*)&tmp[8];
    }
    __syncthreads();

    const short8 qa0 = *(const short8*)&q_s[w * 16 + l15][quad * 8];
    const short8 qa1 = *(const short8*)&q_s[w * 16 + l15][32 + quad * 8];

    // ---- relh: RH col j = y+jj, ky = 63-jj; transposed short4v stores ----
#pragma unroll
    for (int ct = 0; ct < 4; ++ct) {
        const int jj = ct * 16 + l15;
        short8 b0 = *(const short8*)&rh_s[jj][quad * 8];
        short8 b1 = *(const short8*)&rh_s[jj][32 + quad * 8];
        float4v z = (float4v){0.f, 0.f, 0.f, 0.f};
        z = __builtin_amdgcn_mfma_f32_16x16x32_bf16(qa0, b0, z, 0, 0, 0);
        z = __builtin_amdgcn_mfma_f32_16x16x32_bf16(qa1, b1, z, 0, 0, 0);
        const int ky = 63 - jj;
        short4v o4;
#pragma unroll
        for (int r = 0; r < 4; ++r) o4[r] = f2b(z[r] * LOG2E);
        *(short4v*)&RelhT[((size_t)head * HD + ky) * S_TOK + s0 + w * 16 + quad * 4] = o4;
    }

    // ---- relw: kx = q+63-j, keep 0<=kx<64; stage into LDS ----
#pragma unroll
    for (int ct = 0; ct < 8; ++ct) {
        const int j = ct * 16 + l15;
        short8 b0 = *(const short8*)&rw_s[j][quad * 8];
        short8 b1 = *(const short8*)&rw_s[j][32 + quad * 8];
        float4v z = (float4v){0.f, 0.f, 0.f, 0.f};
        z = __builtin_amdgcn_mfma_f32_16x16x32_bf16(qa0, b0, z, 0, 0, 0);
        z = __builtin_amdgcn_mfma_f32_16x16x32_bf16(qa1, b1, z, 0, 0, 0);
#pragma unroll
        for (int r = 0; r < 4; ++r) {
            const int q  = w * 16 + quad * 4 + r;
            const int kx = q + 63 - j;
            if (kx >= 0 && kx < 64)
                relw_t[q][kx] = f2b(z[r] * LOG2E);
        }
    }
    __syncthreads();
    // coalesced: thread -> row tid>>2, 16 cols at (tid&3)*16
    {
        const int row = tid >> 2, c = (tid & 3) * 16;
        short* dst = Relw + ((size_t)head * S_TOK + s0 + row) * HD + c;
        *(short8*)(dst)     = *(const short8*)&relw_t[row][c];
        *(short8*)(dst + 8) = *(const short8*)&relw_t[row][c + 8];
    }
}

// ---------------------------------------------------------------------------
// Flash attention v14 (UNCHANGED, 75.0 us measured): counted-vmcnt protocol,
// race-corrected. 3 light barriers/step, zero forced drains; wait-THEN-barrier
// so every cross-wave read follows a barrier at which all waves drained the
// relevant loads. K(t+1) crosses all barriers in flight. Pair-split, K-dbuf +
// V-single LDS, XCD head-group swizzle, 48 KB, 12 waves/CU, setprio on PV.
// ---------------------------------------------------------------------------
__global__ __launch_bounds__(256, 3) void flash_kernel(
    const short* __restrict__ Qb, const short* __restrict__ Kb,
    const short* __restrict__ Vt, const short* __restrict__ RelhT,
    const short* __restrict__ Relw, short* __restrict__ attn_b)
{
    // shorts 0..16383: K[pair][buf][64][64]; 16384..24575: V[pair][64][64]
    __shared__ __align__(16) short lds_s[24576];

    const int tid  = threadIdx.x;
    const int bid  = blockIdx.x;
    const int logi = (bid & 7) * 96 + (bid >> 3);   // XCD head-grouping swizzle
    const int head = logi >> 6;
    const int s0   = (logi & 63) << 6;
    const int w    = tid >> 6, lane = tid & 63;
    const int l15  = lane & 15, quad = lane >> 4;
    const int ph   = w >> 1;          // key-chunk half: chunks ph*32 + t
    const int qh   = w & 1;           // query half: queries qh*32 + ...

    const float C1 = 0.125f * LOG2E;

    // ---- staging lane mapping (linear dest, pre-swizzled source) ----
    const int lj = lane >> 3;             // row within 8-row DMA group
    const int sl = (lane & 7) ^ lj;       // logical 16B slot this lane fetches
    const int kf0 = (lj & 3) + ((lj & 4) << 1) + qh * 32;  // permuted key, ii=0

    const short* pKs = Kb + (size_t)head * S_TOK * HD
                     + (size_t)(ph * 32 * 64 + kf0) * HD + sl * 8;
    const short* pVs = Vt + ((size_t)head * HD + qh * 32 + lj) * S_TOK
                     + ph * 32 * 64 + sl * 8;

    // wave-uniform LDS dest bases (named; ternary select only)
    short* lk0 = &lds_s[(ph * 2 + 0) << 12] + qh * 32 * 64;
    short* lk1 = &lds_s[(ph * 2 + 1) << 12] + qh * 32 * 64;
    short* lv  = &lds_s[16384 + (ph << 12)] + qh * 32 * 64;
    const short* krd0 = &lds_s[(ph * 2 + 0) << 12];
    const short* krd1 = &lds_s[(ph * 2 + 1) << 12];
    const short* vrd  = &lds_s[16384 + (ph << 12)];

    // swizzled read byte-offsets (row&7 == l15&7 for all frag rows)
    const int roff0 = (quad ^ (l15 & 7)) << 4;   // logical slot quad
    const int roff1 = roff0 ^ 64;                // logical slot 4+quad

    // ---- Q B-frags: 2 q-tiles (32 queries per wave) ----
    short8 qb[2][2];
#pragma unroll
    for (int qt = 0; qt < 2; ++qt) {
        const short* qrow = Qb + ((size_t)head * S_TOK + s0 + qh * 32 + qt * 16 + l15) * HD;
        qb[qt][0] = *(const short8*)(qrow + quad * 8);
        qb[qt][1] = *(const short8*)(qrow + 32 + quad * 8);
    }

    // ---- relw invariants: rwv[qt][kt][r], key = kbase(kt) + quad*8 + r ----
    float rwv[2][4][4];
#pragma unroll
    for (int qt = 0; qt < 2; ++qt) {
        const short* rwrow = Relw + ((size_t)head * S_TOK + s0 + qh * 32 + qt * 16 + l15) * HD;
#pragma unroll
        for (int kt = 0; kt < 4; ++kt) {
            const int base = ((kt & 1) << 2) | ((kt >> 1) << 5);
            short4v v = *(const short4v*)(rwrow + base + quad * 8);
#pragma unroll
            for (int r = 0; r < 4; ++r) rwv[qt][kt][r] = b2f(v[r]);
        }
    }

    // RelhT[head][ky][s]: per-chunk coalesced loads (ky == chunk index)
    const short* rhbase = RelhT + (size_t)head * HD * S_TOK + s0 + qh * 32 + l15;
    float rhc0 = b2f(rhbase[(size_t)(ph * 32) * S_TOK]);
    float rhc1 = b2f(rhbase[(size_t)(ph * 32) * S_TOK + 16]);

    // ones A-frag for the denominator
    short8 aones;
#pragma unroll
    for (int j = 0; j < 8; ++j) aones[j] = (short)0x3F80;

    float4v od[2][4];
#pragma unroll
    for (int qt = 0; qt < 2; ++qt)
#pragma unroll
        for (int dt = 0; dt < 4; ++dt) od[qt][dt] = (float4v){0.f, 0.f, 0.f, 0.f};
    float4v dq0 = (float4v){0.f, 0.f, 0.f, 0.f};
    float4v dq1 = (float4v){0.f, 0.f, 0.f, 0.f};

    // ---- prologue: DMA K chunk (ph*32) into buf0; full drain once ----
    load_lds16(pKs,        lk0);
    load_lds16(pKs + 1024, lk0 + 8  * 64);
    load_lds16(pKs + 256,  lk0 + 16 * 64);
    load_lds16(pKs + 1280, lk0 + 24 * 64);
    __syncthreads();

#define S_PHASE(krd_)                                                          \
        unsigned pkk[2][8];                                                    \
        _Pragma("unroll")                                                      \
        for (int kt = 0; kt < 4; ++kt) {                                       \
            const char* krp = (const char*)((krd_) + (kt * 16 + l15) * 64);    \
            const short8 ka0 = *(const short8*)(krp + roff0);                  \
            const short8 ka1 = *(const short8*)(krp + roff1);                  \
            {                                                                  \
                float4v z = (float4v){0.f, 0.f, 0.f, 0.f};                     \
                z = __builtin_amdgcn_mfma_f32_16x16x32_bf16(ka0, qb[0][0], z, 0, 0, 0); \
                z = __builtin_amdgcn_mfma_f32_16x16x32_bf16(ka1, qb[0][1], z, 0, 0, 0); \
                float p0 = EXP2F(C1 * z[0] + (rhc0 + rwv[0][kt][0]));          \
                float p1 = EXP2F(C1 * z[1] + (rhc0 + rwv[0][kt][1]));          \
                float p2 = EXP2F(C1 * z[2] + (rhc0 + rwv[0][kt][2]));          \
                float p3 = EXP2F(C1 * z[3] + (rhc0 + rwv[0][kt][3]));          \
                pkk[0][kt * 2]     = pack_trunc(p0, p1);                       \
                pkk[0][kt * 2 + 1] = pack_trunc(p2, p3);                       \
            }                                                                  \
            {                                                                  \
                float4v z = (float4v){0.f, 0.f, 0.f, 0.f};                     \
                z = __builtin_amdgcn_mfma_f32_16x16x32_bf16(ka0, qb[1][0], z, 0, 0, 0); \
                z = __builtin_amdgcn_mfma_f32_16x16x32_bf16(ka1, qb[1][1], z, 0, 0, 0); \
                float p0 = EXP2F(C1 * z[0] + (rhc1 + rwv[1][kt][0]));          \
                float p1 = EXP2F(C1 * z[1] + (rhc1 + rwv[1][kt][1]));          \
                float p2 = EXP2F(C1 * z[2] + (rhc1 + rwv[1][kt][2]));          \
                float p3 = EXP2F(C1 * z[3] + (rhc1 + rwv[1][kt][3]));          \
                pkk[1][kt * 2]     = pack_trunc(p0, p1);                       \
                pkk[1][kt * 2 + 1] = pack_trunc(p2, p3);                       \
            }                                                                  \
        }                                                                      \
        const short8 pb00 = u4_to_s8(pkk[0][0], pkk[0][1], pkk[0][2], pkk[0][3]); \
        const short8 pb01 = u4_to_s8(pkk[0][4], pkk[0][5], pkk[0][6], pkk[0][7]); \
        const short8 pb10 = u4_to_s8(pkk[1][0], pkk[1][1], pkk[1][2], pkk[1][3]); \
        const short8 pb11 = u4_to_s8(pkk[1][4], pkk[1][5], pkk[1][6], pkk[1][7]);

#define PV_PHASE                                                               \
        __builtin_amdgcn_s_setprio(1);                                         \
        _Pragma("unroll")                                                      \
        for (int dt = 0; dt < 4; ++dt) {                                       \
            const char* vrp = (const char*)(vrd + (dt * 16 + l15) * 64);       \
            const short8 va0 = *(const short8*)(vrp + roff0);                  \
            const short8 va1 = *(const short8*)(vrp + roff1);                  \
            od[0][dt] = __builtin_amdgcn_mfma_f32_16x16x32_bf16(va0, pb00, od[0][dt], 0, 0, 0); \
            od[0][dt] = __builtin_amdgcn_mfma_f32_16x16x32_bf16(va1, pb01, od[0][dt], 0, 0, 0); \
            od[1][dt] = __builtin_amdgcn_mfma_f32_16x16x32_bf16(va0, pb10, od[1][dt], 0, 0, 0); \
            od[1][dt] = __builtin_amdgcn_mfma_f32_16x16x32_bf16(va1, pb11, od[1][dt], 0, 0, 0); \
        }                                                                      \
        dq0 = __builtin_amdgcn_mfma_f32_16x16x32_bf16(aones, pb00, dq0, 0, 0, 0); \
        dq0 = __builtin_amdgcn_mfma_f32_16x16x32_bf16(aones, pb01, dq0, 0, 0, 0); \
        dq1 = __builtin_amdgcn_mfma_f32_16x16x32_bf16(aones, pb10, dq1, 0, 0, 0); \
        dq1 = __builtin_amdgcn_mfma_f32_16x16x32_bf16(aones, pb11, dq1, 0, 0, 0); \
        __builtin_amdgcn_s_setprio(0);

    for (int t = 0; t < 31; ++t) {
        const int cur = t & 1;
        const short* krd = cur ? krd1 : krd0;
        short* lkn = cur ? lk0 : lk1;

        // ---- issue order pinned: V(t), rh(t+1), K(t+1) ----
        load_lds16(pVs,               lv);
        load_lds16(pVs + 8  * S_TOK,  lv + 8  * 64);
        load_lds16(pVs + 16 * S_TOK,  lv + 16 * 64);
        load_lds16(pVs + 24 * S_TOK,  lv + 24 * 64);
        asm volatile("" ::: "memory");
        short rhn0 = rhbase[(size_t)(ph * 32 + t + 1) * S_TOK];
        short rhn1 = rhbase[(size_t)(ph * 32 + t + 1) * S_TOK + 16];
        asm volatile("" ::: "memory");
        {
            const short* pk = pKs + 4096;
            load_lds16(pk,        lkn);
            load_lds16(pk + 1024, lkn + 8  * 64);
            load_lds16(pk + 256,  lkn + 16 * 64);
            load_lds16(pk + 1280, lkn + 24 * 64);
        }
        pKs += 4096;
        pVs += 64;

        // own K(t) drained (oldest 4); V/rh/K(t+1) stay in flight (10)
        asm volatile("s_waitcnt vmcnt(10)" ::: "memory");
        __builtin_amdgcn_sched_barrier(0);
        __builtin_amdgcn_s_barrier();         // bar1: ALL waves' K(t) visible

        S_PHASE(krd)

        // own V(t) drained; rh(2)+K(t+1)(4) stay in flight
        asm volatile("s_waitcnt vmcnt(6)" ::: "memory");
        __builtin_amdgcn_sched_barrier(0);
        __builtin_amdgcn_s_barrier();         // bar2: ALL waves' V(t) visible

        PV_PHASE

        rhc0 = b2f(rhn0);   // compiler emits vmcnt(4): K(t+1) keeps flying
        rhc1 = b2f(rhn1);

        __builtin_amdgcn_s_barrier();         // bar3: PV reads done before
                                              //        next step's V writes
    }

    // ---- peeled t = 31 (no prefetches; safe drains) ----
    {
        const short* krd = krd1;   // 31 & 1
        load_lds16(pVs,               lv);
        load_lds16(pVs + 8  * S_TOK,  lv + 8  * 64);
        load_lds16(pVs + 16 * S_TOK,  lv + 16 * 64);
        load_lds16(pVs + 24 * S_TOK,  lv + 24 * 64);

        asm volatile("s_waitcnt vmcnt(4)" ::: "memory");   // own K(31) done
        __builtin_amdgcn_sched_barrier(0);
        __builtin_amdgcn_s_barrier();

        S_PHASE(krd)

        asm volatile("s_waitcnt vmcnt(0)" ::: "memory");   // own V(31) done
        __builtin_amdgcn_sched_barrier(0);
        __builtin_amdgcn_s_barrier();

        PV_PHASE
    }
#undef S_PHASE
#undef PV_PHASE

    // ---- cross-pair combine (cf overlays K bufs: all K reads ended before
    //      the peeled bar2; cf does not overlap vrd, so no barrier needed
    //      between PV and the ph==1 cf writes) ----
    float* cf = (float*)lds_s;   // comb: [qh][qt][dt][16][16] floats; dq at 4096
    if (ph == 1) {
#pragma unroll
        for (int qt = 0; qt < 2; ++qt)
#pragma unroll
            for (int dt = 0; dt < 4; ++dt) {
                float* dst = &cf[((((qh * 2 + qt) * 4 + dt) * 16) + quad * 4) * 16 + l15];
#pragma unroll
                for (int r = 0; r < 4; ++r) dst[r * 16] = od[qt][dt][r];
            }
        if (quad == 0) {
            cf[4096 + (qh * 2 + 0) * 16 + l15] = dq0[0];
            cf[4096 + (qh * 2 + 1) * 16 + l15] = dq1[0];
        }
    }
    __syncthreads();
    if (ph == 0) {
#pragma unroll
        for (int qt = 0; qt < 2; ++qt) {
            const float dtot = ((qt == 0) ? dq0[0] : dq1[0])
                             + cf[4096 + (qh * 2 + qt) * 16 + l15];
            const float inv = 1.f / dtot;
            short* outp = attn_b + (size_t)(s0 + qh * 32 + qt * 16 + l15) * CDIM + head * HD;
#pragma unroll
            for (int dt = 0; dt < 4; ++dt) {
                const float* src = &cf[((((qh * 2 + qt) * 4 + dt) * 16) + quad * 4) * 16 + l15];
                short4v o4;
#pragma unroll
                for (int r = 0; r < 4; ++r)
                    o4[r] = f2b((od[qt][dt][r] + src[r * 16]) * inv);
                *(short4v*)(outp + dt * 16 + quad * 4) = o4;
            }
        }
    }
}

// ---------------------------------------------------------------------------
extern "C" void kernel_launch(void* const* d_in, const int* in_sizes, int n_in,
                              void* d_out, int out_size, void* d_ws, size_t ws_size,
                              hipStream_t stream)
{
    const float* x    = (const float*)d_in[0];
    const float* qkvw = (const float*)d_in[1];
    const float* qkvb = (const float*)d_in[2];
    const float* rph  = (const float*)d_in[3];
    const float* rpw  = (const float*)d_in[4];
    const float* pw   = (const float*)d_in[5];
    const float* pb   = (const float*)d_in[6];
    float* out = (float*)d_out;

    // ws layout (shorts), total ~48.8 MB
    const size_t HSD = (size_t)NH * S_TOK * HD;   // 3,145,728
    short* xb     = (short*)d_ws;                 // 4096*768
    short* wt     = xb + (size_t)S_TOK * CDIM;    // 2304*768 (qkv_w^T)
    short* pwt    = wt + (size_t)N3C * CDIM;      // 768*768  (proj_w^T)
    short* Qb     = pwt + (size_t)CDIM * CDIM;
    short* Kb     = Qb + HSD;
    short* Vt     = Kb + HSD;
    short* RelhT  = Vt + HSD;                     // [head][ky][s]
    short* Relw   = RelhT + HSD;
    short* attn_b = Relw + HSD;                   // 4096*768

    // fused prep: 576 transpose blocks + 3072 cast blocks
    prep_kernel<<<dim3(576 + S_TOK * CDIM / 4 / 256), 256, 0, stream>>>(
        x, qkvw, pw, xb, wt, pwt);

    gemm_qkv_mfma<<<dim3((N3C / 128) * (S_TOK / 128)), 256, 0, stream>>>(
        xb, wt, qkvb, Qb, Kb, Vt);
    rel_mfma_kernel<<<dim3(64, NH), 256, 0, stream>>>(Qb, rph, rpw, RelhT, Relw);
    flash_kernel<<<dim3(64 * NH), 256, 0, stream>>>(Qb, Kb, Vt, RelhT, Relw, attn_b);
    gemm_proj_mfma<<<dim3((CDIM / 128) * (S_TOK / 128)), 256, 0, stream>>>(
        attn_b, pwt, pb, out);
}

// Round 14
// 190.536 us; speedup vs baseline: 1.6182x; 1.0732x over previous
//
#include <hip/hip_runtime.h>
#include <hip/hip_bf16.h>

// Problem constants (B=1, H=W=64, C=768, nh=12, hd=64)
#define S_TOK 4096
#define CDIM  768
#define N3C   2304
#define NH    12
#define HD    64

#define LOG2E 1.44269504f

typedef __attribute__((ext_vector_type(8))) short short8;
typedef __attribute__((ext_vector_type(4))) short short4v;
typedef __attribute__((ext_vector_type(4))) float float4v;
typedef __attribute__((ext_vector_type(4))) unsigned uint4v;

__device__ __forceinline__ float b2f(short s) {
    return __uint_as_float(((unsigned)(unsigned short)s) << 16);
}
__device__ __forceinline__ short f2b(float f) {   // round-to-nearest-even
    unsigned u = __float_as_uint(f);
    unsigned r = (u + 0x7FFFu + ((u >> 16) & 1u)) >> 16;
    return (short)r;
}

#if __has_builtin(__builtin_amdgcn_exp2f)
#define EXP2F __builtin_amdgcn_exp2f
#else
#define EXP2F exp2f
#endif

// pack trunc-bf16(a) into low short, trunc-bf16(b) into high short
__device__ __forceinline__ unsigned pack_trunc(float a, float b) {
    return __builtin_amdgcn_perm(__float_as_uint(b), __float_as_uint(a), 0x07060302u);
}

__device__ __forceinline__ short8 u4_to_s8(unsigned a, unsigned b, unsigned c, unsigned d) {
    union { uint4v u; short8 s; } t;
    t.u = (uint4v){a, b, c, d};
    return t.s;
}

// async global->LDS DMA, 16B per lane, dest = ldsbase + lane*16 (linear)
__device__ __forceinline__ void load_lds16(const void* g, void* l) {
    __builtin_amdgcn_global_load_lds(
        (const __attribute__((address_space(1))) unsigned int*)g,
        (__attribute__((address_space(3))) unsigned int*)l, 16, 0, 0);
}

// ---------------------------------------------------------------------------
// Fused preprocessing: ONE kernel.
//   blocks [0,432):   transpose+cast qkv_w fp32[768][2304] -> wt bf16[2304][768]
//   blocks [432,576): transpose+cast proj_w fp32[768][768] -> pwt bf16[768][768]
//   blocks [576,3648): elementwise cast x fp32 -> xb bf16 (4 elems/thread)
// ---------------------------------------------------------------------------
__global__ __launch_bounds__(256) void prep_kernel(
    const float* __restrict__ x, const float* __restrict__ qkvw,
    const float* __restrict__ pw,
    short* __restrict__ xb, short* __restrict__ wt, short* __restrict__ pwt)
{
    __shared__ float t[64][65];
    const int bid = blockIdx.x;
    const int tid = threadIdx.x;

    if (bid < 576) {
        const float* in;
        short* out;
        int C, bx, by;
        if (bid < 432) { in = qkvw; out = wt;  C = N3C;  bx = bid % 36;  by = bid / 36; }
        else           { in = pw;   out = pwt; C = CDIM; bx = (bid - 432) % 12; by = (bid - 432) / 12; }
        const int c0 = bx * 64, r0 = by * 64;
        const int li = tid >> 6;      // 0..3
        const int lj = tid & 63;
#pragma unroll
        for (int p = 0; p < 16; ++p) {
            int i = p * 4 + li;
            t[i][lj] = in[(size_t)(r0 + i) * C + c0 + lj];
        }
        __syncthreads();
#pragma unroll
        for (int p = 0; p < 16; ++p) {
            int i = p * 4 + li;
            out[(size_t)(c0 + i) * CDIM + r0 + lj] = f2b(t[lj][i]);
        }
    } else {
        const int i = (bid - 576) * 256 + tid;   // < 786432 by grid construction
        float4 v = ((const float4*)x)[i];
        short4v o4 = { f2b(v.x), f2b(v.y), f2b(v.z), f2b(v.w) };
        *(short4v*)&xb[(size_t)i * 4] = o4;
    }
}

// ---------------------------------------------------------------------------
// MFMA GEMM core v4: C[128x128] = A[128xK] @ Bt[128xK]^T with the flash-v14
// counted-vmcnt protocol. The old core's [bar; DMA; bar(drain0)] exposed the
// FULL staging latency every one of the 12 K-rounds with zero overlap (the
// barrier drained the just-issued DMAs). v4: double-buffered LDS (64 KB),
// issue round t+1 into buf^1, vmcnt(8) keeps it in flight while waiting only
// on round t, wait-THEN-barrier (cross-wave visibility), compute, end-bar
// (reads consumed via compiler lgkm waits before the bar -> overwrite-safe).
// Buffers are compile-time (loop unrolled) -- no runtime-indexed pointers.
// smem[0..1] (32 KB) is overlaid by the epilogues.
// ---------------------------------------------------------------------------
#define GSTAGE(k0_, bb_)                                                       \
        _Pragma("unroll")                                                      \
        for (int i = 0; i < 4; ++i) {                                          \
            load_lds16(ga + (size_t)i * (32 * 768) + (k0_),                    \
                       &smem[bb_][w * 8 + i * 32][0]);                         \
            load_lds16(gb + (size_t)i * (32 * 768) + (k0_),                    \
                       &smem[(bb_) + 1][w * 8 + i * 32][0]);                   \
        }

#define GCOMPUTE(bb_)                                                          \
        _Pragma("unroll")                                                      \
        for (int kk = 0; kk < 64; kk += 32) {                                  \
            const int roff = kk ? roff1 : roff0;                               \
            short8 af[4], bfr[4];                                              \
            _Pragma("unroll")                                                  \
            for (int i = 0; i < 4; ++i)                                        \
                af[i] = *(const short8*)((const char*)&smem[bb_][wr*64 + i*16 + l15][0] + roff); \
            _Pragma("unroll")                                                  \
            for (int j = 0; j < 4; ++j)                                        \
                bfr[j] = *(const short8*)((const char*)&smem[(bb_)+1][wc*64 + j*16 + l15][0] + roff); \
            _Pragma("unroll")                                                  \
            for (int i = 0; i < 4; ++i)                                        \
                _Pragma("unroll")                                              \
                for (int j = 0; j < 4; ++j)                                    \
                    acc[i][j] = __builtin_amdgcn_mfma_f32_16x16x32_bf16(       \
                        af[i], bfr[j], acc[i][j], 0, 0, 0);                    \
        }

#define GEMM_CORE(A_, Bt_, m0_, n0_)                                           \
    __shared__ __align__(16) short smem[4][128][64];                           \
    const int tid  = threadIdx.x;                                              \
    const int m0 = (m0_);                                                      \
    const int n0 = (n0_);                                                      \
    const int lane = tid & 63, w = tid >> 6;                                   \
    const int l15 = lane & 15, quad = lane >> 4;                               \
    const int wr = w >> 1, wc = w & 1;                                         \
    const int roff0 = (quad ^ (l15 & 7)) << 4;                                 \
    const int roff1 = roff0 ^ 64;                                              \
    const int srow0 = w * 8 + (lane >> 3);                                     \
    const int sslot = (lane & 7) ^ ((lane >> 3) & 7);                          \
    const short* ga = A_ + (size_t)(m0 + srow0) * 768 + sslot * 8;             \
    const short* gb = Bt_ + (size_t)(n0 + srow0) * 768 + sslot * 8;            \
    float4v acc[4][4];                                                         \
    _Pragma("unroll")                                                          \
    for (int i = 0; i < 4; ++i)                                                \
        _Pragma("unroll")                                                      \
        for (int j = 0; j < 4; ++j) acc[i][j] = (float4v){0.f,0.f,0.f,0.f};    \
    GSTAGE(0, 0)                                                               \
    _Pragma("unroll")                                                          \
    for (int tp = 0; tp < 6; ++tp) {                                           \
        /* step A: read buf0, prefetch round 2tp+1 -> buf1 (in flight) */      \
        GSTAGE(tp * 128 + 64, 2)                                               \
        asm volatile("s_waitcnt vmcnt(8)" ::: "memory");                       \
        __builtin_amdgcn_sched_barrier(0);                                     \
        __builtin_amdgcn_s_barrier();                                          \
        GCOMPUTE(0)                                                            \
        __builtin_amdgcn_s_barrier();                                          \
        /* step B: read buf1, prefetch round 2tp+2 -> buf0 (if any) */         \
        if (tp < 5) {                                                          \
            GSTAGE(tp * 128 + 128, 0)                                          \
            asm volatile("s_waitcnt vmcnt(8)" ::: "memory");                   \
        } else {                                                               \
            asm volatile("s_waitcnt vmcnt(0)" ::: "memory");                   \
        }                                                                      \
        __builtin_amdgcn_sched_barrier(0);                                     \
        __builtin_amdgcn_s_barrier();                                          \
        GCOMPUTE(2)                                                            \
        __builtin_amdgcn_s_barrier();                                          \
    }

// QKV GEMM: writes Qb[head][s][d], Kb[head][s][d], Vt[head][d][s] (bf16)
// Grid: 576 1-D blocks, XCD-chunked swizzle (576 = 8 XCD x 72; 72 = 4m x 18n).
// Epilogue: LDS-staged coalesced 16B stores (overlays smem[0..1]).
__global__ __launch_bounds__(256) void gemm_qkv_mfma(
    const short* __restrict__ A, const short* __restrict__ Bt,
    const float* __restrict__ bias,
    short* __restrict__ Qb, short* __restrict__ Kb, short* __restrict__ Vt)
{
    const int flat = blockIdx.x;                    // 0..575
    const int logi = (flat & 7) * 72 + (flat >> 3); // bijective XCD chunking
    GEMM_CORE(A, Bt, (logi / 18) * 128, (logi % 18) * 128)

    const int sec = n0 / CDIM;      // tile fully inside one of q/k/v
    float bj[4];
#pragma unroll
    for (int j = 0; j < 4; ++j) bj[j] = bias[n0 + wc*64 + j*16 + l15];

    if (sec < 2) {
        short* base = (sec == 0) ? Qb : Kb;
        short (*tile)[68] = (short(*)[68])&smem[0][0][0];   // 128x68 = 17408 B
#pragma unroll
        for (int h = 0; h < 2; ++h) {
            __syncthreads();
            if (wc == h) {
#pragma unroll
                for (int i = 0; i < 4; ++i)
#pragma unroll
                    for (int j = 0; j < 4; ++j)
#pragma unroll
                        for (int r = 0; r < 4; ++r)
                            tile[wr*64 + i*16 + quad*4 + r][j*16 + l15] =
                                f2b(acc[i][j][r] + bj[j]);
            }
            __syncthreads();
            const int nn = (n0 % CDIM) + h * 64;
            const int head = nn >> 6;
            short* dst = base + ((size_t)head * S_TOK + m0) * HD;
#pragma unroll
            for (int it = 0; it < 4; ++it) {
                const int row = it * 32 + (tid >> 3), c = (tid & 7) * 8;
                *(short8*)&dst[(size_t)row * HD + c] = *(const short8*)&tile[row][c];
            }
        }
    } else {
        short (*tv)[130] = (short(*)[130])&smem[0][0][0];   // 64x130 = 16640 B
#pragma unroll
        for (int h = 0; h < 2; ++h) {
            __syncthreads();
            if (wc == h) {
#pragma unroll
                for (int i = 0; i < 4; ++i)
#pragma unroll
                    for (int j = 0; j < 4; ++j) {
                        short4v v4;
#pragma unroll
                        for (int r = 0; r < 4; ++r) v4[r] = f2b(acc[i][j][r] + bj[j]);
                        *(short4v*)&tv[j*16 + l15][wr*64 + i*16 + quad*4] = v4;
                    }
            }
            __syncthreads();
            const int nn = (n0 % CDIM) + h * 64;
            const int head = nn >> 6;
            short* dst = Vt + (size_t)head * HD * S_TOK + m0;
#pragma unroll
            for (int it = 0; it < 4; ++it) {
                const int nr = it * 16 + (tid >> 4), sc = (tid & 15) * 8;
                *(short8*)&dst[(size_t)nr * S_TOK + sc] = *(const short8*)&tv[nr][sc];
            }
        }
    }
}

// Proj GEMM: out fp32 [4096][768] = A @ Bt^T + bias
// Grid: 192 1-D blocks, XCD-chunked (192 = 8 x 24; 24 = 4m x 6n).
// Epilogue: LDS float tile (XOR chunk swizzle), coalesced float4 stores.
__global__ __launch_bounds__(256) void gemm_proj_mfma(
    const short* __restrict__ A, const short* __restrict__ Bt,
    const float* __restrict__ bias, float* __restrict__ out)
{
    const int flat = blockIdx.x;                    // 0..191
    const int logi = (flat & 7) * 24 + (flat >> 3); // bijective XCD chunking
    GEMM_CORE(A, Bt, (logi / 6) * 128, (logi % 6) * 128)

    float bj[4];
#pragma unroll
    for (int j = 0; j < 4; ++j) bj[j] = bias[n0 + wc*64 + j*16 + l15];

    float* tf = (float*)&smem[0][0][0];   // [64][128] floats, chunk-XOR layout
#pragma unroll
    for (int h = 0; h < 2; ++h) {
        __syncthreads();
        if (wr == h) {
#pragma unroll
            for (int i = 0; i < 4; ++i)
#pragma unroll
                for (int j = 0; j < 4; ++j) {
                    const int cc = wc*16 + j*4 + (l15 >> 2);   // float4-chunk idx
                    const int ci = l15 & 3;
#pragma unroll
                    for (int r = 0; r < 4; ++r) {
                        const int row = i*16 + quad*4 + r;
                        const int pc = cc ^ ((row & 7) << 2);
                        tf[row * 128 + pc * 4 + ci] = acc[i][j][r] + bj[j];
                    }
                }
        }
        __syncthreads();
        float* dst = out + (size_t)(m0 + h * 64) * CDIM + n0;
#pragma unroll
        for (int it = 0; it < 8; ++it) {
            const int row = it * 8 + (tid >> 5);
            const int gc = tid & 31;
            const int pc = gc ^ ((row & 7) << 2);
            float4 v = *(const float4*)&tf[row * 128 + pc * 4];
            *(float4*)&dst[(size_t)row * CDIM + gc * 4] = v;
        }
    }
}

// ---------------------------------------------------------------------------
// Rel-pos tables via MFMA. One block per (y, head); 64 queries s0=y*64..+63.
// Outputs PRE-SCALED by log2e. Relh stored TRANSPOSED: RelhT[head][ky][s].
// Relw epilogue: LDS-staged -> fully-coalesced 16B row stores.
// ---------------------------------------------------------------------------
__global__ __launch_bounds__(256) void rel_mfma_kernel(
    const short* __restrict__ Qb, const float* __restrict__ rph,
    const float* __restrict__ rpw, short* __restrict__ RelhT,
    short* __restrict__ Relw)
{
    __shared__ __align__(16) short q_s [64][72];
    __shared__ __align__(16) short rh_s[64][72];
    __shared__ __align__(16) short rw_s[128][72];
    __shared__ __align__(16) short relw_t[64][64];

    const int tid  = threadIdx.x;
    const int y    = blockIdx.x;
    const int head = blockIdx.y;
    const int s0   = y * 64;
    const int w = tid >> 6, lane = tid & 63;
    const int l15 = lane & 15, quad = lane >> 4;
    const int srow = tid >> 2;            // 0..63
    const int scol = (tid & 3) << 4;      // 0,16,32,48

    // ---- stage Q (bf16 passthrough) ----
    {
        const uint4* g = (const uint4*)(Qb + ((size_t)head * S_TOK + s0 + srow) * HD + scol);
        *(uint4*)&q_s[srow][scol]     = g[0];
        *(uint4*)&q_s[srow][scol + 8] = g[1];
    }
    // ---- stage rph rows y..y+63 (fp32 -> bf16) ----
    {
        const float* g = rph + (size_t)(y + srow) * HD + scol;
        short tmp[16];
#pragma unroll
        for (int i = 0; i < 16; i += 4) {
            float4 v = *(const float4*)(g + i);
            tmp[i] = f2b(v.x); tmp[i+1] = f2b(v.y); tmp[i+2] = f2b(v.z); tmp[i+3] = f2b(v.w);
        }
        *(short8*)&rh_s[srow][scol]     = *(short8*)&tmp[0];
        *(short8*)&rh_s[srow][scol + 8] = *(short8*)&tmp[8];
    }
    // ---- stage rpw rows 0..127 (row 127 clamped; never consumed) ----
#pragma unroll
    for (int half = 0; half < 2; ++half) {
        const int row = srow + half * 64;
        const int rr  = row > 126 ? 126 : row;
        const float* g = rpw + (size_t)rr * HD + scol;
        short tmp[16];
#pragma unroll
        for (int i = 0; i < 16; i += 4) {
            float4 v = *(const float4*)(g + i);
            tmp[i] = f2b(v.x); tmp[i+1] = f2b(v.y); tmp[i+2] = f2b(v.z); tmp[i+3] = f2b(v.w);
        }
        *(short8*)&rw_s[row][scol]     = *(short8*)&tmp[0];
        *(short8*)&rw_s[row][scol + 8] = *(short8*)&tmp[8];
    }
    __syncthreads();

    const short8 qa0 = *(const short8*)&q_s[w * 16 + l15][quad * 8];
    const short8 qa1 = *(const short8*)&q_s[w * 16 + l15][32 + quad * 8];

    // ---- relh: RH col j = y+jj, ky = 63-jj; transposed short4v stores ----
#pragma unroll
    for (int ct = 0; ct < 4; ++ct) {
        const int jj = ct * 16 + l15;
        short8 b0 = *(const short8*)&rh_s[jj][quad * 8];
        short8 b1 = *(const short8*)&rh_s[jj][32 + quad * 8];
        float4v z = (float4v){0.f, 0.f, 0.f, 0.f};
        z = __builtin_amdgcn_mfma_f32_16x16x32_bf16(qa0, b0, z, 0, 0, 0);
        z = __builtin_amdgcn_mfma_f32_16x16x32_bf16(qa1, b1, z, 0, 0, 0);
        const int ky = 63 - jj;
        short4v o4;
#pragma unroll
        for (int r = 0; r < 4; ++r) o4[r] = f2b(z[r] * LOG2E);
        *(short4v*)&RelhT[((size_t)head * HD + ky) * S_TOK + s0 + w * 16 + quad * 4] = o4;
    }

    // ---- relw: kx = q+63-j, keep 0<=kx<64; stage into LDS ----
#pragma unroll
    for (int ct = 0; ct < 8; ++ct) {
        const int j = ct * 16 + l15;
        short8 b0 = *(const short8*)&rw_s[j][quad * 8];
        short8 b1 = *(const short8*)&rw_s[j][32 + quad * 8];
        float4v z = (float4v){0.f, 0.f, 0.f, 0.f};
        z = __builtin_amdgcn_mfma_f32_16x16x32_bf16(qa0, b0, z, 0, 0, 0);
        z = __builtin_amdgcn_mfma_f32_16x16x32_bf16(qa1, b1, z, 0, 0, 0);
#pragma unroll
        for (int r = 0; r < 4; ++r) {
            const int q  = w * 16 + quad * 4 + r;
            const int kx = q + 63 - j;
            if (kx >= 0 && kx < 64)
                relw_t[q][kx] = f2b(z[r] * LOG2E);
        }
    }
    __syncthreads();
    // coalesced: thread -> row tid>>2, 16 cols at (tid&3)*16
    {
        const int row = tid >> 2, c = (tid & 3) * 16;
        short* dst = Relw + ((size_t)head * S_TOK + s0 + row) * HD + c;
        *(short8*)(dst)     = *(const short8*)&relw_t[row][c];
        *(short8*)(dst + 8) = *(const short8*)&relw_t[row][c + 8];
    }
}

// ---------------------------------------------------------------------------
// Flash attention v14 (UNCHANGED, ~74.5 us measured): counted-vmcnt protocol,
// race-corrected. 3 light barriers/step, zero forced drains; wait-THEN-barrier
// so every cross-wave read follows a barrier at which all waves drained the
// relevant loads. K(t+1) crosses all barriers in flight. Pair-split, K-dbuf +
// V-single LDS, XCD head-group swizzle, 48 KB, 12 waves/CU, setprio on PV.
// ---------------------------------------------------------------------------
__global__ __launch_bounds__(256, 3) void flash_kernel(
    const short* __restrict__ Qb, const short* __restrict__ Kb,
    const short* __restrict__ Vt, const short* __restrict__ RelhT,
    const short* __restrict__ Relw, short* __restrict__ attn_b)
{
    // shorts 0..16383: K[pair][buf][64][64]; 16384..24575: V[pair][64][64]
    __shared__ __align__(16) short lds_s[24576];

    const int tid  = threadIdx.x;
    const int bid  = blockIdx.x;
    const int logi = (bid & 7) * 96 + (bid >> 3);   // XCD head-grouping swizzle
    const int head = logi >> 6;
    const int s0   = (logi & 63) << 6;
    const int w    = tid >> 6, lane = tid & 63;
    const int l15  = lane & 15, quad = lane >> 4;
    const int ph   = w >> 1;          // key-chunk half: chunks ph*32 + t
    const int qh   = w & 1;           // query half: queries qh*32 + ...

    const float C1 = 0.125f * LOG2E;

    // ---- staging lane mapping (linear dest, pre-swizzled source) ----
    const int lj = lane >> 3;             // row within 8-row DMA group
    const int sl = (lane & 7) ^ lj;       // logical 16B slot this lane fetches
    const int kf0 = (lj & 3) + ((lj & 4) << 1) + qh * 32;  // permuted key, ii=0

    const short* pKs = Kb + (size_t)head * S_TOK * HD
                     + (size_t)(ph * 32 * 64 + kf0) * HD + sl * 8;
    const short* pVs = Vt + ((size_t)head * HD + qh * 32 + lj) * S_TOK
                     + ph * 32 * 64 + sl * 8;

    // wave-uniform LDS dest bases (named; ternary select only)
    short* lk0 = &lds_s[(ph * 2 + 0) << 12] + qh * 32 * 64;
    short* lk1 = &lds_s[(ph * 2 + 1) << 12] + qh * 32 * 64;
    short* lv  = &lds_s[16384 + (ph << 12)] + qh * 32 * 64;
    const short* krd0 = &lds_s[(ph * 2 + 0) << 12];
    const short* krd1 = &lds_s[(ph * 2 + 1) << 12];
    const short* vrd  = &lds_s[16384 + (ph << 12)];

    // swizzled read byte-offsets (row&7 == l15&7 for all frag rows)
    const int roff0 = (quad ^ (l15 & 7)) << 4;   // logical slot quad
    const int roff1 = roff0 ^ 64;                // logical slot 4+quad

    // ---- Q B-frags: 2 q-tiles (32 queries per wave) ----
    short8 qb[2][2];
#pragma unroll
    for (int qt = 0; qt < 2; ++qt) {
        const short* qrow = Qb + ((size_t)head * S_TOK + s0 + qh * 32 + qt * 16 + l15) * HD;
        qb[qt][0] = *(const short8*)(qrow + quad * 8);
        qb[qt][1] = *(const short8*)(qrow + 32 + quad * 8);
    }

    // ---- relw invariants: rwv[qt][kt][r], key = kbase(kt) + quad*8 + r ----
    float rwv[2][4][4];
#pragma unroll
    for (int qt = 0; qt < 2; ++qt) {
        const short* rwrow = Relw + ((size_t)head * S_TOK + s0 + qh * 32 + qt * 16 + l15) * HD;
#pragma unroll
        for (int kt = 0; kt < 4; ++kt) {
            const int base = ((kt & 1) << 2) | ((kt >> 1) << 5);
            short4v v = *(const short4v*)(rwrow + base + quad * 8);
#pragma unroll
            for (int r = 0; r < 4; ++r) rwv[qt][kt][r] = b2f(v[r]);
        }
    }

    // RelhT[head][ky][s]: per-chunk coalesced loads (ky == chunk index)
    const short* rhbase = RelhT + (size_t)head * HD * S_TOK + s0 + qh * 32 + l15;
    float rhc0 = b2f(rhbase[(size_t)(ph * 32) * S_TOK]);
    float rhc1 = b2f(rhbase[(size_t)(ph * 32) * S_TOK + 16]);

    // ones A-frag for the denominator
    short8 aones;
#pragma unroll
    for (int j = 0; j < 8; ++j) aones[j] = (short)0x3F80;

    float4v od[2][4];
#pragma unroll
    for (int qt = 0; qt < 2; ++qt)
#pragma unroll
        for (int dt = 0; dt < 4; ++dt) od[qt][dt] = (float4v){0.f, 0.f, 0.f, 0.f};
    float4v dq0 = (float4v){0.f, 0.f, 0.f, 0.f};
    float4v dq1 = (float4v){0.f, 0.f, 0.f, 0.f};

    // ---- prologue: DMA K chunk (ph*32) into buf0; full drain once ----
    load_lds16(pKs,        lk0);
    load_lds16(pKs + 1024, lk0 + 8  * 64);
    load_lds16(pKs + 256,  lk0 + 16 * 64);
    load_lds16(pKs + 1280, lk0 + 24 * 64);
    __syncthreads();

#define S_PHASE(krd_)                                                          \
        unsigned pkk[2][8];                                                    \
        _Pragma("unroll")                                                      \
        for (int kt = 0; kt < 4; ++kt) {                                       \
            const char* krp = (const char*)((krd_) + (kt * 16 + l15) * 64);    \
            const short8 ka0 = *(const short8*)(krp + roff0);                  \
            const short8 ka1 = *(const short8*)(krp + roff1);                  \
            {                                                                  \
                float4v z = (float4v){0.f, 0.f, 0.f, 0.f};                     \
                z = __builtin_amdgcn_mfma_f32_16x16x32_bf16(ka0, qb[0][0], z, 0, 0, 0); \
                z = __builtin_amdgcn_mfma_f32_16x16x32_bf16(ka1, qb[0][1], z, 0, 0, 0); \
                float p0 = EXP2F(C1 * z[0] + (rhc0 + rwv[0][kt][0]));          \
                float p1 = EXP2F(C1 * z[1] + (rhc0 + rwv[0][kt][1]));          \
                float p2 = EXP2F(C1 * z[2] + (rhc0 + rwv[0][kt][2]));          \
                float p3 = EXP2F(C1 * z[3] + (rhc0 + rwv[0][kt][3]));          \
                pkk[0][kt * 2]     = pack_trunc(p0, p1);                       \
                pkk[0][kt * 2 + 1] = pack_trunc(p2, p3);                       \
            }                                                                  \
            {                                                                  \
                float4v z = (float4v){0.f, 0.f, 0.f, 0.f};                     \
                z = __builtin_amdgcn_mfma_f32_16x16x32_bf16(ka0, qb[1][0], z, 0, 0, 0); \
                z = __builtin_amdgcn_mfma_f32_16x16x32_bf16(ka1, qb[1][1], z, 0, 0, 0); \
                float p0 = EXP2F(C1 * z[0] + (rhc1 + rwv[1][kt][0]));          \
                float p1 = EXP2F(C1 * z[1] + (rhc1 + rwv[1][kt][1]));          \
                float p2 = EXP2F(C1 * z[2] + (rhc1 + rwv[1][kt][2]));          \
                float p3 = EXP2F(C1 * z[3] + (rhc1 + rwv[1][kt][3]));          \
                pkk[1][kt * 2]     = pack_trunc(p0, p1);                       \
                pkk[1][kt * 2 + 1] = pack_trunc(p2, p3);                       \
            }                                                                  \
        }                                                                      \
        const short8 pb00 = u4_to_s8(pkk[0][0], pkk[0][1], pkk[0][2], pkk[0][3]); \
        const short8 pb01 = u4_to_s8(pkk[0][4], pkk[0][5], pkk[0][6], pkk[0][7]); \
        const short8 pb10 = u4_to_s8(pkk[1][0], pkk[1][1], pkk[1][2], pkk[1][3]); \
        const short8 pb11 = u4_to_s8(pkk[1][4], pkk[1][5], pkk[1][6], pkk[1][7]);

#define PV_PHASE                                                               \
        __builtin_amdgcn_s_setprio(1);                                         \
        _Pragma("unroll")                                                      \
        for (int dt = 0; dt < 4; ++dt) {                                       \
            const char* vrp = (const char*)(vrd + (dt * 16 + l15) * 64);       \
            const short8 va0 = *(const short8*)(vrp + roff0);                  \
            const short8 va1 = *(const short8*)(vrp + roff1);                  \
            od[0][dt] = __builtin_amdgcn_mfma_f32_16x16x32_bf16(va0, pb00, od[0][dt], 0, 0, 0); \
            od[0][dt] = __builtin_amdgcn_mfma_f32_16x16x32_bf16(va1, pb01, od[0][dt], 0, 0, 0); \
            od[1][dt] = __builtin_amdgcn_mfma_f32_16x16x32_bf16(va0, pb10, od[1][dt], 0, 0, 0); \
            od[1][dt] = __builtin_amdgcn_mfma_f32_16x16x32_bf16(va1, pb11, od[1][dt], 0, 0, 0); \
        }                                                                      \
        dq0 = __builtin_amdgcn_mfma_f32_16x16x32_bf16(aones, pb00, dq0, 0, 0, 0); \
        dq0 = __builtin_amdgcn_mfma_f32_16x16x32_bf16(aones, pb01, dq0, 0, 0, 0); \
        dq1 = __builtin_amdgcn_mfma_f32_16x16x32_bf16(aones, pb10, dq1, 0, 0, 0); \
        dq1 = __builtin_amdgcn_mfma_f32_16x16x32_bf16(aones, pb11, dq1, 0, 0, 0); \
        __builtin_amdgcn_s_setprio(0);

    for (int t = 0; t < 31; ++t) {
        const int cur = t & 1;
        const short* krd = cur ? krd1 : krd0;
        short* lkn = cur ? lk0 : lk1;

        // ---- issue order pinned: V(t), rh(t+1), K(t+1) ----
        load_lds16(pVs,               lv);
        load_lds16(pVs + 8  * S_TOK,  lv + 8  * 64);
        load_lds16(pVs + 16 * S_TOK,  lv + 16 * 64);
        load_lds16(pVs + 24 * S_TOK,  lv + 24 * 64);
        asm volatile("" ::: "memory");
        short rhn0 = rhbase[(size_t)(ph * 32 + t + 1) * S_TOK];
        short rhn1 = rhbase[(size_t)(ph * 32 + t + 1) * S_TOK + 16];
        asm volatile("" ::: "memory");
        {
            const short* pk = pKs + 4096;
            load_lds16(pk,        lkn);
            load_lds16(pk + 1024, lkn + 8  * 64);
            load_lds16(pk + 256,  lkn + 16 * 64);
            load_lds16(pk + 1280, lkn + 24 * 64);
        }
        pKs += 4096;
        pVs += 64;

        // own K(t) drained (oldest 4); V/rh/K(t+1) stay in flight (10)
        asm volatile("s_waitcnt vmcnt(10)" ::: "memory");
        __builtin_amdgcn_sched_barrier(0);
        __builtin_amdgcn_s_barrier();         // bar1: ALL waves' K(t) visible

        S_PHASE(krd)

        // own V(t) drained; rh(2)+K(t+1)(4) stay in flight
        asm volatile("s_waitcnt vmcnt(6)" ::: "memory");
        __builtin_amdgcn_sched_barrier(0);
        __builtin_amdgcn_s_barrier();         // bar2: ALL waves' V(t) visible

        PV_PHASE

        rhc0 = b2f(rhn0);   // compiler emits vmcnt(4): K(t+1) keeps flying
        rhc1 = b2f(rhn1);

        __builtin_amdgcn_s_barrier();         // bar3: PV reads done before
                                              //        next step's V writes
    }

    // ---- peeled t = 31 (no prefetches; safe drains) ----
    {
        const short* krd = krd1;   // 31 & 1
        load_lds16(pVs,               lv);
        load_lds16(pVs + 8  * S_TOK,  lv + 8  * 64);
        load_lds16(pVs + 16 * S_TOK,  lv + 16 * 64);
        load_lds16(pVs + 24 * S_TOK,  lv + 24 * 64);

        asm volatile("s_waitcnt vmcnt(4)" ::: "memory");   // own K(31) done
        __builtin_amdgcn_sched_barrier(0);
        __builtin_amdgcn_s_barrier();

        S_PHASE(krd)

        asm volatile("s_waitcnt vmcnt(0)" ::: "memory");   // own V(31) done
        __builtin_amdgcn_sched_barrier(0);
        __builtin_amdgcn_s_barrier();

        PV_PHASE
    }
#undef S_PHASE
#undef PV_PHASE

    // ---- cross-pair combine (cf overlays K bufs: all K reads ended before
    //      the peeled bar2; cf does not overlap vrd, so no barrier needed
    //      between PV and the ph==1 cf writes) ----
    float* cf = (float*)lds_s;   // comb: [qh][qt][dt][16][16] floats; dq at 4096
    if (ph == 1) {
#pragma unroll
        for (int qt = 0; qt < 2; ++qt)
#pragma unroll
            for (int dt = 0; dt < 4; ++dt) {
                float* dst = &cf[((((qh * 2 + qt) * 4 + dt) * 16) + quad * 4) * 16 + l15];
#pragma unroll
                for (int r = 0; r < 4; ++r) dst[r * 16] = od[qt][dt][r];
            }
        if (quad == 0) {
            cf[4096 + (qh * 2 + 0) * 16 + l15] = dq0[0];
            cf[4096 + (qh * 2 + 1) * 16 + l15] = dq1[0];
        }
    }
    __syncthreads();
    if (ph == 0) {
#pragma unroll
        for (int qt = 0; qt < 2; ++qt) {
            const float dtot = ((qt == 0) ? dq0[0] : dq1[0])
                             + cf[4096 + (qh * 2 + qt) * 16 + l15];
            const float inv = 1.f / dtot;
            short* outp = attn_b + (size_t)(s0 + qh * 32 + qt * 16 + l15) * CDIM + head * HD;
#pragma unroll
            for (int dt = 0; dt < 4; ++dt) {
                const float* src = &cf[((((qh * 2 + qt) * 4 + dt) * 16) + quad * 4) * 16 + l15];
                short4v o4;
#pragma unroll
                for (int r = 0; r < 4; ++r)
                    o4[r] = f2b((od[qt][dt][r] + src[r * 16]) * inv);
                *(short4v*)(outp + dt * 16 + quad * 4) = o4;
            }
        }
    }
}

// ---------------------------------------------------------------------------
extern "C" void kernel_launch(void* const* d_in, const int* in_sizes, int n_in,
                              void* d_out, int out_size, void* d_ws, size_t ws_size,
                              hipStream_t stream)
{
    const float* x    = (const float*)d_in[0];
    const float* qkvw = (const float*)d_in[1];
    const float* qkvb = (const float*)d_in[2];
    const float* rph  = (const float*)d_in[3];
    const float* rpw  = (const float*)d_in[4];
    const float* pw   = (const float*)d_in[5];
    const float* pb   = (const float*)d_in[6];
    float* out = (float*)d_out;

    // ws layout (shorts), total ~48.8 MB
    const size_t HSD = (size_t)NH * S_TOK * HD;   // 3,145,728
    short* xb     = (short*)d_ws;                 // 4096*768
    short* wt     = xb + (size_t)S_TOK * CDIM;    // 2304*768 (qkv_w^T)
    short* pwt    = wt + (size_t)N3C * CDIM;      // 768*768  (proj_w^T)
    short* Qb     = pwt + (size_t)CDIM * CDIM;
    short* Kb     = Qb + HSD;
    short* Vt     = Kb + HSD;
    short* RelhT  = Vt + HSD;                     // [head][ky][s]
    short* Relw   = RelhT + HSD;
    short* attn_b = Relw + HSD;                   // 4096*768

    // fused prep: 576 transpose blocks + 3072 cast blocks
    prep_kernel<<<dim3(576 + S_TOK * CDIM / 4 / 256), 256, 0, stream>>>(
        x, qkvw, pw, xb, wt, pwt);

    gemm_qkv_mfma<<<dim3((N3C / 128) * (S_TOK / 128)), 256, 0, stream>>>(
        xb, wt, qkvb, Qb, Kb, Vt);
    rel_mfma_kernel<<<dim3(64, NH), 256, 0, stream>>>(Qb, rph, rpw, RelhT, Relw);
    flash_kernel<<<dim3(64 * NH), 256, 0, stream>>>(Qb, Kb, Vt, RelhT, Relw, attn_b);
    gemm_proj_mfma<<<dim3((CDIM / 128) * (S_TOK / 128)), 256, 0, stream>>>(
        attn_b, pwt, pb, out);
}